// Round 1
// baseline (41507.852 us; speedup 1.0000x reference)
//
#include <hip/hip_runtime.h>
#include <cstdint>
#include <cstddef>

typedef _Float16 f16;
typedef _Float16 f16x8 __attribute__((ext_vector_type(8)));
typedef float f32x4 __attribute__((ext_vector_type(4)));

#define NWG 256
#define WGSZ 256

namespace gru {

__device__ inline f32x4 mf(f16x8 a, f16x8 b, f32x4 c) {
  return __builtin_amdgcn_mfma_f32_16x16x32_f16(a, b, c, 0, 0, 0);
}
__device__ inline float sigf(float x) { return 1.f / (1.f + __expf(-x)); }
__device__ inline float tanh_fast(float x) {
  float xx = fminf(fmaxf(x, -15.f), 15.f);
  float e = __expf(-2.f * xx);
  return (1.f - e) / (1.f + e);
}

struct SMem {
  f16 wA[48 * 1024];      // 96 KB: whh0 / wih1 / whh1 (swizzled)
  f16 wB[48 * 512];       // 48 KB: wih0 (swizzled)
  float sc[2][4][4][64];  // 8 KB reduce scratch
  float hm0[16][16];      // fp32 h0 master tile
  float hm1[16][16];      // fp32 h1 master tile
  float bA[48];
  float bB[48];
};

struct Args {
  const f16* x16;
  const float* bih0; const float* bhh0; const float* bih1; const float* bhh1; const float* bout;
  const f16* wih0; const f16* whh0; const f16* wih1; const f16* whh1; const f16* wout;
  f16* h0;   // [(C+1)][64][1024]
  f16* gi1;  // [C][64][3072]
  f16* h1;   // [2][64][1024]
  float* out;
  unsigned* bar;  // leaves at [g*16], g<8; root at [192]
  int C; int nchunk;
};

// 2-level monotonic grid barrier: no reset, k = 1-based barrier index.
__device__ inline void gbar(unsigned* bar, unsigned k) {
  __syncthreads();
  if (threadIdx.x == 0) {
    __threadfence();  // release: make h/gi stores device-visible (L2 wb)
    unsigned old = __hip_atomic_fetch_add(&bar[(blockIdx.x >> 5) * 16], 1u,
                                          __ATOMIC_ACQ_REL, __HIP_MEMORY_SCOPE_AGENT);
    if (((old + 1u) & 31u) == 0u)
      __hip_atomic_fetch_add(&bar[192], 1u, __ATOMIC_ACQ_REL, __HIP_MEMORY_SCOPE_AGENT);
    while (__hip_atomic_load(&bar[192], __ATOMIC_RELAXED, __HIP_MEMORY_SCOPE_AGENT) < k * 8u)
      __builtin_amdgcn_s_sleep(2);
    __threadfence();  // acquire: invalidate stale lines
  }
  __syncthreads();
}

// Load 48 gate-rows (triplet j) of W [3072][K8*8] into LDS, XOR-swizzled per 16B unit.
template <int K8>
__device__ void load_w(f16* dst, const f16* W, int j) {
  for (int u = threadIdx.x; u < 48 * K8; u += WGSZ) {
    int row = u / K8, k8 = u - row * K8;
    int gcol = (row >> 4) * 1024 + j * 16 + (row & 15);
    f16x8 v = *(const f16x8*)(W + (size_t)gcol * (size_t)(K8 * 8) + (size_t)k8 * 8);
    *(f16x8*)(dst + ((size_t)row * K8 + (size_t)(k8 ^ (row & 7))) * 8) = v;
  }
}

template <int K8>
__device__ inline f16x8 ldb(const f16* base, int row, int u8) {
  return *(const f16x8*)(base + ((size_t)row * K8 + (size_t)(u8 ^ (row & 7))) * 8);
}

// K-split reduction: waves {2,3} -> {0,1} -> 0. Final sum lives in wave 0's acc.
template <int NT>
__device__ inline void wg_reduce(f32x4* acc, float sc[2][4][4][64], int wave, int lane) {
  if (wave >= 2)
    for (int t = 0; t < NT; ++t)
      for (int q = 0; q < 4; ++q) sc[wave - 2][t][q][lane] = acc[t][q];
  __syncthreads();
  if (wave < 2)
    for (int t = 0; t < NT; ++t)
      for (int q = 0; q < 4; ++q) acc[t][q] += sc[wave][t][q][lane];
  __syncthreads();
  if (wave == 1)
    for (int t = 0; t < NT; ++t)
      for (int q = 0; q < 4; ++q) sc[0][t][q][lane] = acc[t][q];
  __syncthreads();
  if (wave == 0)
    for (int t = 0; t < NT; ++t)
      for (int q = 0; q < 4; ++q) acc[t][q] += sc[0][t][q][lane];
}

}  // namespace gru

// ---------------- prep kernels ----------------

__global__ void gru_k_pe(float* pe) {
  int idx = blockIdx.x * 256 + threadIdx.x;
  if (idx >= 1024 * 512) return;
  int t = idx >> 9, d = idx & 511;
  int jj = d >> 1;
  float freq = expf(-logf(10000.f) * (float)(2 * jj) * (1.f / 512.f));
  float ang = (float)t * freq;
  pe[idx] = (d & 1) ? cosf(ang) : sinf(ang);
}

__global__ void gru_k_x16(const float* __restrict__ x, const float* __restrict__ pe,
                          f16* __restrict__ x16) {
  int d = blockIdx.x * 256 + threadIdx.x;  // grid.x = 2
  int t = blockIdx.y, b = blockIdx.z;
  float v = x[((size_t)b * 1024 + t) * 512 + d] + pe[t * 512 + d];
  x16[((size_t)t * 64 + b) * 512 + d] = (f16)v;
}

__global__ void gru_k_f16(const float* __restrict__ src, f16* __restrict__ dst, int n) {
  int i = blockIdx.x * 256 + threadIdx.x;
  if (i < n) dst[i] = (f16)src[i];
}

// ---------------- main persistent kernel ----------------

__global__ __launch_bounds__(WGSZ, 1) void gru_main(gru::Args A) {
  using namespace gru;
  __shared__ SMem sm;
  const int wg = blockIdx.x, tid = threadIdx.x;
  const int j = wg & 63, rg = wg >> 6;
  const int wave = tid >> 6, lane = tid & 63;
  const int lr = lane & 15, lk8 = lane >> 4;
  const int lk = lk8 * 8, dr = lk8 * 4;
  const int C = A.C;
  unsigned bk = 0;

  ((float*)sm.hm0)[tid] = 0.f;
  ((float*)sm.hm1)[tid] = 0.f;

  for (int c = 0; c < A.nchunk; ++c) {
    // ================= layer-0 recurrence =================
    __syncthreads();
    load_w<128>(sm.wA, A.whh0, j);
    load_w<64>(sm.wB, A.wih0, j);
    if (tid < 48) {
      int gcol = (tid >> 4) * 1024 + j * 16 + (tid & 15);
      sm.bA[tid] = A.bih0[gcol];
      sm.bB[tid] = A.bhh0[gcol];
    }
    __syncthreads();
    for (int i = 0; i < C; ++i) {
      const int rs = (i == 0) ? C : i;  // slot C carries state across chunks (memset 0 at start)
      const f16* Ax = A.x16 + ((size_t)(c * C + i) * 64 + rg * 16 + lr) * 512 + lk;
      const f16* Ah = A.h0 + ((size_t)rs * 64 + rg * 16 + lr) * 1024 + lk;
      f32x4 acc[4];
      for (int t = 0; t < 4; ++t) acc[t] = (f32x4){0.f, 0.f, 0.f, 0.f};
#pragma unroll
      for (int s = 0; s < 12; ++s) {
        const int ks = wave * 12 + s;  // concat-K: 0..15 = x-part, 16..47 = h-part
        if (ks < 16) {
          f16x8 a = *(const f16x8*)(Ax + ks * 32);
          const int u8 = ks * 4 + lk8;
          acc[0] = mf(a, ldb<64>(sm.wB, lr, u8), acc[0]);
          acc[1] = mf(a, ldb<64>(sm.wB, 16 + lr, u8), acc[1]);
          acc[2] = mf(a, ldb<64>(sm.wB, 32 + lr, u8), acc[2]);  // i_n
        } else {
          const int kk = ks - 16;
          f16x8 a = *(const f16x8*)(Ah + kk * 32);
          const int u8 = kk * 4 + lk8;
          acc[0] = mf(a, ldb<128>(sm.wA, lr, u8), acc[0]);
          acc[1] = mf(a, ldb<128>(sm.wA, 16 + lr, u8), acc[1]);
          acc[3] = mf(a, ldb<128>(sm.wA, 32 + lr, u8), acc[3]);  // h_n
        }
      }
      wg_reduce<4>(acc, sm.sc, wave, lane);
      if (wave == 0) {
#pragma unroll
        for (int q = 0; q < 4; ++q) {
          int row = dr + q;
          float r = sigf(acc[0][q] + sm.bA[lr] + sm.bB[lr]);
          float z = sigf(acc[1][q] + sm.bA[16 + lr] + sm.bB[16 + lr]);
          float n = tanh_fast(acc[2][q] + sm.bA[32 + lr] + r * (acc[3][q] + sm.bB[32 + lr]));
          float hp = sm.hm0[row][lr];
          float hn = (1.f - z) * n + z * hp;
          sm.hm0[row][lr] = hn;
          A.h0[((size_t)(i + 1) * 64 + rg * 16 + row) * 1024 + j * 16 + lr] = (f16)hn;
        }
      }
      gbar(A.bar, ++bk);
    }
    // ================= gi1 chunk GEMM =================
    load_w<128>(sm.wA, A.wih1, j);
    if (tid < 48) sm.bA[tid] = A.bih1[(tid >> 4) * 1024 + j * 16 + (tid & 15)];
    __syncthreads();
    {
      const int nblk = C / 4;  // 64-row blocks over C*16 rows per rowgroup
      for (int blk = 0; blk < nblk; ++blk) {
        const int R0 = rg * (C * 16) + blk * 64 + wave * 16;
        const f16* Ap = A.h0 + ((size_t)(64 + R0 + lr)) * 1024 + lk;
        f32x4 acc[3];
        for (int t = 0; t < 3; ++t) acc[t] = (f32x4){0.f, 0.f, 0.f, 0.f};
#pragma unroll 8
        for (int ks = 0; ks < 32; ++ks) {
          f16x8 a = *(const f16x8*)(Ap + ks * 32);
          const int u8 = ks * 4 + lk8;
          acc[0] = mf(a, ldb<128>(sm.wA, lr, u8), acc[0]);
          acc[1] = mf(a, ldb<128>(sm.wA, 16 + lr, u8), acc[1]);
          acc[2] = mf(a, ldb<128>(sm.wA, 32 + lr, u8), acc[2]);
        }
#pragma unroll
        for (int q = 0; q < 4; ++q) {
          const size_t R = (size_t)R0 + dr + q;
          f16* o = A.gi1 + R * 3072 + j * 16 + lr;
          o[0] = (f16)(acc[0][q] + sm.bA[lr]);
          o[1024] = (f16)(acc[1][q] + sm.bA[16 + lr]);
          o[2048] = (f16)(acc[2][q] + sm.bA[32 + lr]);
        }
      }
    }
    gbar(A.bar, ++bk);
    // ================= layer-1 recurrence =================
    load_w<128>(sm.wA, A.whh1, j);
    if (tid < 48) sm.bA[tid] = A.bhh1[(tid >> 4) * 1024 + j * 16 + (tid & 15)];
    __syncthreads();
    for (int i = 0; i < C; ++i) {
      const int gt = c * C + i;
      float gi[3][4];
      if (wave == 0) {
#pragma unroll
        for (int q = 0; q < 4; ++q) {
          const f16* gp = A.gi1 + ((size_t)i * 64 + rg * 16 + dr + q) * 3072 + j * 16 + lr;
          gi[0][q] = (float)gp[0];
          gi[1][q] = (float)gp[1024];
          gi[2][q] = (float)gp[2048];
        }
      }
      const f16* Ah = A.h1 + ((size_t)(gt & 1) * 64 + rg * 16 + lr) * 1024 + lk;
      f32x4 acc[3];
      for (int t = 0; t < 3; ++t) acc[t] = (f32x4){0.f, 0.f, 0.f, 0.f};
#pragma unroll
      for (int s = 0; s < 8; ++s) {
        const int ks = wave * 8 + s;
        f16x8 a = *(const f16x8*)(Ah + ks * 32);
        const int u8 = ks * 4 + lk8;
        acc[0] = mf(a, ldb<128>(sm.wA, lr, u8), acc[0]);
        acc[1] = mf(a, ldb<128>(sm.wA, 16 + lr, u8), acc[1]);
        acc[2] = mf(a, ldb<128>(sm.wA, 32 + lr, u8), acc[2]);
      }
      wg_reduce<3>(acc, sm.sc, wave, lane);
      if (wave == 0) {
#pragma unroll
        for (int q = 0; q < 4; ++q) {
          int row = dr + q;
          float r = sigf(gi[0][q] + acc[0][q] + sm.bA[lr]);
          float z = sigf(gi[1][q] + acc[1][q] + sm.bA[16 + lr]);
          float n = tanh_fast(gi[2][q] + r * (acc[2][q] + sm.bA[32 + lr]));
          float hp = sm.hm1[row][lr];
          float hn = (1.f - z) * n + z * hp;
          sm.hm1[row][lr] = hn;
          A.h1[((size_t)((gt + 1) & 1) * 64 + rg * 16 + row) * 1024 + j * 16 + lr] = (f16)hn;
        }
      }
      gbar(A.bar, ++bk);
    }
  }
  // ================= output projection: out = h1(1024) @ w_out^T + b_out =================
  if (wg < 128) {
    using namespace gru;
    const int j2 = wg & 31, rg2 = wg >> 5;
    const f16* Ah = A.h1 + ((size_t)(rg2 * 16 + lr)) * 1024 + lk;  // h1(1024) is in slot 0
    const f16* Bp = A.wout + ((size_t)(j2 * 16 + lr)) * 1024 + lk;
    f32x4 acc[1];
    acc[0] = (f32x4){0.f, 0.f, 0.f, 0.f};
#pragma unroll
    for (int s = 0; s < 8; ++s) {
      const int ks = wave * 8 + s;
      f16x8 a = *(const f16x8*)(Ah + ks * 32);
      f16x8 b = *(const f16x8*)(Bp + ks * 32);
      acc[0] = gru::mf(a, b, acc[0]);
    }
    gru::wg_reduce<1>(acc, sm.sc, wave, lane);
    if (wave == 0) {
#pragma unroll
      for (int q = 0; q < 4; ++q) {
        const int row = rg2 * 16 + dr + q;
        const int col = j2 * 16 + lr;
        A.out[row * 512 + col] = acc[0][q] + A.bout[col];
      }
    }
  }
}

// ---------------- host ----------------

extern "C" void kernel_launch(void* const* d_in, const int* in_sizes, int n_in,
                              void* d_out, int out_size, void* d_ws, size_t ws_size,
                              hipStream_t stream) {
  (void)in_sizes; (void)n_in; (void)out_size;
  const float* x = (const float*)d_in[0];
  const float* w_ih0 = (const float*)d_in[1];
  const float* w_hh0 = (const float*)d_in[2];
  const float* b_ih0 = (const float*)d_in[3];
  const float* b_hh0 = (const float*)d_in[4];
  const float* w_ih1 = (const float*)d_in[5];
  const float* w_hh1 = (const float*)d_in[6];
  const float* b_ih1 = (const float*)d_in[7];
  const float* b_hh1 = (const float*)d_in[8];
  const float* w_out = (const float*)d_in[9];
  const float* b_out = (const float*)d_in[10];

  char* ws = (char*)d_ws;
  size_t off = 0;
  auto alloc = [&](size_t b) {
    off = (off + 255) & ~(size_t)255;
    char* p = ws + off;
    off += b;
    return p;
  };

  float* pe = (float*)alloc((size_t)1024 * 512 * 4);
  f16* x16 = (f16*)alloc((size_t)1024 * 64 * 512 * 2);
  f16* wih0 = (f16*)alloc((size_t)3072 * 512 * 2);
  f16* whh0 = (f16*)alloc((size_t)3072 * 1024 * 2);
  f16* wih1 = (f16*)alloc((size_t)3072 * 1024 * 2);
  f16* whh1 = (f16*)alloc((size_t)3072 * 1024 * 2);
  f16* wout = (f16*)alloc((size_t)512 * 1024 * 2);
  f16* h1buf = (f16*)alloc((size_t)2 * 64 * 1024 * 2);
  unsigned* bar = (unsigned*)alloc(1024);

  size_t fixed = (off + 255) & ~(size_t)255;
  int C = 16;
  {
    const int cands[7] = {1024, 512, 256, 128, 64, 32, 16};
    for (int ci = 0; ci < 7; ++ci) {
      int cc = cands[ci];
      size_t need = fixed + 256 + ((size_t)cc + 1) * 64 * 1024 * 2 + 256 + (size_t)cc * 64 * 3072 * 2;
      if (need <= ws_size) { C = cc; break; }
    }
  }
  f16* h0hist = (f16*)alloc(((size_t)C + 1) * 64 * 1024 * 2);
  f16* gi1 = (f16*)alloc((size_t)C * 64 * 3072 * 2);

  // per-call init (harness poisons ws once; we must re-zero what we read-before-write)
  (void)hipMemsetAsync(bar, 0, 1024, stream);
  (void)hipMemsetAsync(h1buf, 0, (size_t)2 * 64 * 1024 * 2, stream);
  (void)hipMemsetAsync(h0hist + (size_t)C * 64 * 1024, 0, (size_t)64 * 1024 * 2, stream);

  gru_k_pe<<<(1024 * 512 + 255) / 256, 256, 0, stream>>>(pe);
  gru_k_x16<<<dim3(2, 1024, 64), 256, 0, stream>>>(x, pe, x16);
  gru_k_f16<<<(3072 * 512 + 255) / 256, 256, 0, stream>>>(w_ih0, wih0, 3072 * 512);
  gru_k_f16<<<(3072 * 1024 + 255) / 256, 256, 0, stream>>>(w_hh0, whh0, 3072 * 1024);
  gru_k_f16<<<(3072 * 1024 + 255) / 256, 256, 0, stream>>>(w_ih1, wih1, 3072 * 1024);
  gru_k_f16<<<(3072 * 1024 + 255) / 256, 256, 0, stream>>>(w_hh1, whh1, 3072 * 1024);
  gru_k_f16<<<(512 * 1024 + 255) / 256, 256, 0, stream>>>(w_out, wout, 512 * 1024);

  gru::Args A;
  A.x16 = x16;
  A.bih0 = b_ih0; A.bhh0 = b_hh0; A.bih1 = b_ih1; A.bhh1 = b_hh1; A.bout = b_out;
  A.wih0 = wih0; A.whh0 = whh0; A.wih1 = wih1; A.whh1 = whh1; A.wout = wout;
  A.h0 = h0hist; A.gi1 = gi1; A.h1 = h1buf;
  A.out = (float*)d_out;
  A.bar = bar;
  A.C = C;
  A.nchunk = 1024 / C;

  void* kargs[] = {(void*)&A};
  (void)hipLaunchCooperativeKernel((const void*)gru_main, dim3(NWG), dim3(WGSZ), kargs, 0, stream);
}

// Round 5
// 17486.639 us; speedup vs baseline: 2.3737x; 2.3737x over previous
//
#include <hip/hip_runtime.h>
#include <cstdint>
#include <cstddef>

typedef _Float16 f16;
typedef _Float16 f16x8 __attribute__((ext_vector_type(8)));
typedef float f32x4 __attribute__((ext_vector_type(4)));
typedef unsigned long long u64;

#define NWG 256
#define WGSZ 256

namespace gru {

__device__ inline f32x4 mf(f16x8 a, f16x8 b, f32x4 c) {
  return __builtin_amdgcn_mfma_f32_16x16x32_f16(a, b, c, 0, 0, 0);
}
__device__ inline float sigf(float x) { return 1.f / (1.f + __expf(-x)); }
__device__ inline float tanh_fast(float x) {
  float xx = fminf(fmaxf(x, -15.f), 15.f);
  float e = __expf(-2.f * xx);
  return (1.f - e) / (1.f + e);
}

struct SMem {
  f16 wA[48 * 1024];      // 96 KB: whh0 (L0) or whh1 (L1), swizzled
  f16 wB[48 * 512];       // 48 KB: wih0 (L0 only), swizzled
  float sc[2][4][4][64];  // 8 KB pairwise-reduce scratch
  float hm[32][16];       // fp32 master h tile (this WG's 32 rows x 16 cols)
  float bI[48], bH[48];
};

struct Args {
  const f16* x16;
  const float* bih0; const float* bhh0; const float* bih1; const float* bhh1; const float* bout;
  const f16* wih0; const f16* whh0; const f16* wih1; const f16* whh1; const f16* wout;
  f16* h0;   // ring [2][64][1024]
  f16* h1;   // ring [2][64][1024]
  float* out;
  unsigned* bar;  // leaves at [(bid&7)*16], root at [128]
};

// ---- coherent cross-XCD exchange: compiler-lowered agent-scope atomics only.
// R1 proved (passing run): relaxed agent atomic LOAD observes remote agent RMW.

__device__ inline u64 ald8(const f16* p) {
  return __hip_atomic_load((u64*)p, __ATOMIC_RELAXED, __HIP_MEMORY_SCOPE_AGENT);
}
__device__ inline f16x8 ld8c(const f16* p) {
  union { u64 u[2]; f16x8 v; } x;
  x.u[0] = ald8(p);
  x.u[1] = ald8(p + 4);
  return x.v;
}
__device__ inline void axch8(f16* p, u64 v) {
  (void)__hip_atomic_exchange((u64*)p, v, __ATOMIC_RELAXED, __HIP_MEMORY_SCOPE_AGENT);
}

// Pack this lane's 4 gate outputs (rows dr..dr+3 of col lr) into one u64 holding
// 4 adjacent cols of ONE row, via 2x shfl_xor across the 4-lane col-group.
// Lane with (lr&3)==q ends up owning row dr+q, cols (lr&~3)..+3.
__device__ inline u64 pack4(const float* hn4, int lr) {
  u64 w = 0;
#pragma unroll
  for (int q = 0; q < 4; ++q) {
    f16 h = (f16)hn4[q];
    unsigned own = (unsigned)__builtin_bit_cast(unsigned short, h);
    unsigned p1 = (unsigned)__shfl_xor((int)own, 1, 64);
    unsigned v32 = (lr & 1) ? ((own << 16) | p1) : (own | (p1 << 16));
    unsigned o2 = (unsigned)__shfl_xor((int)v32, 2, 64);
    u64 v64 = (lr & 2) ? (((u64)v32 << 32) | (u64)o2) : (((u64)o2 << 32) | (u64)v32);
    if ((lr & 3) == q) w = v64;
  }
  return w;
}

// 2-level grid barrier: leaf/root RELEASE fetch_add (orders prior exchanges),
// RELAXED spin. No cache maintenance anywhere -> weights/x stay cached.
__device__ inline void gbar(unsigned* bar, unsigned k) {
  __syncthreads();
  if (threadIdx.x == 0) {
    unsigned old = __hip_atomic_fetch_add(&bar[(blockIdx.x & 7) << 4], 1u,
                                          __ATOMIC_RELEASE, __HIP_MEMORY_SCOPE_AGENT);
    if ((old & 31u) == 31u)
      __hip_atomic_fetch_add(&bar[128], 1u, __ATOMIC_RELEASE, __HIP_MEMORY_SCOPE_AGENT);
    while (__hip_atomic_load(&bar[128], __ATOMIC_RELAXED, __HIP_MEMORY_SCOPE_AGENT) < k * 8u)
      __builtin_amdgcn_s_sleep(1);
  }
  __syncthreads();
}

// Load 48 gate-rows (triplet j) of W [3072][K8*8] into LDS, XOR-swizzled per 16B unit.
template <int K8>
__device__ void load_w(f16* dst, const f16* W, int j) {
  for (int u = threadIdx.x; u < 48 * K8; u += WGSZ) {
    int row = u / K8, k8 = u - row * K8;
    int gcol = (row >> 4) * 1024 + j * 16 + (row & 15);
    f16x8 v = *(const f16x8*)(W + (size_t)gcol * (size_t)(K8 * 8) + (size_t)k8 * 8);
    *(f16x8*)(dst + ((size_t)row * K8 + (size_t)(k8 ^ (row & 7))) * 8) = v;
  }
}

template <int K8>
__device__ inline f16x8 ldb(const f16* base, int row, int u8) {
  return *(const f16x8*)(base + ((size_t)row * K8 + (size_t)(u8 ^ (row & 7))) * 8);
}

}  // namespace gru

// ---------------- prep kernels ----------------

__global__ void gru_k_pe(float* pe) {
  int idx = blockIdx.x * 256 + threadIdx.x;
  if (idx >= 1024 * 512) return;
  int t = idx >> 9, d = idx & 511;
  int jj = d >> 1;
  float freq = expf(-logf(10000.f) * (float)(2 * jj) * (1.f / 512.f));
  float ang = (float)t * freq;
  pe[idx] = (d & 1) ? cosf(ang) : sinf(ang);
}

__global__ void gru_k_x16(const float* __restrict__ x, const float* __restrict__ pe,
                          f16* __restrict__ x16) {
  int d = blockIdx.x * 256 + threadIdx.x;  // grid.x = 2
  int t = blockIdx.y, b = blockIdx.z;
  float v = x[((size_t)b * 1024 + t) * 512 + d] + pe[t * 512 + d];
  x16[((size_t)t * 64 + b) * 512 + d] = (f16)v;
}

__global__ void gru_k_f16(const float* __restrict__ src, f16* __restrict__ dst, int n) {
  int i = blockIdx.x * 256 + threadIdx.x;
  if (i < n) dst[i] = (f16)src[i];
}

// ---------------- main persistent pipelined kernel ----------------
// PLAIN (non-cooperative) launch: 256 blocks x 154KB LDS = exactly 1 block/CU
// on 256 CUs -> all blocks co-resident by construction.
// WGs 0..127: layer-0 at step t=s.  WGs 128..255: layer-1 at t=s-1 (skew 1).

__global__ __launch_bounds__(WGSZ, 1) void gru_main(gru::Args A) {
  using namespace gru;
  __shared__ SMem sm;
  const int wg = blockIdx.x, tid = threadIdx.x;
  const bool isL0 = wg < 128;
  const int j = wg & 63, rg = (wg >> 6) & 1;
  const int wave = tid >> 6, lane = tid & 63;
  const int lr = lane & 15, lk8 = lane >> 4;
  const int lk = lk8 * 8, dr = lk8 * 4;
  const int rt = wave >> 1, kh = wave & 1;  // rowtile, K-half per wave
  const int rowbase = rg * 32 + rt * 16;
  unsigned bk = 0;

  ((float*)sm.hm)[tid] = 0.f;
  ((float*)sm.hm)[tid + 256] = 0.f;

  if (isL0) {
    load_w<128>(sm.wA, A.whh0, j);
    load_w<64>(sm.wB, A.wih0, j);
    if (tid < 48) {
      int gcol = (tid >> 4) * 1024 + j * 16 + (tid & 15);
      sm.bI[tid] = A.bih0[gcol];
      sm.bH[tid] = A.bhh0[gcol];
    }
  } else {
    load_w<128>(sm.wA, A.whh1, j);
    if (tid < 48) {
      int gcol = (tid >> 4) * 1024 + j * 16 + (tid & 15);
      sm.bI[tid] = A.bih1[gcol];
      sm.bH[tid] = A.bhh1[gcol];
    }
  }
  __syncthreads();

  f16x8 xf[8];
  if (isL0) {
    const f16* xp = A.x16 + ((size_t)0 * 64 + rowbase + lr) * 512 + kh * 256 + lk;
#pragma unroll
    for (int q2 = 0; q2 < 8; ++q2) xf[q2] = *(const f16x8*)(xp + q2 * 32);
  }

  for (int s = 0; s <= 1024; ++s) {
    if (isL0) {
      if (s < 1024) {
        const int t = s;
        // h0(t-1) lives in ring slot (t+1)&1 (zeros at t=0 via memset)
        const f16* hp = A.h0 + ((size_t)((t + 1) & 1) * 64 + rowbase + lr) * 1024 + kh * 512 + lk;
        f32x4 a0 = {0.f, 0.f, 0.f, 0.f}, a1 = a0, a2 = a0, a3 = a0;
#pragma unroll
        for (int q2 = 0; q2 < 8; ++q2) {
          const int u8 = (kh * 8 + q2) * 4 + lk8;
          a0 = mf(xf[q2], ldb<64>(sm.wB, lr, u8), a0);
          a1 = mf(xf[q2], ldb<64>(sm.wB, 16 + lr, u8), a1);
          a2 = mf(xf[q2], ldb<64>(sm.wB, 32 + lr, u8), a2);  // i_n
        }
        // h-part: coherent loads chunked 4 fragments at a time (VGPR diet)
#pragma unroll
        for (int c4 = 0; c4 < 4; ++c4) {
          f16x8 h4[4];
#pragma unroll
          for (int u = 0; u < 4; ++u) h4[u] = ld8c(hp + (c4 * 4 + u) * 32);
#pragma unroll
          for (int u = 0; u < 4; ++u) {
            const int q2 = c4 * 4 + u;
            const int u8 = (kh * 16 + q2) * 4 + lk8;
            a0 = mf(h4[u], ldb<128>(sm.wA, lr, u8), a0);
            a1 = mf(h4[u], ldb<128>(sm.wA, 16 + lr, u8), a1);
            a3 = mf(h4[u], ldb<128>(sm.wA, 32 + lr, u8), a3);  // h_n
          }
        }
        if (t + 1 < 1024) {  // prefetch next x (cached loads, latency off crit path)
          const f16* xp = A.x16 + ((size_t)(t + 1) * 64 + rowbase + lr) * 512 + kh * 256 + lk;
#pragma unroll
          for (int q2 = 0; q2 < 8; ++q2) xf[q2] = *(const f16x8*)(xp + q2 * 32);
        }
        if (kh) {
#pragma unroll
          for (int q = 0; q < 4; ++q) {
            sm.sc[rt][0][q][lane] = a0[q]; sm.sc[rt][1][q][lane] = a1[q];
            sm.sc[rt][2][q][lane] = a2[q]; sm.sc[rt][3][q][lane] = a3[q];
          }
        }
        __syncthreads();
        if (!kh) {
          float hn4[4];
#pragma unroll
          for (int q = 0; q < 4; ++q) {
            a0[q] += sm.sc[rt][0][q][lane]; a1[q] += sm.sc[rt][1][q][lane];
            a2[q] += sm.sc[rt][2][q][lane]; a3[q] += sm.sc[rt][3][q][lane];
          }
#pragma unroll
          for (int q = 0; q < 4; ++q) {
            const int row = rt * 16 + dr + q;
            float r = sigf(a0[q] + sm.bI[lr] + sm.bH[lr]);
            float z = sigf(a1[q] + sm.bI[16 + lr] + sm.bH[16 + lr]);
            float n = tanh_fast(a2[q] + sm.bI[32 + lr] + r * (a3[q] + sm.bH[32 + lr]));
            float hn = n + z * (sm.hm[row][lr] - n);
            sm.hm[row][lr] = hn;
            hn4[q] = hn;
          }
          u64 w = pack4(hn4, lr);
          const int srow = rt * 16 + dr + (lr & 3);
          axch8(A.h0 + ((size_t)((t & 1) * 64 + rg * 32 + srow)) * 1024 + j * 16 + (lr & ~3), w);
        }
      }
    } else if (s >= 1) {
      const int t = s - 1;
      const f16* gp = A.h0 + ((size_t)(t & 1) * 64 + rowbase + lr) * 1024 + kh * 512 + lk;
      const f16* hp = A.h1 + ((size_t)((t + 1) & 1) * 64 + rowbase + lr) * 1024 + kh * 512 + lk;
      f32x4 a0 = {0.f, 0.f, 0.f, 0.f}, a1 = a0, a2 = a0, a3 = a0;
      const f16* wb = A.wih1 + ((size_t)(j * 16 + lr)) * 1024 + kh * 512 + lk;
      // gi1 part: h0(t) coherent, wih1 streamed from L2; chunked 4 frags
#pragma unroll
      for (int c4 = 0; c4 < 4; ++c4) {
        f16x8 g4[4];
#pragma unroll
        for (int u = 0; u < 4; ++u) g4[u] = ld8c(gp + (c4 * 4 + u) * 32);
#pragma unroll
        for (int u = 0; u < 4; ++u) {
          const size_t o = (size_t)(c4 * 4 + u) * 32;
          a0 = mf(g4[u], *(const f16x8*)(wb + o), a0);
          a1 = mf(g4[u], *(const f16x8*)(wb + (size_t)1024 * 1024 + o), a1);
          a2 = mf(g4[u], *(const f16x8*)(wb + (size_t)2048 * 1024 + o), a2);  // i_n
        }
      }
      // recurrent part: h1(t-1) coherent, whh1 in LDS; chunked 4 frags
#pragma unroll
      for (int c4 = 0; c4 < 4; ++c4) {
        f16x8 h4[4];
#pragma unroll
        for (int u = 0; u < 4; ++u) h4[u] = ld8c(hp + (c4 * 4 + u) * 32);
#pragma unroll
        for (int u = 0; u < 4; ++u) {
          const int q2 = c4 * 4 + u;
          const int u8 = (kh * 16 + q2) * 4 + lk8;
          a0 = mf(h4[u], ldb<128>(sm.wA, lr, u8), a0);
          a1 = mf(h4[u], ldb<128>(sm.wA, 16 + lr, u8), a1);
          a3 = mf(h4[u], ldb<128>(sm.wA, 32 + lr, u8), a3);  // h_n
        }
      }
      if (kh) {
#pragma unroll
        for (int q = 0; q < 4; ++q) {
          sm.sc[rt][0][q][lane] = a0[q]; sm.sc[rt][1][q][lane] = a1[q];
          sm.sc[rt][2][q][lane] = a2[q]; sm.sc[rt][3][q][lane] = a3[q];
        }
      }
      __syncthreads();
      if (!kh) {
        float hn4[4];
#pragma unroll
        for (int q = 0; q < 4; ++q) {
          a0[q] += sm.sc[rt][0][q][lane]; a1[q] += sm.sc[rt][1][q][lane];
          a2[q] += sm.sc[rt][2][q][lane]; a3[q] += sm.sc[rt][3][q][lane];
        }
#pragma unroll
        for (int q = 0; q < 4; ++q) {
          const int row = rt * 16 + dr + q;
          float r = sigf(a0[q] + sm.bI[lr] + sm.bH[lr]);
          float z = sigf(a1[q] + sm.bI[16 + lr] + sm.bH[16 + lr]);
          float n = tanh_fast(a2[q] + sm.bI[32 + lr] + r * (a3[q] + sm.bH[32 + lr]));
          float hn = n + z * (sm.hm[row][lr] - n);
          sm.hm[row][lr] = hn;
          hn4[q] = hn;
        }
        u64 w = pack4(hn4, lr);
        const int srow = rt * 16 + dr + (lr & 3);
        axch8(A.h1 + ((size_t)((t & 1) * 64 + rg * 32 + srow)) * 1024 + j * 16 + (lr & ~3), w);
      }
    }
    gbar(A.bar, ++bk);
  }

  // ---- output projection: out = h1(1023) @ w_out^T + b_out (h1 ring slot 1) ----
  // Must read h1 via the coherent path (caches were never invalidated).
  if (!isL0) {
    const int g = wg - 128;
    const int j2 = g & 31, rg2 = g >> 5;
    f32x4 acc = {0.f, 0.f, 0.f, 0.f};
    if (wave < 2) {
      const f16* Ah = A.h1 + ((size_t)64 + rg2 * 16 + lr) * 1024 + wave * 512 + lk;
      const f16* Bp = A.wout + ((size_t)(j2 * 16 + lr)) * 1024 + wave * 512 + lk;
#pragma unroll
      for (int c4 = 0; c4 < 4; ++c4) {
        f16x8 h4[4];
#pragma unroll
        for (int u = 0; u < 4; ++u) h4[u] = ld8c(Ah + (c4 * 4 + u) * 32);
#pragma unroll
        for (int u = 0; u < 4; ++u)
          acc = mf(h4[u], *(const f16x8*)(Bp + (c4 * 4 + u) * 32), acc);
      }
    }
    if (wave == 1) {
#pragma unroll
      for (int q = 0; q < 4; ++q) sm.sc[0][0][q][lane] = acc[q];
    }
    __syncthreads();
    if (wave == 0) {
#pragma unroll
      for (int q = 0; q < 4; ++q) {
        float v = acc[q] + sm.sc[0][0][q][lane] + A.bout[j2 * 16 + lr];
        A.out[(rg2 * 16 + dr + q) * 512 + j2 * 16 + lr] = v;
      }
    }
  }
}

// ---------------- host ----------------

extern "C" void kernel_launch(void* const* d_in, const int* in_sizes, int n_in,
                              void* d_out, int out_size, void* d_ws, size_t ws_size,
                              hipStream_t stream) {
  (void)in_sizes; (void)n_in; (void)out_size; (void)ws_size;
  const float* x = (const float*)d_in[0];
  const float* w_ih0 = (const float*)d_in[1];
  const float* w_hh0 = (const float*)d_in[2];
  const float* b_ih0 = (const float*)d_in[3];
  const float* b_hh0 = (const float*)d_in[4];
  const float* w_ih1 = (const float*)d_in[5];
  const float* w_hh1 = (const float*)d_in[6];
  const float* b_ih1 = (const float*)d_in[7];
  const float* b_hh1 = (const float*)d_in[8];
  const float* w_out = (const float*)d_in[9];
  const float* b_out = (const float*)d_in[10];

  char* ws = (char*)d_ws;
  size_t off = 0;
  auto alloc = [&](size_t b) {
    off = (off + 255) & ~(size_t)255;
    char* p = ws + off;
    off += b;
    return p;
  };

  float* pe = (float*)alloc((size_t)1024 * 512 * 4);
  f16* x16 = (f16*)alloc((size_t)1024 * 64 * 512 * 2);
  f16* wih0 = (f16*)alloc((size_t)3072 * 512 * 2);
  f16* whh0 = (f16*)alloc((size_t)3072 * 1024 * 2);
  f16* wih1 = (f16*)alloc((size_t)3072 * 1024 * 2);
  f16* whh1 = (f16*)alloc((size_t)3072 * 1024 * 2);
  f16* wout = (f16*)alloc((size_t)512 * 1024 * 2);
  f16* h0r = (f16*)alloc((size_t)2 * 64 * 1024 * 2);
  f16* h1r = (f16*)alloc((size_t)2 * 64 * 1024 * 2);
  unsigned* bar = (unsigned*)alloc(1024);

  (void)hipMemsetAsync(bar, 0, 1024, stream);
  (void)hipMemsetAsync(h0r, 0, (size_t)2 * 64 * 1024 * 2, stream);
  (void)hipMemsetAsync(h1r, 0, (size_t)2 * 64 * 1024 * 2, stream);

  gru_k_pe<<<(1024 * 512 + 255) / 256, 256, 0, stream>>>(pe);
  gru_k_x16<<<dim3(2, 1024, 64), 256, 0, stream>>>(x, pe, x16);
  gru_k_f16<<<(3072 * 512 + 255) / 256, 256, 0, stream>>>(w_ih0, wih0, 3072 * 512);
  gru_k_f16<<<(3072 * 1024 + 255) / 256, 256, 0, stream>>>(w_hh0, whh0, 3072 * 1024);
  gru_k_f16<<<(3072 * 1024 + 255) / 256, 256, 0, stream>>>(w_ih1, wih1, 3072 * 1024);
  gru_k_f16<<<(3072 * 1024 + 255) / 256, 256, 0, stream>>>(w_hh1, whh1, 3072 * 1024);
  gru_k_f16<<<(512 * 1024 + 255) / 256, 256, 0, stream>>>(w_out, wout, 512 * 1024);

  gru::Args A;
  A.x16 = x16;
  A.bih0 = b_ih0; A.bhh0 = b_hh0; A.bih1 = b_ih1; A.bhh1 = b_hh1; A.bout = b_out;
  A.wih0 = wih0; A.whh0 = whh0; A.wih1 = wih1; A.whh1 = whh1; A.wout = wout;
  A.h0 = h0r; A.h1 = h1r;
  A.out = (float*)d_out;
  A.bar = bar;

  // Plain launch: 256 blocks x 1 block/CU (LDS-bound) on 256 CUs -> co-resident.
  gru_main<<<dim3(NWG), dim3(WGSZ), 0, stream>>>(A);
}

// Round 6
// 17244.028 us; speedup vs baseline: 2.4071x; 1.0141x over previous
//
#include <hip/hip_runtime.h>
#include <cstdint>
#include <cstddef>

typedef _Float16 f16;
typedef _Float16 f16x8 __attribute__((ext_vector_type(8)));
typedef float f32x4 __attribute__((ext_vector_type(4)));
typedef unsigned long long u64;

#define NWG 256
#define WGSZ 256

namespace gru {

__device__ inline f32x4 mf(f16x8 a, f16x8 b, f32x4 c) {
  return __builtin_amdgcn_mfma_f32_16x16x32_f16(a, b, c, 0, 0, 0);
}
__device__ inline float sigf(float x) { return 1.f / (1.f + __expf(-x)); }
__device__ inline float tanh_fast(float x) {
  float xx = fminf(fmaxf(x, -15.f), 15.f);
  float e = __expf(-2.f * xx);
  return (1.f - e) / (1.f + e);
}

struct SMem {
  f16 wA[48 * 1024];      // 96 KB: whh0 (L0) or whh1 (L1), swizzled
  f16 wB[48 * 512];       // 48 KB: wih0 (L0 only), swizzled
  float sc[2][4][4][64];  // 8 KB pairwise-reduce scratch
  float hm[32][16];       // fp32 master h tile (this WG's 32 rows x 16 cols)
  float bI[48], bH[48];
};

struct Args {
  const f16* x16;
  const float* bih0; const float* bhh0; const float* bih1; const float* bhh1; const float* bout;
  const f16* wih0; const f16* whh0; const f16* wih1; const f16* whh1; const f16* wout;
  f16* h0;   // ring [2][64][1024]
  f16* h1;   // ring [2][64][1024]
  float* out;
  unsigned* bar;  // leaves at [(bid&7)*16], root at [128]
};

// ---- coherent cross-XCD exchange: compiler-lowered agent-scope atomics only.
// Proven on HW (R5 pass): exchange-RMW writes + relaxed atomic-load reads.

__device__ inline u64 ald8(const f16* p) {
  return __hip_atomic_load((u64*)p, __ATOMIC_RELAXED, __HIP_MEMORY_SCOPE_AGENT);
}
__device__ inline f16x8 ld8c(const f16* p) {
  union { u64 u[2]; f16x8 v; } x;
  x.u[0] = ald8(p);
  x.u[1] = ald8(p + 4);
  return x.v;
}
__device__ inline void axch8(f16* p, u64 v) {
  (void)__hip_atomic_exchange((u64*)p, v, __ATOMIC_RELAXED, __HIP_MEMORY_SCOPE_AGENT);
}

// Pack this lane's 4 gate outputs (rows dr..dr+3 of col lr) into one u64 holding
// 4 adjacent cols of ONE row, via 2x shfl_xor across the 4-lane col-group.
// Lane with (lr&3)==q ends up owning row dr+q, cols (lr&~3)..+3.
__device__ inline u64 pack4(const float* hn4, int lr) {
  u64 w = 0;
#pragma unroll
  for (int q = 0; q < 4; ++q) {
    f16 h = (f16)hn4[q];
    unsigned own = (unsigned)__builtin_bit_cast(unsigned short, h);
    unsigned p1 = (unsigned)__shfl_xor((int)own, 1, 64);
    unsigned v32 = (lr & 1) ? ((own << 16) | p1) : (own | (p1 << 16));
    unsigned o2 = (unsigned)__shfl_xor((int)v32, 2, 64);
    u64 v64 = (lr & 2) ? (((u64)v32 << 32) | (u64)o2) : (((u64)o2 << 32) | (u64)v32);
    if ((lr & 3) == q) w = v64;
  }
  return w;
}

// 2-level grid barrier, ALL-RELAXED (no release -> no L2 writeback).
// Ordering: __syncthreads() makes the compiler drain vmcnt(0) per wave
// (exchange RMWs complete at the coherent point) BEFORE thread 0's leaf RMW;
// leaf->root is ordered by the data dependency on the returned value; readers
// issue data loads only after the spin-load observes the root -> branch-
// dependent, so loads can't start early.
__device__ inline void gbar(unsigned* bar, unsigned k) {
  __syncthreads();
  if (threadIdx.x == 0) {
    unsigned old = __hip_atomic_fetch_add(&bar[(blockIdx.x & 7) << 4], 1u,
                                          __ATOMIC_RELAXED, __HIP_MEMORY_SCOPE_AGENT);
    if ((old & 31u) == 31u)
      __hip_atomic_fetch_add(&bar[128], 1u, __ATOMIC_RELAXED, __HIP_MEMORY_SCOPE_AGENT);
    while (__hip_atomic_load(&bar[128], __ATOMIC_RELAXED, __HIP_MEMORY_SCOPE_AGENT) < k * 8u)
      __builtin_amdgcn_s_sleep(1);
  }
  __syncthreads();
}

// Load 48 gate-rows (triplet j) of W [3072][K8*8] into LDS, XOR-swizzled per 16B unit.
template <int K8>
__device__ void load_w(f16* dst, const f16* W, int j) {
  for (int u = threadIdx.x; u < 48 * K8; u += WGSZ) {
    int row = u / K8, k8 = u - row * K8;
    int gcol = (row >> 4) * 1024 + j * 16 + (row & 15);
    f16x8 v = *(const f16x8*)(W + (size_t)gcol * (size_t)(K8 * 8) + (size_t)k8 * 8);
    *(f16x8*)(dst + ((size_t)row * K8 + (size_t)(k8 ^ (row & 7))) * 8) = v;
  }
}

template <int K8>
__device__ inline f16x8 ldb(const f16* base, int row, int u8) {
  return *(const f16x8*)(base + ((size_t)row * K8 + (size_t)(u8 ^ (row & 7))) * 8);
}

}  // namespace gru

// ---------------- prep kernels ----------------

__global__ void gru_k_pe(float* pe) {
  int idx = blockIdx.x * 256 + threadIdx.x;
  if (idx >= 1024 * 512) return;
  int t = idx >> 9, d = idx & 511;
  int jj = d >> 1;
  float freq = expf(-logf(10000.f) * (float)(2 * jj) * (1.f / 512.f));
  float ang = (float)t * freq;
  pe[idx] = (d & 1) ? cosf(ang) : sinf(ang);
}

__global__ void gru_k_x16(const float* __restrict__ x, const float* __restrict__ pe,
                          f16* __restrict__ x16) {
  int d = blockIdx.x * 256 + threadIdx.x;  // grid.x = 2
  int t = blockIdx.y, b = blockIdx.z;
  float v = x[((size_t)b * 1024 + t) * 512 + d] + pe[t * 512 + d];
  x16[((size_t)t * 64 + b) * 512 + d] = (f16)v;
}

__global__ void gru_k_f16(const float* __restrict__ src, f16* __restrict__ dst, int n) {
  int i = blockIdx.x * 256 + threadIdx.x;
  if (i < n) dst[i] = (f16)src[i];
}

// ---------------- main persistent pipelined kernel ----------------
// PLAIN (non-cooperative) launch: 256 blocks x 154KB LDS = 1 block/CU on
// 256 CUs -> co-resident by construction (cooperative launch silently failed).
// WGs 0..127: layer-0 at step t=s.  WGs 128..255: layer-1 at t=s-1 (skew 1).
// ALL coherent loads of a step are issued as one batch -> one MALL round-trip
// of latency per step instead of 8 chunked ones (the R5 17us/step killer).

__global__ __launch_bounds__(WGSZ, 1) void gru_main(gru::Args A) {
  using namespace gru;
  __shared__ SMem sm;
  const int wg = blockIdx.x, tid = threadIdx.x;
  const bool isL0 = wg < 128;
  const int j = wg & 63, rg = (wg >> 6) & 1;
  const int wave = tid >> 6, lane = tid & 63;
  const int lr = lane & 15, lk8 = lane >> 4;
  const int lk = lk8 * 8, dr = lk8 * 4;
  const int rt = wave >> 1, kh = wave & 1;  // rowtile, K-half per wave
  const int rowbase = rg * 32 + rt * 16;
  unsigned bk = 0;

  ((float*)sm.hm)[tid] = 0.f;
  ((float*)sm.hm)[tid + 256] = 0.f;

  if (isL0) {
    load_w<128>(sm.wA, A.whh0, j);
    load_w<64>(sm.wB, A.wih0, j);
    if (tid < 48) {
      int gcol = (tid >> 4) * 1024 + j * 16 + (tid & 15);
      sm.bI[tid] = A.bih0[gcol];
      sm.bH[tid] = A.bhh0[gcol];
    }
  } else {
    load_w<128>(sm.wA, A.whh1, j);
    if (tid < 48) {
      int gcol = (tid >> 4) * 1024 + j * 16 + (tid & 15);
      sm.bI[tid] = A.bih1[gcol];
      sm.bH[tid] = A.bhh1[gcol];
    }
  }
  __syncthreads();

  f16x8 xf[8];
  if (isL0) {
    const f16* xp = A.x16 + ((size_t)0 * 64 + rowbase + lr) * 512 + kh * 256 + lk;
#pragma unroll
    for (int q2 = 0; q2 < 8; ++q2) xf[q2] = *(const f16x8*)(xp + q2 * 32);
  }

  for (int s = 0; s <= 1024; ++s) {
    if (isL0) {
      if (s < 1024) {
        const int t = s;
        // h0(t-1) lives in ring slot (t+1)&1 (zeros at t=0 via memset)
        const f16* hp = A.h0 + ((size_t)((t + 1) & 1) * 64 + rowbase + lr) * 1024 + kh * 512 + lk;
        // ---- batch-issue ALL coherent loads (32 u64), then compute ----
        f16x8 hf[16];
#pragma unroll
        for (int q2 = 0; q2 < 16; ++q2) hf[q2] = ld8c(hp + q2 * 32);
        f32x4 a0 = {0.f, 0.f, 0.f, 0.f}, a1 = a0, a2 = a0, a3 = a0;
#pragma unroll
        for (int q2 = 0; q2 < 8; ++q2) {
          const int u8 = (kh * 8 + q2) * 4 + lk8;
          a0 = mf(xf[q2], ldb<64>(sm.wB, lr, u8), a0);
          a1 = mf(xf[q2], ldb<64>(sm.wB, 16 + lr, u8), a1);
          a2 = mf(xf[q2], ldb<64>(sm.wB, 32 + lr, u8), a2);  // i_n
        }
#pragma unroll
        for (int q2 = 0; q2 < 16; ++q2) {
          const int u8 = (kh * 16 + q2) * 4 + lk8;
          a0 = mf(hf[q2], ldb<128>(sm.wA, lr, u8), a0);
          a1 = mf(hf[q2], ldb<128>(sm.wA, 16 + lr, u8), a1);
          a3 = mf(hf[q2], ldb<128>(sm.wA, 32 + lr, u8), a3);  // h_n
        }
        if (t + 1 < 1024) {  // prefetch next x (cached loads, latency off crit path)
          const f16* xp = A.x16 + ((size_t)(t + 1) * 64 + rowbase + lr) * 512 + kh * 256 + lk;
#pragma unroll
          for (int q2 = 0; q2 < 8; ++q2) xf[q2] = *(const f16x8*)(xp + q2 * 32);
        }
        if (kh) {
#pragma unroll
          for (int q = 0; q < 4; ++q) {
            sm.sc[rt][0][q][lane] = a0[q]; sm.sc[rt][1][q][lane] = a1[q];
            sm.sc[rt][2][q][lane] = a2[q]; sm.sc[rt][3][q][lane] = a3[q];
          }
        }
        __syncthreads();
        if (!kh) {
          float hn4[4];
#pragma unroll
          for (int q = 0; q < 4; ++q) {
            a0[q] += sm.sc[rt][0][q][lane]; a1[q] += sm.sc[rt][1][q][lane];
            a2[q] += sm.sc[rt][2][q][lane]; a3[q] += sm.sc[rt][3][q][lane];
          }
#pragma unroll
          for (int q = 0; q < 4; ++q) {
            const int row = rt * 16 + dr + q;
            float r = sigf(a0[q] + sm.bI[lr] + sm.bH[lr]);
            float z = sigf(a1[q] + sm.bI[16 + lr] + sm.bH[16 + lr]);
            float n = tanh_fast(a2[q] + sm.bI[32 + lr] + r * (a3[q] + sm.bH[32 + lr]));
            float hn = n + z * (sm.hm[row][lr] - n);
            sm.hm[row][lr] = hn;
            hn4[q] = hn;
          }
          u64 w = pack4(hn4, lr);
          const int srow = rt * 16 + dr + (lr & 3);
          axch8(A.h0 + ((size_t)((t & 1) * 64 + rg * 32 + srow)) * 1024 + j * 16 + (lr & ~3), w);
        }
      }
    } else if (s >= 1) {
      const int t = s - 1;
      const f16* gp = A.h0 + ((size_t)(t & 1) * 64 + rowbase + lr) * 1024 + kh * 512 + lk;
      const f16* hp = A.h1 + ((size_t)((t + 1) & 1) * 64 + rowbase + lr) * 1024 + kh * 512 + lk;
      // ---- batch-issue ALL coherent loads (64 u64), then compute ----
      f16x8 gf[16], hf[16];
#pragma unroll
      for (int q2 = 0; q2 < 16; ++q2) gf[q2] = ld8c(gp + q2 * 32);
#pragma unroll
      for (int q2 = 0; q2 < 16; ++q2) hf[q2] = ld8c(hp + q2 * 32);
      f32x4 a0 = {0.f, 0.f, 0.f, 0.f}, a1 = a0, a2 = a0, a3 = a0;
      const f16* wb = A.wih1 + ((size_t)(j * 16 + lr)) * 1024 + kh * 512 + lk;
#pragma unroll
      for (int q2 = 0; q2 < 16; ++q2) {
        const size_t o = (size_t)q2 * 32;
        a0 = mf(gf[q2], *(const f16x8*)(wb + o), a0);
        a1 = mf(gf[q2], *(const f16x8*)(wb + (size_t)1024 * 1024 + o), a1);
        a2 = mf(gf[q2], *(const f16x8*)(wb + (size_t)2048 * 1024 + o), a2);  // i_n
      }
#pragma unroll
      for (int q2 = 0; q2 < 16; ++q2) {
        const int u8 = (kh * 16 + q2) * 4 + lk8;
        a0 = mf(hf[q2], ldb<128>(sm.wA, lr, u8), a0);
        a1 = mf(hf[q2], ldb<128>(sm.wA, 16 + lr, u8), a1);
        a3 = mf(hf[q2], ldb<128>(sm.wA, 32 + lr, u8), a3);  // h_n
      }
      if (kh) {
#pragma unroll
        for (int q = 0; q < 4; ++q) {
          sm.sc[rt][0][q][lane] = a0[q]; sm.sc[rt][1][q][lane] = a1[q];
          sm.sc[rt][2][q][lane] = a2[q]; sm.sc[rt][3][q][lane] = a3[q];
        }
      }
      __syncthreads();
      if (!kh) {
        float hn4[4];
#pragma unroll
        for (int q = 0; q < 4; ++q) {
          a0[q] += sm.sc[rt][0][q][lane]; a1[q] += sm.sc[rt][1][q][lane];
          a2[q] += sm.sc[rt][2][q][lane]; a3[q] += sm.sc[rt][3][q][lane];
        }
#pragma unroll
        for (int q = 0; q < 4; ++q) {
          const int row = rt * 16 + dr + q;
          float r = sigf(a0[q] + sm.bI[lr] + sm.bH[lr]);
          float z = sigf(a1[q] + sm.bI[16 + lr] + sm.bH[16 + lr]);
          float n = tanh_fast(a2[q] + sm.bI[32 + lr] + r * (a3[q] + sm.bH[32 + lr]));
          float hn = n + z * (sm.hm[row][lr] - n);
          sm.hm[row][lr] = hn;
          hn4[q] = hn;
        }
        u64 w = pack4(hn4, lr);
        const int srow = rt * 16 + dr + (lr & 3);
        axch8(A.h1 + ((size_t)((t & 1) * 64 + rg * 32 + srow)) * 1024 + j * 16 + (lr & ~3), w);
      }
    }
    gbar(A.bar, ++bk);
  }

  // ---- output projection: out = h1(1023) @ w_out^T + b_out (h1 ring slot 1) ----
  // Must read h1 via the coherent path (caches were never invalidated).
  if (!isL0) {
    const int g = wg - 128;
    const int j2 = g & 31, rg2 = g >> 5;
    f32x4 acc = {0.f, 0.f, 0.f, 0.f};
    if (wave < 2) {
      const f16* Ah = A.h1 + ((size_t)64 + rg2 * 16 + lr) * 1024 + wave * 512 + lk;
      const f16* Bp = A.wout + ((size_t)(j2 * 16 + lr)) * 1024 + wave * 512 + lk;
      f16x8 hf[16];
#pragma unroll
      for (int q2 = 0; q2 < 16; ++q2) hf[q2] = ld8c(Ah + q2 * 32);
#pragma unroll
      for (int q2 = 0; q2 < 16; ++q2)
        acc = mf(hf[q2], *(const f16x8*)(Bp + q2 * 32), acc);
    }
    if (wave == 1) {
#pragma unroll
      for (int q = 0; q < 4; ++q) sm.sc[0][0][q][lane] = acc[q];
    }
    __syncthreads();
    if (wave == 0) {
#pragma unroll
      for (int q = 0; q < 4; ++q) {
        float v = acc[q] + sm.sc[0][0][q][lane] + A.bout[j2 * 16 + lr];
        A.out[(rg2 * 16 + dr + q) * 512 + j2 * 16 + lr] = v;
      }
    }
  }
}

// ---------------- host ----------------

extern "C" void kernel_launch(void* const* d_in, const int* in_sizes, int n_in,
                              void* d_out, int out_size, void* d_ws, size_t ws_size,
                              hipStream_t stream) {
  (void)in_sizes; (void)n_in; (void)out_size; (void)ws_size;
  const float* x = (const float*)d_in[0];
  const float* w_ih0 = (const float*)d_in[1];
  const float* w_hh0 = (const float*)d_in[2];
  const float* b_ih0 = (const float*)d_in[3];
  const float* b_hh0 = (const float*)d_in[4];
  const float* w_ih1 = (const float*)d_in[5];
  const float* w_hh1 = (const float*)d_in[6];
  const float* b_ih1 = (const float*)d_in[7];
  const float* b_hh1 = (const float*)d_in[8];
  const float* w_out = (const float*)d_in[9];
  const float* b_out = (const float*)d_in[10];

  char* ws = (char*)d_ws;
  size_t off = 0;
  auto alloc = [&](size_t b) {
    off = (off + 255) & ~(size_t)255;
    char* p = ws + off;
    off += b;
    return p;
  };

  float* pe = (float*)alloc((size_t)1024 * 512 * 4);
  f16* x16 = (f16*)alloc((size_t)1024 * 64 * 512 * 2);
  f16* wih0 = (f16*)alloc((size_t)3072 * 512 * 2);
  f16* whh0 = (f16*)alloc((size_t)3072 * 1024 * 2);
  f16* wih1 = (f16*)alloc((size_t)3072 * 1024 * 2);
  f16* whh1 = (f16*)alloc((size_t)3072 * 1024 * 2);
  f16* wout = (f16*)alloc((size_t)512 * 1024 * 2);
  f16* h0r = (f16*)alloc((size_t)2 * 64 * 1024 * 2);
  f16* h1r = (f16*)alloc((size_t)2 * 64 * 1024 * 2);
  unsigned* bar = (unsigned*)alloc(1024);

  (void)hipMemsetAsync(bar, 0, 1024, stream);
  (void)hipMemsetAsync(h0r, 0, (size_t)2 * 64 * 1024 * 2, stream);
  (void)hipMemsetAsync(h1r, 0, (size_t)2 * 64 * 1024 * 2, stream);

  gru_k_pe<<<(1024 * 512 + 255) / 256, 256, 0, stream>>>(pe);
  gru_k_x16<<<dim3(2, 1024, 64), 256, 0, stream>>>(x, pe, x16);
  gru_k_f16<<<(3072 * 512 + 255) / 256, 256, 0, stream>>>(w_ih0, wih0, 3072 * 512);
  gru_k_f16<<<(3072 * 1024 + 255) / 256, 256, 0, stream>>>(w_hh0, whh0, 3072 * 1024);
  gru_k_f16<<<(3072 * 1024 + 255) / 256, 256, 0, stream>>>(w_ih1, wih1, 3072 * 1024);
  gru_k_f16<<<(3072 * 1024 + 255) / 256, 256, 0, stream>>>(w_hh1, whh1, 3072 * 1024);
  gru_k_f16<<<(512 * 1024 + 255) / 256, 256, 0, stream>>>(w_out, wout, 512 * 1024);

  gru::Args A;
  A.x16 = x16;
  A.bih0 = b_ih0; A.bhh0 = b_hh0; A.bih1 = b_ih1; A.bhh1 = b_hh1; A.bout = b_out;
  A.wih0 = wih0; A.whh0 = whh0; A.wih1 = wih1; A.whh1 = whh1; A.wout = wout;
  A.h0 = h0r; A.h1 = h1r;
  A.out = (float*)d_out;
  A.bar = bar;

  // Plain launch: 256 blocks x 1 block/CU (LDS-bound) on 256 CUs -> co-resident.
  gru_main<<<dim3(NWG), dim3(WGSZ), 0, stream>>>(A);
}

// Round 7
// 12974.878 us; speedup vs baseline: 3.1991x; 1.3290x over previous
//
#include <hip/hip_runtime.h>
#include <cstdint>
#include <cstddef>

typedef _Float16 f16;
typedef _Float16 f16x8 __attribute__((ext_vector_type(8)));
typedef float f32x4 __attribute__((ext_vector_type(4)));
typedef unsigned long long u64;

#define NWG 256
#define WGSZ 256
#define RING 64   // h-ring depth (slots); addr reuse every RING steps
#define INVP 48   // own-step period of L1/L2 invalidate; must be < RING

namespace gru {

__device__ inline f32x4 mf(f16x8 a, f16x8 b, f32x4 c) {
  return __builtin_amdgcn_mfma_f32_16x16x32_f16(a, b, c, 0, 0, 0);
}
__device__ inline float sigf(float x) { return 1.f / (1.f + __expf(-x)); }
__device__ inline float tanh_fast(float x) {
  float xx = fminf(fmaxf(x, -15.f), 15.f);
  float e = __expf(-2.f * xx);
  return (1.f - e) / (1.f + e);
}

struct SMem {
  f16 wA[48 * 1024];      // 96 KB: whh0 (L0) or whh1 (L1), swizzled
  f16 wB[48 * 512];       // 48 KB: wih0 (L0 only), swizzled
  float sc[2][4][4][64];  // 8 KB pairwise-reduce scratch
  float hm[32][16];       // fp32 master h tile (this WG's 32 rows x 16 cols)
  float bI[48], bH[48];
};

struct Args {
  const f16* x16;
  const float* bih0; const float* bhh0; const float* bih1; const float* bhh1; const float* bout;
  const f16* wih0; const f16* whh0; const f16* wih1; const f16* whh1; const f16* wout;
  f16* h0;   // ring [RING][64][1024]
  f16* h1;   // ring [RING][64][1024]
  float* out;
  unsigned* flg;  // leaf0[l] = flg[l*32]; leaf1[l] = flg[256 + l*32]; l<8, 16 WGs/leaf
};

// ---- flags: monotonic per-side leaf counters (agent-scope atomics, proven) ----

__device__ inline unsigned aldu(const unsigned* p) {
  return __hip_atomic_load(p, __ATOMIC_RELAXED, __HIP_MEMORY_SCOPE_AGENT);
}
__device__ inline void bump(unsigned* p) {
  (void)__hip_atomic_fetch_add(p, 1u, __ATOMIC_RELAXED, __HIP_MEMORY_SCOPE_AGENT);
}
// Spin until min(leaves f0) >= t0 AND min(leaves f1) >= t1. 16 independent
// atomic loads per poll round -> ~one MALL round-trip per poll.
__device__ inline void wait2(const unsigned* f0, unsigned t0, const unsigned* f1, unsigned t1) {
  for (;;) {
    unsigned m0 = 0xffffffffu, m1 = 0xffffffffu;
#pragma unroll
    for (int l = 0; l < 8; ++l) m0 = min(m0, aldu(f0 + l * 32));
#pragma unroll
    for (int l = 0; l < 8; ++l) m1 = min(m1, aldu(f1 + l * 32));
    if (m0 >= t0 && m1 >= t1) return;
    __builtin_amdgcn_s_sleep(1);
  }
}

// ---- h writes: atomic-exchange write-through to the coherent point (proven R5/R6) ----
__device__ inline void axch8(f16* p, u64 v) {
  (void)__hip_atomic_exchange((u64*)p, v, __ATOMIC_RELAXED, __HIP_MEMORY_SCOPE_AGENT);
}

// Pack this lane's 4 gate outputs (rows dr..dr+3 of col lr) into one u64 holding
// 4 adjacent cols of ONE row, via 2x shfl_xor across the 4-lane col-group.
__device__ inline u64 pack4(const float* hn4, int lr) {
  u64 w = 0;
#pragma unroll
  for (int q = 0; q < 4; ++q) {
    f16 h = (f16)hn4[q];
    unsigned own = (unsigned)__builtin_bit_cast(unsigned short, h);
    unsigned p1 = (unsigned)__shfl_xor((int)own, 1, 64);
    unsigned v32 = (lr & 1) ? ((own << 16) | p1) : (own | (p1 << 16));
    unsigned o2 = (unsigned)__shfl_xor((int)v32, 2, 64);
    u64 v64 = (lr & 2) ? (((u64)v32 << 32) | (u64)o2) : (((u64)o2 << 32) | (u64)v32);
    if ((lr & 3) == q) w = v64;
  }
  return w;
}

// Load 48 gate-rows (triplet j) of W [3072][K8*8] into LDS, XOR-swizzled per 16B unit.
template <int K8>
__device__ void load_w(f16* dst, const f16* W, int j) {
  for (int u = threadIdx.x; u < 48 * K8; u += WGSZ) {
    int row = u / K8, k8 = u - row * K8;
    int gcol = (row >> 4) * 1024 + j * 16 + (row & 15);
    f16x8 v = *(const f16x8*)(W + (size_t)gcol * (size_t)(K8 * 8) + (size_t)k8 * 8);
    *(f16x8*)(dst + ((size_t)row * K8 + (size_t)(k8 ^ (row & 7))) * 8) = v;
  }
}

template <int K8>
__device__ inline f16x8 ldb(const f16* base, int row, int u8) {
  return *(const f16x8*)(base + ((size_t)row * K8 + (size_t)(u8 ^ (row & 7))) * 8);
}

}  // namespace gru

// ---------------- prep kernels ----------------

__global__ void gru_k_pe(float* pe) {
  int idx = blockIdx.x * 256 + threadIdx.x;
  if (idx >= 1024 * 512) return;
  int t = idx >> 9, d = idx & 511;
  int jj = d >> 1;
  float freq = expf(-logf(10000.f) * (float)(2 * jj) * (1.f / 512.f));
  float ang = (float)t * freq;
  pe[idx] = (d & 1) ? cosf(ang) : sinf(ang);
}

__global__ void gru_k_x16(const float* __restrict__ x, const float* __restrict__ pe,
                          f16* __restrict__ x16) {
  int d = blockIdx.x * 256 + threadIdx.x;  // grid.x = 2
  int t = blockIdx.y, b = blockIdx.z;
  float v = x[((size_t)b * 1024 + t) * 512 + d] + pe[t * 512 + d];
  x16[((size_t)t * 64 + b) * 512 + d] = (f16)v;
}

__global__ void gru_k_f16(const float* __restrict__ src, f16* __restrict__ dst, int n) {
  int i = blockIdx.x * 256 + threadIdx.x;
  if (i < n) dst[i] = (f16)src[i];
}

// ---------------- main persistent pipelined kernel ----------------
// Plain launch, 1 block/CU (LDS-bound). WGs 0..127: layer-0; 128..255: layer-1.
// No global barrier: per-side monotonic leaf flags. h rings are RING deep so
// readers use CACHED loads (64x cross-WG redundancy hits L1/L2); a periodic
// __threadfence (every INVP own steps, INVP < RING) wipes stale copies before
// any slot address is reused. Writes remain agent-scope atomic exchanges.

__global__ __launch_bounds__(WGSZ, 1) void gru_main(gru::Args A) {
  using namespace gru;
  __shared__ SMem sm;
  const int wg = blockIdx.x, tid = threadIdx.x;
  const bool isL0 = wg < 128;
  const int j = wg & 63, rg = (wg >> 6) & 1;
  const int wave = tid >> 6, lane = tid & 63;
  const int lr = lane & 15, lk8 = lane >> 4;
  const int lk = lk8 * 8, dr = lk8 * 4;
  const int rt = wave >> 1, kh = wave & 1;  // rowtile, K-half per wave
  const int rowbase = rg * 32 + rt * 16;

  ((float*)sm.hm)[tid] = 0.f;
  ((float*)sm.hm)[tid + 256] = 0.f;

  if (isL0) {
    load_w<128>(sm.wA, A.whh0, j);
    load_w<64>(sm.wB, A.wih0, j);
    if (tid < 48) {
      int gcol = (tid >> 4) * 1024 + j * 16 + (tid & 15);
      sm.bI[tid] = A.bih0[gcol];
      sm.bH[tid] = A.bhh0[gcol];
    }
  } else {
    load_w<128>(sm.wA, A.whh1, j);
    if (tid < 48) {
      int gcol = (tid >> 4) * 1024 + j * 16 + (tid & 15);
      sm.bI[tid] = A.bih1[gcol];
      sm.bH[tid] = A.bhh1[gcol];
    }
  }
  __syncthreads();

  if (isL0) {
    // =============== layer-0: free-running, throttled only by ring wrap ===============
    f16x8 xf[8];
    {
      const f16* xp = A.x16 + ((size_t)0 * 64 + rowbase + lr) * 512 + kh * 256 + lk;
#pragma unroll
      for (int q2 = 0; q2 < 8; ++q2) xf[q2] = *(const f16x8*)(xp + q2 * 32);
    }
    for (int t = 0; t < 1024; ++t) {
      if ((t % INVP) == INVP - 1) __threadfence();  // periodic L1/L2 invalidate
      if (tid == 0) {
        unsigned g0 = (t > 0) ? 16u * (unsigned)t : 0u;           // done0[t-1]
        unsigned g1 = (t >= 60) ? 16u * (unsigned)(t - 59) : 0u;  // ring-wrap guard
        wait2(A.flg, g0, A.flg + 256, g1);
      }
      __syncthreads();
      const f16* hp = A.h0 + ((size_t)((t + RING - 1) & (RING - 1)) * 64 + rowbase + lr) * 1024 + kh * 512 + lk;
      f16x8 hf[16];
#pragma unroll
      for (int q2 = 0; q2 < 16; ++q2) hf[q2] = *(const f16x8*)(hp + q2 * 32);  // CACHED
      f32x4 a0 = {0.f, 0.f, 0.f, 0.f}, a1 = a0, a2 = a0, a3 = a0;
#pragma unroll
      for (int q2 = 0; q2 < 8; ++q2) {
        const int u8 = (kh * 8 + q2) * 4 + lk8;
        a0 = mf(xf[q2], ldb<64>(sm.wB, lr, u8), a0);
        a1 = mf(xf[q2], ldb<64>(sm.wB, 16 + lr, u8), a1);
        a2 = mf(xf[q2], ldb<64>(sm.wB, 32 + lr, u8), a2);  // i_n
      }
#pragma unroll
      for (int q2 = 0; q2 < 16; ++q2) {
        const int u8 = (kh * 16 + q2) * 4 + lk8;
        a0 = mf(hf[q2], ldb<128>(sm.wA, lr, u8), a0);
        a1 = mf(hf[q2], ldb<128>(sm.wA, 16 + lr, u8), a1);
        a3 = mf(hf[q2], ldb<128>(sm.wA, 32 + lr, u8), a3);  // h_n
      }
      if (t + 1 < 1024) {  // prefetch next x (cached)
        const f16* xp = A.x16 + ((size_t)(t + 1) * 64 + rowbase + lr) * 512 + kh * 256 + lk;
#pragma unroll
        for (int q2 = 0; q2 < 8; ++q2) xf[q2] = *(const f16x8*)(xp + q2 * 32);
      }
      if (kh) {
#pragma unroll
        for (int q = 0; q < 4; ++q) {
          sm.sc[rt][0][q][lane] = a0[q]; sm.sc[rt][1][q][lane] = a1[q];
          sm.sc[rt][2][q][lane] = a2[q]; sm.sc[rt][3][q][lane] = a3[q];
        }
      }
      __syncthreads();
      if (!kh) {
        float hn4[4];
#pragma unroll
        for (int q = 0; q < 4; ++q) {
          a0[q] += sm.sc[rt][0][q][lane]; a1[q] += sm.sc[rt][1][q][lane];
          a2[q] += sm.sc[rt][2][q][lane]; a3[q] += sm.sc[rt][3][q][lane];
        }
#pragma unroll
        for (int q = 0; q < 4; ++q) {
          const int row = rt * 16 + dr + q;
          float r = sigf(a0[q] + sm.bI[lr] + sm.bH[lr]);
          float z = sigf(a1[q] + sm.bI[16 + lr] + sm.bH[16 + lr]);
          float n = tanh_fast(a2[q] + sm.bI[32 + lr] + r * (a3[q] + sm.bH[32 + lr]));
          float hn = n + z * (sm.hm[row][lr] - n);
          sm.hm[row][lr] = hn;
          hn4[q] = hn;
        }
        u64 w = pack4(hn4, lr);
        const int srow = rt * 16 + dr + (lr & 3);
        axch8(A.h0 + ((size_t)(t & (RING - 1)) * 64 + rg * 32 + srow) * 1024 + j * 16 + (lr & ~3), w);
      }
      __syncthreads();  // drains exchange RMWs (vmcnt) before the flag bump
      if (tid == 0) bump(A.flg + (wg & 7) * 32);
    }
  } else {
    // =============== layer-1: consumes h0(t), recurrent on h1(t-1) ===============
    for (int t = 0; t < 1024; ++t) {
      if ((t % INVP) == INVP - 1) __threadfence();
      if (tid == 0) {
        unsigned g0 = 16u * (unsigned)(t + 1);            // done0[t]
        unsigned g1 = (t > 0) ? 16u * (unsigned)t : 0u;   // done1[t-1]
        wait2(A.flg, g0, A.flg + 256, g1);
      }
      __syncthreads();
      const f16* gp = A.h0 + ((size_t)(t & (RING - 1)) * 64 + rowbase + lr) * 1024 + kh * 512 + lk;
      const f16* hp = A.h1 + ((size_t)((t + RING - 1) & (RING - 1)) * 64 + rowbase + lr) * 1024 + kh * 512 + lk;
      f16x8 gf[16], hf[16];
#pragma unroll
      for (int q2 = 0; q2 < 16; ++q2) gf[q2] = *(const f16x8*)(gp + q2 * 32);  // CACHED
#pragma unroll
      for (int q2 = 0; q2 < 16; ++q2) hf[q2] = *(const f16x8*)(hp + q2 * 32);  // CACHED
      f32x4 a0 = {0.f, 0.f, 0.f, 0.f}, a1 = a0, a2 = a0, a3 = a0;
      const f16* wb = A.wih1 + ((size_t)(j * 16 + lr)) * 1024 + kh * 512 + lk;
#pragma unroll
      for (int q2 = 0; q2 < 16; ++q2) {
        const size_t o = (size_t)q2 * 32;
        a0 = mf(gf[q2], *(const f16x8*)(wb + o), a0);
        a1 = mf(gf[q2], *(const f16x8*)(wb + (size_t)1024 * 1024 + o), a1);
        a2 = mf(gf[q2], *(const f16x8*)(wb + (size_t)2048 * 1024 + o), a2);  // i_n
      }
#pragma unroll
      for (int q2 = 0; q2 < 16; ++q2) {
        const int u8 = (kh * 16 + q2) * 4 + lk8;
        a0 = mf(hf[q2], ldb<128>(sm.wA, lr, u8), a0);
        a1 = mf(hf[q2], ldb<128>(sm.wA, 16 + lr, u8), a1);
        a3 = mf(hf[q2], ldb<128>(sm.wA, 32 + lr, u8), a3);  // h_n
      }
      if (kh) {
#pragma unroll
        for (int q = 0; q < 4; ++q) {
          sm.sc[rt][0][q][lane] = a0[q]; sm.sc[rt][1][q][lane] = a1[q];
          sm.sc[rt][2][q][lane] = a2[q]; sm.sc[rt][3][q][lane] = a3[q];
        }
      }
      __syncthreads();
      if (!kh) {
        float hn4[4];
#pragma unroll
        for (int q = 0; q < 4; ++q) {
          a0[q] += sm.sc[rt][0][q][lane]; a1[q] += sm.sc[rt][1][q][lane];
          a2[q] += sm.sc[rt][2][q][lane]; a3[q] += sm.sc[rt][3][q][lane];
        }
#pragma unroll
        for (int q = 0; q < 4; ++q) {
          const int row = rt * 16 + dr + q;
          float r = sigf(a0[q] + sm.bI[lr] + sm.bH[lr]);
          float z = sigf(a1[q] + sm.bI[16 + lr] + sm.bH[16 + lr]);
          float n = tanh_fast(a2[q] + sm.bI[32 + lr] + r * (a3[q] + sm.bH[32 + lr]));
          float hn = n + z * (sm.hm[row][lr] - n);
          sm.hm[row][lr] = hn;
          hn4[q] = hn;
        }
        u64 w = pack4(hn4, lr);
        const int srow = rt * 16 + dr + (lr & 3);
        axch8(A.h1 + ((size_t)(t & (RING - 1)) * 64 + rg * 32 + srow) * 1024 + j * 16 + (lr & ~3), w);
      }
      __syncthreads();
      if (tid == 0) bump(A.flg + 256 + (wg & 7) * 32);
    }

    // ---- output projection: out = h1(1023) @ w_out^T + b_out (ring slot 63) ----
    // Slot-63 lines were last cached at step 64 and wiped by the t=1007 inv;
    // not re-read since -> cached loads below fill fresh from the coherent point.
    if (tid == 0) wait2(A.flg + 256, 16u * 1024u, A.flg + 256, 16u * 1024u);
    __syncthreads();
    const int g = wg - 128;
    const int j2 = g & 31, rg2 = g >> 5;
    f32x4 acc = {0.f, 0.f, 0.f, 0.f};
    if (wave < 2) {
      const f16* Ah = A.h1 + ((size_t)(RING - 1) * 64 + rg2 * 16 + lr) * 1024 + wave * 512 + lk;
      const f16* Bp = A.wout + ((size_t)(j2 * 16 + lr)) * 1024 + wave * 512 + lk;
#pragma unroll
      for (int q2 = 0; q2 < 16; ++q2)
        acc = mf(*(const f16x8*)(Ah + q2 * 32), *(const f16x8*)(Bp + q2 * 32), acc);
    }
    if (wave == 1) {
#pragma unroll
      for (int q = 0; q < 4; ++q) sm.sc[0][0][q][lane] = acc[q];
    }
    __syncthreads();
    if (wave == 0) {
#pragma unroll
      for (int q = 0; q < 4; ++q) {
        float v = acc[q] + sm.sc[0][0][q][lane] + A.bout[j2 * 16 + lr];
        A.out[(rg2 * 16 + dr + q) * 512 + j2 * 16 + lr] = v;
      }
    }
  }
}

// ---------------- host ----------------

extern "C" void kernel_launch(void* const* d_in, const int* in_sizes, int n_in,
                              void* d_out, int out_size, void* d_ws, size_t ws_size,
                              hipStream_t stream) {
  (void)in_sizes; (void)n_in; (void)out_size; (void)ws_size;
  const float* x = (const float*)d_in[0];
  const float* w_ih0 = (const float*)d_in[1];
  const float* w_hh0 = (const float*)d_in[2];
  const float* b_ih0 = (const float*)d_in[3];
  const float* b_hh0 = (const float*)d_in[4];
  const float* w_ih1 = (const float*)d_in[5];
  const float* w_hh1 = (const float*)d_in[6];
  const float* b_ih1 = (const float*)d_in[7];
  const float* b_hh1 = (const float*)d_in[8];
  const float* w_out = (const float*)d_in[9];
  const float* b_out = (const float*)d_in[10];

  char* ws = (char*)d_ws;
  size_t off = 0;
  auto alloc = [&](size_t b) {
    off = (off + 255) & ~(size_t)255;
    char* p = ws + off;
    off += b;
    return p;
  };

  float* pe = (float*)alloc((size_t)1024 * 512 * 4);
  f16* x16 = (f16*)alloc((size_t)1024 * 64 * 512 * 2);
  f16* wih0 = (f16*)alloc((size_t)3072 * 512 * 2);
  f16* whh0 = (f16*)alloc((size_t)3072 * 1024 * 2);
  f16* wih1 = (f16*)alloc((size_t)3072 * 1024 * 2);
  f16* whh1 = (f16*)alloc((size_t)3072 * 1024 * 2);
  f16* wout = (f16*)alloc((size_t)512 * 1024 * 2);
  f16* h0r = (f16*)alloc((size_t)RING * 64 * 1024 * 2);
  f16* h1r = (f16*)alloc((size_t)RING * 64 * 1024 * 2);
  unsigned* flg = (unsigned*)alloc(4096);

  // per-call init: flags zero; ring slot RING-1 (initial h=0) zero
  (void)hipMemsetAsync(flg, 0, 4096, stream);
  (void)hipMemsetAsync(h0r + (size_t)(RING - 1) * 64 * 1024, 0, (size_t)64 * 1024 * 2, stream);
  (void)hipMemsetAsync(h1r + (size_t)(RING - 1) * 64 * 1024, 0, (size_t)64 * 1024 * 2, stream);

  gru_k_pe<<<(1024 * 512 + 255) / 256, 256, 0, stream>>>(pe);
  gru_k_x16<<<dim3(2, 1024, 64), 256, 0, stream>>>(x, pe, x16);
  gru_k_f16<<<(3072 * 512 + 255) / 256, 256, 0, stream>>>(w_ih0, wih0, 3072 * 512);
  gru_k_f16<<<(3072 * 1024 + 255) / 256, 256, 0, stream>>>(w_hh0, whh0, 3072 * 1024);
  gru_k_f16<<<(3072 * 1024 + 255) / 256, 256, 0, stream>>>(w_ih1, wih1, 3072 * 1024);
  gru_k_f16<<<(3072 * 1024 + 255) / 256, 256, 0, stream>>>(w_hh1, whh1, 3072 * 1024);
  gru_k_f16<<<(512 * 1024 + 255) / 256, 256, 0, stream>>>(w_out, wout, 512 * 1024);

  gru::Args A;
  A.x16 = x16;
  A.bih0 = b_ih0; A.bhh0 = b_hh0; A.bih1 = b_ih1; A.bhh1 = b_hh1; A.bout = b_out;
  A.wih0 = wih0; A.whh0 = whh0; A.wih1 = wih1; A.whh1 = whh1; A.wout = wout;
  A.h0 = h0r; A.h1 = h1r;
  A.out = (float*)d_out;
  A.flg = flg;

  // Plain launch: 256 blocks x 1 block/CU (LDS-bound) on 256 CUs -> co-resident.
  gru_main<<<dim3(NWG), dim3(WGSZ), 0, stream>>>(A);
}

// Round 8
// 12342.477 us; speedup vs baseline: 3.3630x; 1.0512x over previous
//
#include <hip/hip_runtime.h>
#include <cstdint>
#include <cstddef>

typedef _Float16 f16;
typedef _Float16 f16x8 __attribute__((ext_vector_type(8)));
typedef float f32x4 __attribute__((ext_vector_type(4)));
typedef unsigned long long u64;

#define NWG 256
#define WGSZ 256
#define RING 64   // h-ring depth (slots); addr reuse every RING steps
#define INVP 48   // own-step period of L1/L2 invalidate; must be < RING

namespace gru {

__device__ inline f32x4 mf(f16x8 a, f16x8 b, f32x4 c) {
  return __builtin_amdgcn_mfma_f32_16x16x32_f16(a, b, c, 0, 0, 0);
}
__device__ inline float sigf(float x) { return 1.f / (1.f + __expf(-x)); }
__device__ inline float tanh_fast(float x) {
  float xx = fminf(fmaxf(x, -15.f), 15.f);
  float e = __expf(-2.f * xx);
  return (1.f - e) / (1.f + e);
}

struct SMem {
  f16 wA[48 * 1024];      // 96 KB: whh0 (L0) or whh1 (L1), swizzled
  f16 wB[48 * 512];       // 48 KB: wih0 (L0 only), swizzled
  float sc[2][4][4][64];  // 8 KB pairwise-reduce scratch
  float hm[32][16];       // fp32 master h tile (this WG's 32 rows x 16 cols)
  float bI[48], bH[48];
};

struct Args {
  const f16* x16;
  const float* bih0; const float* bhh0; const float* bih1; const float* bhh1; const float* bout;
  const f16* wih0; const f16* whh0; const f16* wih1; const f16* whh1; const f16* wout;
  f16* h0;   // ring [RING][64][1024]
  f16* h1;   // ring [RING][64][1024]
  float* out;
  unsigned* flg;  // leaf0[l] = flg[l*32]; leaf1[l] = flg[256 + l*32]; l<8, 16 WGs/leaf
};

// ---- flags: monotonic per-side leaf counters (agent-scope atomics, proven) ----

__device__ inline unsigned aldu(const unsigned* p) {
  return __hip_atomic_load(p, __ATOMIC_RELAXED, __HIP_MEMORY_SCOPE_AGENT);
}
__device__ inline void bump(unsigned* p) {
  (void)__hip_atomic_fetch_add(p, 1u, __ATOMIC_RELAXED, __HIP_MEMORY_SCOPE_AGENT);
}
// Spin until min(leaves f0) >= t0 AND min(leaves f1) >= t1.
// Check FIRST (common fast path), then back off with s_sleep(16) (~0.4us):
// at s_sleep(1) the 256 pollers x 16 hot lines congest the coherent point and
// the producer's bump queues behind the polls (the R7 12.7us/step suspect).
__device__ inline void wait2(const unsigned* f0, unsigned t0, const unsigned* f1, unsigned t1) {
  for (;;) {
    unsigned m0 = 0xffffffffu, m1 = 0xffffffffu;
#pragma unroll
    for (int l = 0; l < 8; ++l) m0 = min(m0, aldu(f0 + l * 32));
#pragma unroll
    for (int l = 0; l < 8; ++l) m1 = min(m1, aldu(f1 + l * 32));
    if (m0 >= t0 && m1 >= t1) return;
    __builtin_amdgcn_s_sleep(16);
  }
}

// ---- h writes: WRITE-THROUGH atomic stores (system scope -> sc0 sc1, no RMW).
// R7 used atomic-exchange RMWs here: 32K RMWs/step serialized at the coherent
// point and drained before each bump. Plain WT stores halve that MALL work.
__device__ inline void ast8(f16* p, u64 v) {
  __hip_atomic_store((u64*)p, v, __ATOMIC_RELAXED, __HIP_MEMORY_SCOPE_SYSTEM);
}

// Pack this lane's 4 gate outputs (rows dr..dr+3 of col lr) into one u64 holding
// 4 adjacent cols of ONE row, via 2x shfl_xor across the 4-lane col-group.
__device__ inline u64 pack4(const float* hn4, int lr) {
  u64 w = 0;
#pragma unroll
  for (int q = 0; q < 4; ++q) {
    f16 h = (f16)hn4[q];
    unsigned own = (unsigned)__builtin_bit_cast(unsigned short, h);
    unsigned p1 = (unsigned)__shfl_xor((int)own, 1, 64);
    unsigned v32 = (lr & 1) ? ((own << 16) | p1) : (own | (p1 << 16));
    unsigned o2 = (unsigned)__shfl_xor((int)v32, 2, 64);
    u64 v64 = (lr & 2) ? (((u64)v32 << 32) | (u64)o2) : (((u64)o2 << 32) | (u64)v32);
    if ((lr & 3) == q) w = v64;
  }
  return w;
}

// Load 48 gate-rows (triplet j) of W [3072][K8*8] into LDS, XOR-swizzled per 16B unit.
template <int K8>
__device__ void load_w(f16* dst, const f16* W, int j) {
  for (int u = threadIdx.x; u < 48 * K8; u += WGSZ) {
    int row = u / K8, k8 = u - row * K8;
    int gcol = (row >> 4) * 1024 + j * 16 + (row & 15);
    f16x8 v = *(const f16x8*)(W + (size_t)gcol * (size_t)(K8 * 8) + (size_t)k8 * 8);
    *(f16x8*)(dst + ((size_t)row * K8 + (size_t)(k8 ^ (row & 7))) * 8) = v;
  }
}

template <int K8>
__device__ inline f16x8 ldb(const f16* base, int row, int u8) {
  return *(const f16x8*)(base + ((size_t)row * K8 + (size_t)(u8 ^ (row & 7))) * 8);
}

}  // namespace gru

// ---------------- prep kernels ----------------

__global__ void gru_k_pe(float* pe) {
  int idx = blockIdx.x * 256 + threadIdx.x;
  if (idx >= 1024 * 512) return;
  int t = idx >> 9, d = idx & 511;
  int jj = d >> 1;
  float freq = expf(-logf(10000.f) * (float)(2 * jj) * (1.f / 512.f));
  float ang = (float)t * freq;
  pe[idx] = (d & 1) ? cosf(ang) : sinf(ang);
}

__global__ void gru_k_x16(const float* __restrict__ x, const float* __restrict__ pe,
                          f16* __restrict__ x16) {
  int d = blockIdx.x * 256 + threadIdx.x;  // grid.x = 2
  int t = blockIdx.y, b = blockIdx.z;
  float v = x[((size_t)b * 1024 + t) * 512 + d] + pe[t * 512 + d];
  x16[((size_t)t * 64 + b) * 512 + d] = (f16)v;
}

__global__ void gru_k_f16(const float* __restrict__ src, f16* __restrict__ dst, int n) {
  int i = blockIdx.x * 256 + threadIdx.x;
  if (i < n) dst[i] = (f16)src[i];
}

// ---------------- main persistent pipelined kernel ----------------
// Plain launch, 1 block/CU (LDS-bound). WGs 0..127: layer-0; 128..255: layer-1.
// Per-side monotonic leaf flags; h rings RING deep; readers use CACHED loads;
// periodic __threadfence (every INVP own steps < RING) wipes stale copies
// before slot reuse. Writes: write-through system-scope atomic stores.

__global__ __launch_bounds__(WGSZ, 1) void gru_main(gru::Args A) {
  using namespace gru;
  __shared__ SMem sm;
  const int wg = blockIdx.x, tid = threadIdx.x;
  const bool isL0 = wg < 128;
  const int j = wg & 63, rg = (wg >> 6) & 1;
  const int wave = tid >> 6, lane = tid & 63;
  const int lr = lane & 15, lk8 = lane >> 4;
  const int lk = lk8 * 8, dr = lk8 * 4;
  const int rt = wave >> 1, kh = wave & 1;  // rowtile, K-half per wave
  const int rowbase = rg * 32 + rt * 16;

  ((float*)sm.hm)[tid] = 0.f;
  ((float*)sm.hm)[tid + 256] = 0.f;

  if (isL0) {
    load_w<128>(sm.wA, A.whh0, j);
    load_w<64>(sm.wB, A.wih0, j);
    if (tid < 48) {
      int gcol = (tid >> 4) * 1024 + j * 16 + (tid & 15);
      sm.bI[tid] = A.bih0[gcol];
      sm.bH[tid] = A.bhh0[gcol];
    }
  } else {
    load_w<128>(sm.wA, A.whh1, j);
    if (tid < 48) {
      int gcol = (tid >> 4) * 1024 + j * 16 + (tid & 15);
      sm.bI[tid] = A.bih1[gcol];
      sm.bH[tid] = A.bhh1[gcol];
    }
  }
  __syncthreads();

  if (isL0) {
    // =============== layer-0: free-running, throttled only by ring wrap ===============
    f16x8 xf[8];
    {
      const f16* xp = A.x16 + ((size_t)0 * 64 + rowbase + lr) * 512 + kh * 256 + lk;
#pragma unroll
      for (int q2 = 0; q2 < 8; ++q2) xf[q2] = *(const f16x8*)(xp + q2 * 32);
    }
    for (int t = 0; t < 1024; ++t) {
      if ((t % INVP) == INVP - 1) __threadfence();  // periodic L1/L2 invalidate
      if (tid == 0) {
        unsigned g0 = (t > 0) ? 16u * (unsigned)t : 0u;           // done0[t-1]
        unsigned g1 = (t >= 60) ? 16u * (unsigned)(t - 59) : 0u;  // ring-wrap guard
        wait2(A.flg, g0, A.flg + 256, g1);
      }
      __syncthreads();
      const f16* hp = A.h0 + ((size_t)((t + RING - 1) & (RING - 1)) * 64 + rowbase + lr) * 1024 + kh * 512 + lk;
      f16x8 hf[16];
#pragma unroll
      for (int q2 = 0; q2 < 16; ++q2) hf[q2] = *(const f16x8*)(hp + q2 * 32);  // CACHED
      f32x4 a0 = {0.f, 0.f, 0.f, 0.f}, a1 = a0, a2 = a0, a3 = a0;
#pragma unroll
      for (int q2 = 0; q2 < 8; ++q2) {
        const int u8 = (kh * 8 + q2) * 4 + lk8;
        a0 = mf(xf[q2], ldb<64>(sm.wB, lr, u8), a0);
        a1 = mf(xf[q2], ldb<64>(sm.wB, 16 + lr, u8), a1);
        a2 = mf(xf[q2], ldb<64>(sm.wB, 32 + lr, u8), a2);  // i_n
      }
#pragma unroll
      for (int q2 = 0; q2 < 16; ++q2) {
        const int u8 = (kh * 16 + q2) * 4 + lk8;
        a0 = mf(hf[q2], ldb<128>(sm.wA, lr, u8), a0);
        a1 = mf(hf[q2], ldb<128>(sm.wA, 16 + lr, u8), a1);
        a3 = mf(hf[q2], ldb<128>(sm.wA, 32 + lr, u8), a3);  // h_n
      }
      if (t + 1 < 1024) {  // prefetch next x (cached)
        const f16* xp = A.x16 + ((size_t)(t + 1) * 64 + rowbase + lr) * 512 + kh * 256 + lk;
#pragma unroll
        for (int q2 = 0; q2 < 8; ++q2) xf[q2] = *(const f16x8*)(xp + q2 * 32);
      }
      if (kh) {
#pragma unroll
        for (int q = 0; q < 4; ++q) {
          sm.sc[rt][0][q][lane] = a0[q]; sm.sc[rt][1][q][lane] = a1[q];
          sm.sc[rt][2][q][lane] = a2[q]; sm.sc[rt][3][q][lane] = a3[q];
        }
      }
      __syncthreads();
      if (!kh) {
        float hn4[4];
#pragma unroll
        for (int q = 0; q < 4; ++q) {
          a0[q] += sm.sc[rt][0][q][lane]; a1[q] += sm.sc[rt][1][q][lane];
          a2[q] += sm.sc[rt][2][q][lane]; a3[q] += sm.sc[rt][3][q][lane];
        }
#pragma unroll
        for (int q = 0; q < 4; ++q) {
          const int row = rt * 16 + dr + q;
          float r = sigf(a0[q] + sm.bI[lr] + sm.bH[lr]);
          float z = sigf(a1[q] + sm.bI[16 + lr] + sm.bH[16 + lr]);
          float n = tanh_fast(a2[q] + sm.bI[32 + lr] + r * (a3[q] + sm.bH[32 + lr]));
          float hn = n + z * (sm.hm[row][lr] - n);
          sm.hm[row][lr] = hn;
          hn4[q] = hn;
        }
        u64 w = pack4(hn4, lr);
        const int srow = rt * 16 + dr + (lr & 3);
        ast8(A.h0 + ((size_t)(t & (RING - 1)) * 64 + rg * 32 + srow) * 1024 + j * 16 + (lr & ~3), w);
      }
      __syncthreads();  // drains WT stores (vmcnt) before the flag bump
      if (tid == 0) bump(A.flg + (wg & 7) * 32);
    }
  } else {
    // =============== layer-1: consumes h0(t), recurrent on h1(t-1) ===============
    for (int t = 0; t < 1024; ++t) {
      if ((t % INVP) == INVP - 1) __threadfence();
      if (tid == 0) {
        unsigned g0 = 16u * (unsigned)(t + 1);            // done0[t]
        unsigned g1 = (t > 0) ? 16u * (unsigned)t : 0u;   // done1[t-1]
        wait2(A.flg, g0, A.flg + 256, g1);
      }
      __syncthreads();
      const f16* gp = A.h0 + ((size_t)(t & (RING - 1)) * 64 + rowbase + lr) * 1024 + kh * 512 + lk;
      const f16* hp = A.h1 + ((size_t)((t + RING - 1) & (RING - 1)) * 64 + rowbase + lr) * 1024 + kh * 512 + lk;
      f16x8 gf[16], hf[16];
#pragma unroll
      for (int q2 = 0; q2 < 16; ++q2) gf[q2] = *(const f16x8*)(gp + q2 * 32);  // CACHED
#pragma unroll
      for (int q2 = 0; q2 < 16; ++q2) hf[q2] = *(const f16x8*)(hp + q2 * 32);  // CACHED
      f32x4 a0 = {0.f, 0.f, 0.f, 0.f}, a1 = a0, a2 = a0, a3 = a0;
      const f16* wb = A.wih1 + ((size_t)(j * 16 + lr)) * 1024 + kh * 512 + lk;
#pragma unroll
      for (int q2 = 0; q2 < 16; ++q2) {
        const size_t o = (size_t)q2 * 32;
        a0 = mf(gf[q2], *(const f16x8*)(wb + o), a0);
        a1 = mf(gf[q2], *(const f16x8*)(wb + (size_t)1024 * 1024 + o), a1);
        a2 = mf(gf[q2], *(const f16x8*)(wb + (size_t)2048 * 1024 + o), a2);  // i_n
      }
#pragma unroll
      for (int q2 = 0; q2 < 16; ++q2) {
        const int u8 = (kh * 16 + q2) * 4 + lk8;
        a0 = mf(hf[q2], ldb<128>(sm.wA, lr, u8), a0);
        a1 = mf(hf[q2], ldb<128>(sm.wA, 16 + lr, u8), a1);
        a3 = mf(hf[q2], ldb<128>(sm.wA, 32 + lr, u8), a3);  // h_n
      }
      if (kh) {
#pragma unroll
        for (int q = 0; q < 4; ++q) {
          sm.sc[rt][0][q][lane] = a0[q]; sm.sc[rt][1][q][lane] = a1[q];
          sm.sc[rt][2][q][lane] = a2[q]; sm.sc[rt][3][q][lane] = a3[q];
        }
      }
      __syncthreads();
      if (!kh) {
        float hn4[4];
#pragma unroll
        for (int q = 0; q < 4; ++q) {
          a0[q] += sm.sc[rt][0][q][lane]; a1[q] += sm.sc[rt][1][q][lane];
          a2[q] += sm.sc[rt][2][q][lane]; a3[q] += sm.sc[rt][3][q][lane];
        }
#pragma unroll
        for (int q = 0; q < 4; ++q) {
          const int row = rt * 16 + dr + q;
          float r = sigf(a0[q] + sm.bI[lr] + sm.bH[lr]);
          float z = sigf(a1[q] + sm.bI[16 + lr] + sm.bH[16 + lr]);
          float n = tanh_fast(a2[q] + sm.bI[32 + lr] + r * (a3[q] + sm.bH[32 + lr]));
          float hn = n + z * (sm.hm[row][lr] - n);
          sm.hm[row][lr] = hn;
          hn4[q] = hn;
        }
        u64 w = pack4(hn4, lr);
        const int srow = rt * 16 + dr + (lr & 3);
        ast8(A.h1 + ((size_t)(t & (RING - 1)) * 64 + rg * 32 + srow) * 1024 + j * 16 + (lr & ~3), w);
      }
      __syncthreads();
      if (tid == 0) bump(A.flg + 256 + (wg & 7) * 32);
    }

    // ---- output projection: out = h1(1023) @ w_out^T + b_out (ring slot 63) ----
    if (tid == 0) wait2(A.flg + 256, 16u * 1024u, A.flg + 256, 16u * 1024u);
    __syncthreads();
    const int g = wg - 128;
    const int j2 = g & 31, rg2 = g >> 5;
    f32x4 acc = {0.f, 0.f, 0.f, 0.f};
    if (wave < 2) {
      const f16* Ah = A.h1 + ((size_t)(RING - 1) * 64 + rg2 * 16 + lr) * 1024 + wave * 512 + lk;
      const f16* Bp = A.wout + ((size_t)(j2 * 16 + lr)) * 1024 + wave * 512 + lk;
#pragma unroll
      for (int q2 = 0; q2 < 16; ++q2)
        acc = mf(*(const f16x8*)(Ah + q2 * 32), *(const f16x8*)(Bp + q2 * 32), acc);
    }
    if (wave == 1) {
#pragma unroll
      for (int q = 0; q < 4; ++q) sm.sc[0][0][q][lane] = acc[q];
    }
    __syncthreads();
    if (wave == 0) {
#pragma unroll
      for (int q = 0; q < 4; ++q) {
        float v = acc[q] + sm.sc[0][0][q][lane] + A.bout[j2 * 16 + lr];
        A.out[(rg2 * 16 + dr + q) * 512 + j2 * 16 + lr] = v;
      }
    }
  }
}

// ---------------- host ----------------

extern "C" void kernel_launch(void* const* d_in, const int* in_sizes, int n_in,
                              void* d_out, int out_size, void* d_ws, size_t ws_size,
                              hipStream_t stream) {
  (void)in_sizes; (void)n_in; (void)out_size; (void)ws_size;
  const float* x = (const float*)d_in[0];
  const float* w_ih0 = (const float*)d_in[1];
  const float* w_hh0 = (const float*)d_in[2];
  const float* b_ih0 = (const float*)d_in[3];
  const float* b_hh0 = (const float*)d_in[4];
  const float* w_ih1 = (const float*)d_in[5];
  const float* w_hh1 = (const float*)d_in[6];
  const float* b_ih1 = (const float*)d_in[7];
  const float* b_hh1 = (const float*)d_in[8];
  const float* w_out = (const float*)d_in[9];
  const float* b_out = (const float*)d_in[10];

  char* ws = (char*)d_ws;
  size_t off = 0;
  auto alloc = [&](size_t b) {
    off = (off + 255) & ~(size_t)255;
    char* p = ws + off;
    off += b;
    return p;
  };

  float* pe = (float*)alloc((size_t)1024 * 512 * 4);
  f16* x16 = (f16*)alloc((size_t)1024 * 64 * 512 * 2);
  f16* wih0 = (f16*)alloc((size_t)3072 * 512 * 2);
  f16* whh0 = (f16*)alloc((size_t)3072 * 1024 * 2);
  f16* wih1 = (f16*)alloc((size_t)3072 * 1024 * 2);
  f16* whh1 = (f16*)alloc((size_t)3072 * 1024 * 2);
  f16* wout = (f16*)alloc((size_t)512 * 1024 * 2);
  f16* h0r = (f16*)alloc((size_t)RING * 64 * 1024 * 2);
  f16* h1r = (f16*)alloc((size_t)RING * 64 * 1024 * 2);
  unsigned* flg = (unsigned*)alloc(4096);

  // per-call init: flags zero; ring slot RING-1 (initial h=0) zero
  (void)hipMemsetAsync(flg, 0, 4096, stream);
  (void)hipMemsetAsync(h0r + (size_t)(RING - 1) * 64 * 1024, 0, (size_t)64 * 1024 * 2, stream);
  (void)hipMemsetAsync(h1r + (size_t)(RING - 1) * 64 * 1024, 0, (size_t)64 * 1024 * 2, stream);

  gru_k_pe<<<(1024 * 512 + 255) / 256, 256, 0, stream>>>(pe);
  gru_k_x16<<<dim3(2, 1024, 64), 256, 0, stream>>>(x, pe, x16);
  gru_k_f16<<<(3072 * 512 + 255) / 256, 256, 0, stream>>>(w_ih0, wih0, 3072 * 512);
  gru_k_f16<<<(3072 * 1024 + 255) / 256, 256, 0, stream>>>(w_hh0, whh0, 3072 * 1024);
  gru_k_f16<<<(3072 * 1024 + 255) / 256, 256, 0, stream>>>(w_ih1, wih1, 3072 * 1024);
  gru_k_f16<<<(3072 * 1024 + 255) / 256, 256, 0, stream>>>(w_hh1, whh1, 3072 * 1024);
  gru_k_f16<<<(512 * 1024 + 255) / 256, 256, 0, stream>>>(w_out, wout, 512 * 1024);

  gru::Args A;
  A.x16 = x16;
  A.bih0 = b_ih0; A.bhh0 = b_hh0; A.bih1 = b_ih1; A.bhh1 = b_hh1; A.bout = b_out;
  A.wih0 = wih0; A.whh0 = whh0; A.wih1 = wih1; A.whh1 = whh1; A.wout = wout;
  A.h0 = h0r; A.h1 = h1r;
  A.out = (float*)d_out;
  A.flg = flg;

  // Plain launch: 256 blocks x 1 block/CU (LDS-bound) on 256 CUs -> co-resident.
  gru_main<<<dim3(NWG), dim3(WGSZ), 0, stream>>>(A);
}

// Round 9
// 11779.443 us; speedup vs baseline: 3.5238x; 1.0478x over previous
//
#include <hip/hip_runtime.h>
#include <cstdint>
#include <cstddef>

typedef _Float16 f16;
typedef _Float16 f16x8 __attribute__((ext_vector_type(8)));
typedef float f32x4 __attribute__((ext_vector_type(4)));
typedef unsigned long long u64;

#define NWG 256
#define WGSZ 256
#define RING 64   // h-ring depth (slots); addr reuse every RING steps
#define INVP 48   // own-step period of L1/L2 invalidate; must be < RING

namespace gru {

__device__ inline f32x4 mf(f16x8 a, f16x8 b, f32x4 c) {
  return __builtin_amdgcn_mfma_f32_16x16x32_f16(a, b, c, 0, 0, 0);
}
__device__ inline float sigf(float x) { return 1.f / (1.f + __expf(-x)); }
__device__ inline float tanh_fast(float x) {
  float xx = fminf(fmaxf(x, -15.f), 15.f);
  float e = __expf(-2.f * xx);
  return (1.f - e) / (1.f + e);
}

struct SMem {
  f16 wA[48 * 1024];      // 96 KB: whh0 (L0) or whh1 (L1), swizzled
  f16 wB[48 * 512];       // 48 KB: wih0 (L0 only), swizzled
  float sc[2][4][4][64];  // 8 KB pairwise-reduce scratch
  float hm[32][16];       // fp32 master h tile (this WG's 32 rows x 16 cols)
  float bI[48], bH[48];
};

struct Args {
  const f16* x16;
  const float* bih0; const float* bhh0; const float* bih1; const float* bhh1; const float* bout;
  const f16* wih0; const f16* whh0; const f16* wih1; const f16* whh1; const f16* wout;
  f16* h0;   // per-group rings: [2][RING][32][1024]
  f16* h1;   // per-group rings: [2][RING][32][1024]
  float* out;
  unsigned* flg;  // (grp*8 + side*4 + leaf) * 32 dwords; leaf<4, 16 WGs/leaf
};

// ---- flags: monotonic leaf counters via agent-scope atomics (proven R5-R8) ----

__device__ inline unsigned aldu(const unsigned* p) {
  return __hip_atomic_load(p, __ATOMIC_RELAXED, __HIP_MEMORY_SCOPE_AGENT);
}
__device__ inline void bump(unsigned* p) {
  (void)__hip_atomic_fetch_add(p, 1u, __ATOMIC_RELAXED, __HIP_MEMORY_SCOPE_AGENT);
}
// Spin until min(4 leaves of s0) >= t0 AND min(4 leaves of s1) >= t1.
// Fine-grained sleep (85ns): R8 showed poll contention is NOT dominant, so
// prioritize detection latency; only 64 pollers per flag set now.
__device__ inline void wait2(const unsigned* s0, unsigned t0, const unsigned* s1, unsigned t1) {
  for (;;) {
    unsigned m0 = 0xffffffffu, m1 = 0xffffffffu;
#pragma unroll
    for (int l = 0; l < 4; ++l) m0 = min(m0, aldu(s0 + l * 32));
#pragma unroll
    for (int l = 0; l < 4; ++l) m1 = min(m1, aldu(s1 + l * 32));
    if (m0 >= t0 && m1 >= t1) return;
    __builtin_amdgcn_s_sleep(2);
  }
}

// ---- h writes: write-through system-scope atomic stores (proven R8) ----
__device__ inline void ast8(f16* p, u64 v) {
  __hip_atomic_store((u64*)p, v, __ATOMIC_RELAXED, __HIP_MEMORY_SCOPE_SYSTEM);
}

// Pack this lane's 4 gate outputs (rows dr..dr+3 of col lr) into one u64 holding
// 4 adjacent cols of ONE row, via 2x shfl_xor across the 4-lane col-group.
__device__ inline u64 pack4(const float* hn4, int lr) {
  u64 w = 0;
#pragma unroll
  for (int q = 0; q < 4; ++q) {
    f16 h = (f16)hn4[q];
    unsigned own = (unsigned)__builtin_bit_cast(unsigned short, h);
    unsigned p1 = (unsigned)__shfl_xor((int)own, 1, 64);
    unsigned v32 = (lr & 1) ? ((own << 16) | p1) : (own | (p1 << 16));
    unsigned o2 = (unsigned)__shfl_xor((int)v32, 2, 64);
    u64 v64 = (lr & 2) ? (((u64)v32 << 32) | (u64)o2) : (((u64)o2 << 32) | (u64)v32);
    if ((lr & 3) == q) w = v64;
  }
  return w;
}

// Load 48 gate-rows (triplet j) of W [3072][K8*8] into LDS, XOR-swizzled per 16B unit.
template <int K8>
__device__ void load_w(f16* dst, const f16* W, int j) {
  for (int u = threadIdx.x; u < 48 * K8; u += WGSZ) {
    int row = u / K8, k8 = u - row * K8;
    int gcol = (row >> 4) * 1024 + j * 16 + (row & 15);
    f16x8 v = *(const f16x8*)(W + (size_t)gcol * (size_t)(K8 * 8) + (size_t)k8 * 8);
    *(f16x8*)(dst + ((size_t)row * K8 + (size_t)(k8 ^ (row & 7))) * 8) = v;
  }
}

template <int K8>
__device__ inline f16x8 ldb(const f16* base, int row, int u8) {
  return *(const f16x8*)(base + ((size_t)row * K8 + (size_t)(u8 ^ (row & 7))) * 8);
}

}  // namespace gru

// ---------------- prep kernels ----------------

__global__ void gru_k_pe(float* pe) {
  int idx = blockIdx.x * 256 + threadIdx.x;
  if (idx >= 1024 * 512) return;
  int t = idx >> 9, d = idx & 511;
  int jj = d >> 1;
  float freq = expf(-logf(10000.f) * (float)(2 * jj) * (1.f / 512.f));
  float ang = (float)t * freq;
  pe[idx] = (d & 1) ? cosf(ang) : sinf(ang);
}

__global__ void gru_k_x16(const float* __restrict__ x, const float* __restrict__ pe,
                          f16* __restrict__ x16) {
  int d = blockIdx.x * 256 + threadIdx.x;  // grid.x = 2
  int t = blockIdx.y, b = blockIdx.z;
  float v = x[((size_t)b * 1024 + t) * 512 + d] + pe[t * 512 + d];
  x16[((size_t)t * 64 + b) * 512 + d] = (f16)v;
}

__global__ void gru_k_f16(const float* __restrict__ src, f16* __restrict__ dst, int n) {
  int i = blockIdx.x * 256 + threadIdx.x;
  if (i < n) dst[i] = (f16)src[i];
}

// ---------------- main persistent pipelined kernel ----------------
// Batch split into 2 INDEPENDENT groups of 32 rows (no cross-group coupling):
//   xcd = wg%8:  xcd>>2 = group;  (xcd>>1)&1 = role (0=L0, 1=L1);
//   wgid = ((xcd&1)<<5) | (wg>>3)  in 0..63  -> gate-column triplet j.
// Each group's convergence: 64 WGs spanning 2 XCDs (vs 128 across 8 in R8).
// Per-WG tile/work identical to R8. Rings/flags are per-group.

__global__ __launch_bounds__(WGSZ, 1) void gru_main(gru::Args A) {
  using namespace gru;
  __shared__ SMem sm;
  const int wg = blockIdx.x, tid = threadIdx.x;
  const int xcd = wg & 7, slot = wg >> 3;
  const int grp = xcd >> 2;
  const bool isL0 = ((xcd >> 1) & 1) == 0;
  const int wgid = ((xcd & 1) << 5) | slot;
  const int j = wgid;
  const int wave = tid >> 6, lane = tid & 63;
  const int lr = lane & 15, lk8 = lane >> 4;
  const int lk = lk8 * 8, dr = lk8 * 4;
  const int rt = wave >> 1, kh = wave & 1;  // rowtile, K-half per wave
  const int rowbase = rt * 16;              // within the group's 32 rows
  const int gb = grp * 32;                  // global batch base

  f16* h0g = A.h0 + (size_t)grp * RING * 32 * 1024;
  f16* h1g = A.h1 + (size_t)grp * RING * 32 * 1024;
  unsigned* myleaf = A.flg + (size_t)(grp * 8 + (isL0 ? 0 : 4) + (wgid & 3)) * 32;
  const unsigned* s0 = A.flg + (size_t)(grp * 8) * 32;
  const unsigned* s1 = A.flg + (size_t)(grp * 8 + 4) * 32;

  __threadfence();  // cross-replay cache hygiene (once; before any cached read)

  ((float*)sm.hm)[tid] = 0.f;
  ((float*)sm.hm)[tid + 256] = 0.f;

  if (isL0) {
    load_w<128>(sm.wA, A.whh0, j);
    load_w<64>(sm.wB, A.wih0, j);
    if (tid < 48) {
      int gcol = (tid >> 4) * 1024 + j * 16 + (tid & 15);
      sm.bI[tid] = A.bih0[gcol];
      sm.bH[tid] = A.bhh0[gcol];
    }
  } else {
    load_w<128>(sm.wA, A.whh1, j);
    if (tid < 48) {
      int gcol = (tid >> 4) * 1024 + j * 16 + (tid & 15);
      sm.bI[tid] = A.bih1[gcol];
      sm.bH[tid] = A.bhh1[gcol];
    }
  }
  __syncthreads();

  if (isL0) {
    // =============== layer-0 ===============
    f16x8 xf[2][8];
    {
      const f16* xp = A.x16 + ((size_t)0 * 64 + gb + rowbase + lr) * 512 + kh * 256 + lk;
#pragma unroll
      for (int q2 = 0; q2 < 8; ++q2) xf[0][q2] = *(const f16x8*)(xp + q2 * 32);
    }
    for (int t = 0; t < 1024; ++t) {
      if ((t % INVP) == INVP - 1) __threadfence();  // periodic L1/L2 invalidate
      if (tid == 0) {
        unsigned g0 = (t > 0) ? 16u * (unsigned)t : 0u;           // done0[t-1]
        unsigned g1 = (t >= 60) ? 16u * (unsigned)(t - 59) : 0u;  // ring-wrap guard
        wait2(s0, g0, s1, g1);
      }
      __syncthreads();
      const int cur = t & 1;
      if (t + 1 < 1024) {  // prefetch next x EARLY: completes under the MFMAs
        const f16* xp = A.x16 + ((size_t)(t + 1) * 64 + gb + rowbase + lr) * 512 + kh * 256 + lk;
#pragma unroll
        for (int q2 = 0; q2 < 8; ++q2) xf[cur ^ 1][q2] = *(const f16x8*)(xp + q2 * 32);
      }
      const f16* hp = h0g + ((size_t)((t + RING - 1) & (RING - 1)) * 32 + rowbase + lr) * 1024 + kh * 512 + lk;
      f16x8 hf[16];
#pragma unroll
      for (int q2 = 0; q2 < 16; ++q2) hf[q2] = *(const f16x8*)(hp + q2 * 32);  // CACHED
      f32x4 a0 = {0.f, 0.f, 0.f, 0.f}, a1 = a0, a2 = a0, a3 = a0;
#pragma unroll
      for (int q2 = 0; q2 < 8; ++q2) {
        const int u8 = (kh * 8 + q2) * 4 + lk8;
        a0 = mf(xf[cur][q2], ldb<64>(sm.wB, lr, u8), a0);
        a1 = mf(xf[cur][q2], ldb<64>(sm.wB, 16 + lr, u8), a1);
        a2 = mf(xf[cur][q2], ldb<64>(sm.wB, 32 + lr, u8), a2);  // i_n
      }
#pragma unroll
      for (int q2 = 0; q2 < 16; ++q2) {
        const int u8 = (kh * 16 + q2) * 4 + lk8;
        a0 = mf(hf[q2], ldb<128>(sm.wA, lr, u8), a0);
        a1 = mf(hf[q2], ldb<128>(sm.wA, 16 + lr, u8), a1);
        a3 = mf(hf[q2], ldb<128>(sm.wA, 32 + lr, u8), a3);  // h_n
      }
      if (kh) {
#pragma unroll
        for (int q = 0; q < 4; ++q) {
          sm.sc[rt][0][q][lane] = a0[q]; sm.sc[rt][1][q][lane] = a1[q];
          sm.sc[rt][2][q][lane] = a2[q]; sm.sc[rt][3][q][lane] = a3[q];
        }
      }
      __syncthreads();
      if (!kh) {
        float hn4[4];
#pragma unroll
        for (int q = 0; q < 4; ++q) {
          a0[q] += sm.sc[rt][0][q][lane]; a1[q] += sm.sc[rt][1][q][lane];
          a2[q] += sm.sc[rt][2][q][lane]; a3[q] += sm.sc[rt][3][q][lane];
        }
#pragma unroll
        for (int q = 0; q < 4; ++q) {
          const int row = rt * 16 + dr + q;
          float r = sigf(a0[q] + sm.bI[lr] + sm.bH[lr]);
          float z = sigf(a1[q] + sm.bI[16 + lr] + sm.bH[16 + lr]);
          float n = tanh_fast(a2[q] + sm.bI[32 + lr] + r * (a3[q] + sm.bH[32 + lr]));
          float hn = n + z * (sm.hm[row][lr] - n);
          sm.hm[row][lr] = hn;
          hn4[q] = hn;
        }
        u64 w = pack4(hn4, lr);
        const int srow = rt * 16 + dr + (lr & 3);
        ast8(h0g + ((size_t)(t & (RING - 1)) * 32 + srow) * 1024 + j * 16 + (lr & ~3), w);
      }
      __syncthreads();  // drains WT stores (vmcnt) before the flag bump
      if (tid == 0) bump(myleaf);
    }
  } else {
    // =============== layer-1 ===============
    for (int t = 0; t < 1024; ++t) {
      if ((t % INVP) == INVP - 1) __threadfence();
      if (tid == 0) {
        unsigned g0 = 16u * (unsigned)(t + 1);            // done0[t]
        unsigned g1 = (t > 0) ? 16u * (unsigned)t : 0u;   // done1[t-1]
        wait2(s0, g0, s1, g1);
      }
      __syncthreads();
      const f16* gp = h0g + ((size_t)(t & (RING - 1)) * 32 + rowbase + lr) * 1024 + kh * 512 + lk;
      const f16* hp = h1g + ((size_t)((t + RING - 1) & (RING - 1)) * 32 + rowbase + lr) * 1024 + kh * 512 + lk;
      f16x8 gf[16], hf[16];
#pragma unroll
      for (int q2 = 0; q2 < 16; ++q2) gf[q2] = *(const f16x8*)(gp + q2 * 32);  // CACHED
#pragma unroll
      for (int q2 = 0; q2 < 16; ++q2) hf[q2] = *(const f16x8*)(hp + q2 * 32);  // CACHED
      f32x4 a0 = {0.f, 0.f, 0.f, 0.f}, a1 = a0, a2 = a0, a3 = a0;
      const f16* wb = A.wih1 + ((size_t)(j * 16 + lr)) * 1024 + kh * 512 + lk;
#pragma unroll
      for (int q2 = 0; q2 < 16; ++q2) {
        const size_t o = (size_t)q2 * 32;
        a0 = mf(gf[q2], *(const f16x8*)(wb + o), a0);
        a1 = mf(gf[q2], *(const f16x8*)(wb + (size_t)1024 * 1024 + o), a1);
        a2 = mf(gf[q2], *(const f16x8*)(wb + (size_t)2048 * 1024 + o), a2);  // i_n
      }
#pragma unroll
      for (int q2 = 0; q2 < 16; ++q2) {
        const int u8 = (kh * 16 + q2) * 4 + lk8;
        a0 = mf(hf[q2], ldb<128>(sm.wA, lr, u8), a0);
        a1 = mf(hf[q2], ldb<128>(sm.wA, 16 + lr, u8), a1);
        a3 = mf(hf[q2], ldb<128>(sm.wA, 32 + lr, u8), a3);  // h_n
      }
      if (kh) {
#pragma unroll
        for (int q = 0; q < 4; ++q) {
          sm.sc[rt][0][q][lane] = a0[q]; sm.sc[rt][1][q][lane] = a1[q];
          sm.sc[rt][2][q][lane] = a2[q]; sm.sc[rt][3][q][lane] = a3[q];
        }
      }
      __syncthreads();
      if (!kh) {
        float hn4[4];
#pragma unroll
        for (int q = 0; q < 4; ++q) {
          a0[q] += sm.sc[rt][0][q][lane]; a1[q] += sm.sc[rt][1][q][lane];
          a2[q] += sm.sc[rt][2][q][lane]; a3[q] += sm.sc[rt][3][q][lane];
        }
#pragma unroll
        for (int q = 0; q < 4; ++q) {
          const int row = rt * 16 + dr + q;
          float r = sigf(a0[q] + sm.bI[lr] + sm.bH[lr]);
          float z = sigf(a1[q] + sm.bI[16 + lr] + sm.bH[16 + lr]);
          float n = tanh_fast(a2[q] + sm.bI[32 + lr] + r * (a3[q] + sm.bH[32 + lr]));
          float hn = n + z * (sm.hm[row][lr] - n);
          sm.hm[row][lr] = hn;
          hn4[q] = hn;
        }
        u64 w = pack4(hn4, lr);
        const int srow = rt * 16 + dr + (lr & 3);
        ast8(h1g + ((size_t)(t & (RING - 1)) * 32 + srow) * 1024 + j * 16 + (lr & ~3), w);
      }
      __syncthreads();
      if (tid == 0) bump(myleaf);
    }

    // ---- output projection: out rows gb..gb+31 = h1(1023) @ w_out^T + b_out ----
    if (tid == 0) wait2(s1, 16u * 1024u, s1, 0u);
    __syncthreads();
    const int j2 = wgid & 31, rg2 = wgid >> 5;
    f32x4 acc = {0.f, 0.f, 0.f, 0.f};
    if (wave < 2) {
      const f16* Ah = h1g + ((size_t)(RING - 1) * 32 + rg2 * 16 + lr) * 1024 + wave * 512 + lk;
      const f16* Bp = A.wout + ((size_t)(j2 * 16 + lr)) * 1024 + wave * 512 + lk;
#pragma unroll
      for (int q2 = 0; q2 < 16; ++q2)
        acc = mf(*(const f16x8*)(Ah + q2 * 32), *(const f16x8*)(Bp + q2 * 32), acc);
    }
    if (wave == 1) {
#pragma unroll
      for (int q = 0; q < 4; ++q) sm.sc[0][0][q][lane] = acc[q];
    }
    __syncthreads();
    if (wave == 0) {
#pragma unroll
      for (int q = 0; q < 4; ++q) {
        float v = acc[q] + sm.sc[0][0][q][lane] + A.bout[j2 * 16 + lr];
        A.out[(gb + rg2 * 16 + dr + q) * 512 + j2 * 16 + lr] = v;
      }
    }
  }
}

// ---------------- host ----------------

extern "C" void kernel_launch(void* const* d_in, const int* in_sizes, int n_in,
                              void* d_out, int out_size, void* d_ws, size_t ws_size,
                              hipStream_t stream) {
  (void)in_sizes; (void)n_in; (void)out_size; (void)ws_size;
  const float* x = (const float*)d_in[0];
  const float* w_ih0 = (const float*)d_in[1];
  const float* w_hh0 = (const float*)d_in[2];
  const float* b_ih0 = (const float*)d_in[3];
  const float* b_hh0 = (const float*)d_in[4];
  const float* w_ih1 = (const float*)d_in[5];
  const float* w_hh1 = (const float*)d_in[6];
  const float* b_ih1 = (const float*)d_in[7];
  const float* b_hh1 = (const float*)d_in[8];
  const float* w_out = (const float*)d_in[9];
  const float* b_out = (const float*)d_in[10];

  char* ws = (char*)d_ws;
  size_t off = 0;
  auto alloc = [&](size_t b) {
    off = (off + 255) & ~(size_t)255;
    char* p = ws + off;
    off += b;
    return p;
  };

  float* pe = (float*)alloc((size_t)1024 * 512 * 4);
  f16* x16 = (f16*)alloc((size_t)1024 * 64 * 512 * 2);
  f16* wih0 = (f16*)alloc((size_t)3072 * 512 * 2);
  f16* whh0 = (f16*)alloc((size_t)3072 * 1024 * 2);
  f16* wih1 = (f16*)alloc((size_t)3072 * 1024 * 2);
  f16* whh1 = (f16*)alloc((size_t)3072 * 1024 * 2);
  f16* wout = (f16*)alloc((size_t)512 * 1024 * 2);
  f16* h0r = (f16*)alloc((size_t)2 * RING * 32 * 1024 * 2);
  f16* h1r = (f16*)alloc((size_t)2 * RING * 32 * 1024 * 2);
  unsigned* flg = (unsigned*)alloc(4096);

  // per-call init: flags zero; ring slot RING-1 (initial h=0) zero, per group
  (void)hipMemsetAsync(flg, 0, 4096, stream);
  for (int g = 0; g < 2; ++g) {
    (void)hipMemsetAsync(h0r + ((size_t)g * RING + RING - 1) * 32 * 1024, 0, (size_t)32 * 1024 * 2, stream);
    (void)hipMemsetAsync(h1r + ((size_t)g * RING + RING - 1) * 32 * 1024, 0, (size_t)32 * 1024 * 2, stream);
  }

  gru_k_pe<<<(1024 * 512 + 255) / 256, 256, 0, stream>>>(pe);
  gru_k_x16<<<dim3(2, 1024, 64), 256, 0, stream>>>(x, pe, x16);
  gru_k_f16<<<(3072 * 512 + 255) / 256, 256, 0, stream>>>(w_ih0, wih0, 3072 * 512);
  gru_k_f16<<<(3072 * 1024 + 255) / 256, 256, 0, stream>>>(w_hh0, whh0, 3072 * 1024);
  gru_k_f16<<<(3072 * 1024 + 255) / 256, 256, 0, stream>>>(w_ih1, wih1, 3072 * 1024);
  gru_k_f16<<<(3072 * 1024 + 255) / 256, 256, 0, stream>>>(w_hh1, whh1, 3072 * 1024);
  gru_k_f16<<<(512 * 1024 + 255) / 256, 256, 0, stream>>>(w_out, wout, 512 * 1024);

  gru::Args A;
  A.x16 = x16;
  A.bih0 = b_ih0; A.bhh0 = b_hh0; A.bih1 = b_ih1; A.bhh1 = b_hh1; A.bout = b_out;
  A.wih0 = wih0; A.whh0 = whh0; A.wih1 = wih1; A.whh1 = whh1; A.wout = wout;
  A.h0 = h0r; A.h1 = h1r;
  A.out = (float*)d_out;
  A.flg = flg;

  // Plain launch: 256 blocks x 1 block/CU (LDS-bound) on 256 CUs -> co-resident.
  gru_main<<<dim3(NWG), dim3(WGSZ), 0, stream>>>(A);
}

// Round 10
// 11733.997 us; speedup vs baseline: 3.5374x; 1.0039x over previous
//
#include <hip/hip_runtime.h>
#include <cstdint>
#include <cstddef>

typedef _Float16 f16;
typedef _Float16 f16x8 __attribute__((ext_vector_type(8)));
typedef float f32x4 __attribute__((ext_vector_type(4)));
typedef unsigned u32x4 __attribute__((ext_vector_type(4)));
typedef unsigned long long u64;

#define NWG 256
#define WGSZ 256
#define RING 64   // h-ring depth (slots); addr reuse every RING steps
#define INVP 48   // own-step period of L1/L2 invalidate; must be < RING

namespace gru {

__device__ inline f32x4 mf(f16x8 a, f16x8 b, f32x4 c) {
  return __builtin_amdgcn_mfma_f32_16x16x32_f16(a, b, c, 0, 0, 0);
}
__device__ inline float sigf(float x) { return 1.f / (1.f + __expf(-x)); }
__device__ inline float tanh_fast(float x) {
  float xx = fminf(fmaxf(x, -15.f), 15.f);
  float e = __expf(-2.f * xx);
  return (1.f - e) / (1.f + e);
}

struct SMem {
  f16 wA[48 * 1024];      // 96 KB: whh0 (L0) or whh1 (L1), swizzled
  f16 wB[48 * 512];       // 48 KB: wih0 (L0 only), swizzled
  float sc[2][4][4][64];  // 8 KB pairwise-reduce scratch
  float hm[32][16];       // fp32 master h tile (this WG's 32 rows x 16 cols)
  float bI[48], bH[48];
};

struct Args {
  const f16* x16;
  const float* bih0; const float* bhh0; const float* bih1; const float* bhh1; const float* bout;
  const f16* wih0; const f16* whh0; const f16* wih1; const f16* whh1; const f16* wout;
  f16* h0;   // per-group rings: [2][RING][32][1024]
  f16* h1;   // per-group rings: [2][RING][32][1024]
  float* out;
  unsigned* flg;  // per group: 6 regions x 64 words x 128B stride (see kernel)
};

// ---- sync primitives: SINGLE-WRITER / SINGLE-READER lines only.
// R7-R9 floor diagnosis: shared flag lines polled by 100+ WGs serialize at the
// coherent point; the producer's bump queues BEHIND the poll queue (~us each).
// Here: private per-WG counters (1 writer), designated scanner broadcasts to
// private per-consumer mailboxes (1 reader each). No line has >1 poller.

__device__ inline unsigned aldu(const unsigned* p) {
  return __hip_atomic_load(p, __ATOMIC_RELAXED, __HIP_MEMORY_SCOPE_AGENT);
}
__device__ inline void astu(unsigned* p, unsigned v) {
  __hip_atomic_store(p, v, __ATOMIC_RELAXED, __HIP_MEMORY_SCOPE_AGENT);
}

// Pack this lane's 4 gate outputs (rows dr..dr+3 of col lr) into one u64 holding
// 4 adjacent cols of ONE row, via 2x shfl_xor across the 4-lane col-group.
__device__ inline u64 pack4(const float* hn4, int lr) {
  u64 w = 0;
#pragma unroll
  for (int q = 0; q < 4; ++q) {
    f16 h = (f16)hn4[q];
    unsigned own = (unsigned)__builtin_bit_cast(unsigned short, h);
    unsigned p1 = (unsigned)__shfl_xor((int)own, 1, 64);
    unsigned v32 = (lr & 1) ? ((own << 16) | p1) : (own | (p1 << 16));
    unsigned o2 = (unsigned)__shfl_xor((int)v32, 2, 64);
    u64 v64 = (lr & 2) ? (((u64)v32 << 32) | (u64)o2) : (((u64)o2 << 32) | (u64)v32);
    if ((lr & 3) == q) w = v64;
  }
  return w;
}

// 16B coherent write-through store (2 rows' worth merged per lane pair).
__device__ inline void st16_coh(f16* p, u32x4 v) {
  asm volatile("global_store_dwordx4 %0, %1, off sc0 sc1" :: "v"(p), "v"(v) : "memory");
}

// Load 48 gate-rows (triplet j) of W [3072][K8*8] into LDS, XOR-swizzled per 16B unit.
template <int K8>
__device__ void load_w(f16* dst, const f16* W, int j) {
  for (int u = threadIdx.x; u < 48 * K8; u += WGSZ) {
    int row = u / K8, k8 = u - row * K8;
    int gcol = (row >> 4) * 1024 + j * 16 + (row & 15);
    f16x8 v = *(const f16x8*)(W + (size_t)gcol * (size_t)(K8 * 8) + (size_t)k8 * 8);
    *(f16x8*)(dst + ((size_t)row * K8 + (size_t)(k8 ^ (row & 7))) * 8) = v;
  }
}

template <int K8>
__device__ inline f16x8 ldb(const f16* base, int row, int u8) {
  return *(const f16x8*)(base + ((size_t)row * K8 + (size_t)(u8 ^ (row & 7))) * 8);
}

}  // namespace gru

// ---------------- prep kernels ----------------

__global__ void gru_k_pe(float* pe) {
  int idx = blockIdx.x * 256 + threadIdx.x;
  if (idx >= 1024 * 512) return;
  int t = idx >> 9, d = idx & 511;
  int jj = d >> 1;
  float freq = expf(-logf(10000.f) * (float)(2 * jj) * (1.f / 512.f));
  float ang = (float)t * freq;
  pe[idx] = (d & 1) ? cosf(ang) : sinf(ang);
}

__global__ void gru_k_x16(const float* __restrict__ x, const float* __restrict__ pe,
                          f16* __restrict__ x16) {
  int d = blockIdx.x * 256 + threadIdx.x;  // grid.x = 2
  int t = blockIdx.y, b = blockIdx.z;
  float v = x[((size_t)b * 1024 + t) * 512 + d] + pe[t * 512 + d];
  x16[((size_t)t * 64 + b) * 512 + d] = (f16)v;
}

__global__ void gru_k_f16(const float* __restrict__ src, f16* __restrict__ dst, int n) {
  int i = blockIdx.x * 256 + threadIdx.x;
  if (i < n) dst[i] = (f16)src[i];
}

// ---------------- main persistent pipelined kernel ----------------
// Batch split into 2 independent groups of 32 rows (R9 layout):
//   xcd = wg%8:  xcd>>2 = group;  (xcd>>1)&1 = role (0=L0, 1=L1);
//   wgid = ((xcd&1)<<5) | (wg>>3)  in 0..63  -> gate-column triplet j.
// Sync per side: private bump -> designee (wgid 0) scan-loop -> push-broadcast
// to private mailboxes. Flag regions per group (stride 32 dwords = 128B/word):
//   0: prod0[64]  1: prod1[64]  2: mbA (done0->L0)  3: mbB (done0->L1)
//   4: mbC (done1->L1)  5: mbD (done1->L0, ring guard)

__global__ __launch_bounds__(WGSZ, 1) void gru_main(gru::Args A) {
  using namespace gru;
  __shared__ SMem sm;
  const int wg = blockIdx.x, tid = threadIdx.x;
  const int xcd = wg & 7, slot = wg >> 3;
  const int grp = xcd >> 2;
  const bool isL0 = ((xcd >> 1) & 1) == 0;
  const int wgid = ((xcd & 1) << 5) | slot;
  const int j = wgid;
  const int wave = tid >> 6, lane = tid & 63;
  const int lr = lane & 15, lk8 = lane >> 4;
  const int lk = lk8 * 8, dr = lk8 * 4;
  const int rt = wave >> 1, kh = wave & 1;  // rowtile, K-half per wave
  const int rowbase = rt * 16;              // within the group's 32 rows
  const int gb = grp * 32;                  // global batch base

  f16* h0g = A.h0 + (size_t)grp * RING * 32 * 1024;
  f16* h1g = A.h1 + (size_t)grp * RING * 32 * 1024;
  unsigned* fg = A.flg + (size_t)grp * 6 * 2048;
  unsigned* prod0 = fg;
  unsigned* prod1 = fg + 2048;
  unsigned* mbA = fg + 2 * 2048;
  unsigned* mbB = fg + 3 * 2048;
  unsigned* mbC = fg + 4 * 2048;
  unsigned* mbD = fg + 5 * 2048;

  __threadfence();  // cross-replay cache hygiene (once; before any cached read)

  ((float*)sm.hm)[tid] = 0.f;
  ((float*)sm.hm)[tid + 256] = 0.f;

  if (isL0) {
    load_w<128>(sm.wA, A.whh0, j);
    load_w<64>(sm.wB, A.wih0, j);
    if (tid < 48) {
      int gcol = (tid >> 4) * 1024 + j * 16 + (tid & 15);
      sm.bI[tid] = A.bih0[gcol];
      sm.bH[tid] = A.bhh0[gcol];
    }
  } else {
    load_w<128>(sm.wA, A.whh1, j);
    if (tid < 48) {
      int gcol = (tid >> 4) * 1024 + j * 16 + (tid & 15);
      sm.bI[tid] = A.bih1[gcol];
      sm.bH[tid] = A.bhh1[gcol];
    }
  }
  __syncthreads();

  if (isL0) {
    // =============== layer-0 ===============
    f16x8 xf[2][8];
    {
      const f16* xp = A.x16 + ((size_t)0 * 64 + gb + rowbase + lr) * 512 + kh * 256 + lk;
#pragma unroll
      for (int q2 = 0; q2 < 8; ++q2) xf[0][q2] = *(const f16x8*)(xp + q2 * 32);
    }
    for (int t = 0; t < 1024; ++t) {
      if ((t % INVP) == INVP - 1) __threadfence();  // periodic L1/L2 invalidate
      if (tid == 0) {  // private-mailbox waits: done0[t-1]; ring guard done1
        if (t > 0)
          while (aldu(mbA + wgid * 32) < (unsigned)t) __builtin_amdgcn_s_sleep(2);
        if (t >= 60)
          while (aldu(mbD + wgid * 32) + 59u < (unsigned)t) __builtin_amdgcn_s_sleep(2);
      }
      __syncthreads();
      const int cur = t & 1;
      if (t + 1 < 1024) {  // prefetch next x EARLY: completes under the MFMAs
        const f16* xp = A.x16 + ((size_t)(t + 1) * 64 + gb + rowbase + lr) * 512 + kh * 256 + lk;
#pragma unroll
        for (int q2 = 0; q2 < 8; ++q2) xf[cur ^ 1][q2] = *(const f16x8*)(xp + q2 * 32);
      }
      const f16* hp = h0g + ((size_t)((t + RING - 1) & (RING - 1)) * 32 + rowbase + lr) * 1024 + kh * 512 + lk;
      f16x8 hf[16];
#pragma unroll
      for (int q2 = 0; q2 < 16; ++q2) hf[q2] = *(const f16x8*)(hp + q2 * 32);  // CACHED
      f32x4 a0 = {0.f, 0.f, 0.f, 0.f}, a1 = a0, a2 = a0, a3 = a0;
#pragma unroll
      for (int q2 = 0; q2 < 8; ++q2) {
        const int u8 = (kh * 8 + q2) * 4 + lk8;
        a0 = mf(xf[cur][q2], ldb<64>(sm.wB, lr, u8), a0);
        a1 = mf(xf[cur][q2], ldb<64>(sm.wB, 16 + lr, u8), a1);
        a2 = mf(xf[cur][q2], ldb<64>(sm.wB, 32 + lr, u8), a2);  // i_n
      }
#pragma unroll
      for (int q2 = 0; q2 < 16; ++q2) {
        const int u8 = (kh * 16 + q2) * 4 + lk8;
        a0 = mf(hf[q2], ldb<128>(sm.wA, lr, u8), a0);
        a1 = mf(hf[q2], ldb<128>(sm.wA, 16 + lr, u8), a1);
        a3 = mf(hf[q2], ldb<128>(sm.wA, 32 + lr, u8), a3);  // h_n
      }
      if (kh) {
#pragma unroll
        for (int q = 0; q < 4; ++q) {
          sm.sc[rt][0][q][lane] = a0[q]; sm.sc[rt][1][q][lane] = a1[q];
          sm.sc[rt][2][q][lane] = a2[q]; sm.sc[rt][3][q][lane] = a3[q];
        }
      }
      __syncthreads();
      if (!kh) {
        float hn4[4];
#pragma unroll
        for (int q = 0; q < 4; ++q) {
          a0[q] += sm.sc[rt][0][q][lane]; a1[q] += sm.sc[rt][1][q][lane];
          a2[q] += sm.sc[rt][2][q][lane]; a3[q] += sm.sc[rt][3][q][lane];
        }
#pragma unroll
        for (int q = 0; q < 4; ++q) {
          const int row = rt * 16 + dr + q;
          float r = sigf(a0[q] + sm.bI[lr] + sm.bH[lr]);
          float z = sigf(a1[q] + sm.bI[16 + lr] + sm.bH[16 + lr]);
          float n = tanh_fast(a2[q] + sm.bI[32 + lr] + r * (a3[q] + sm.bH[32 + lr]));
          float hn = n + z * (sm.hm[row][lr] - n);
          sm.hm[row][lr] = hn;
          hn4[q] = hn;
        }
        u64 w = pack4(hn4, lr);
        unsigned wlo = (unsigned)w, whi = (unsigned)(w >> 32);
        unsigned plo = (unsigned)__shfl_xor((int)wlo, 4, 64);
        unsigned phi = (unsigned)__shfl_xor((int)whi, 4, 64);
        if ((lr & 4) == 0) {  // lane pair merged: 16B per store, 64 stores/WG
          const int srow = rt * 16 + dr + (lr & 3);
          u32x4 v4 = {wlo, whi, plo, phi};
          st16_coh(h0g + ((size_t)(t & (RING - 1)) * 32 + srow) * 1024 + j * 16 + (lr & ~7), v4);
        }
      }
      __syncthreads();  // drains WT stores (vmcnt) before the signal
      if (wave == 0) {
        if (lane == 0) astu(prod0 + wgid * 32, (unsigned)(t + 1));  // private bump
        if (wgid == 0) {  // designee: scan private counters, push-broadcast
          for (;;) {
            unsigned v = aldu(prod0 + lane * 32);
            if (__all((v >= (unsigned)(t + 1)) || (lane == 0))) break;
            __builtin_amdgcn_s_sleep(1);
          }
          astu(mbA + lane * 32, (unsigned)(t + 1));
          astu(mbB + lane * 32, (unsigned)(t + 1));
        }
      }
    }
  } else {
    // =============== layer-1 ===============
    for (int t = 0; t < 1024; ++t) {
      if ((t % INVP) == INVP - 1) __threadfence();
      if (tid == 0) {  // waits: done0[t] and done1[t-1]
        while (aldu(mbB + wgid * 32) < (unsigned)(t + 1)) __builtin_amdgcn_s_sleep(2);
        if (t > 0)
          while (aldu(mbC + wgid * 32) < (unsigned)t) __builtin_amdgcn_s_sleep(2);
      }
      __syncthreads();
      const f16* gp = h0g + ((size_t)(t & (RING - 1)) * 32 + rowbase + lr) * 1024 + kh * 512 + lk;
      const f16* hp = h1g + ((size_t)((t + RING - 1) & (RING - 1)) * 32 + rowbase + lr) * 1024 + kh * 512 + lk;
      f16x8 gf[16], hf[16];
#pragma unroll
      for (int q2 = 0; q2 < 16; ++q2) gf[q2] = *(const f16x8*)(gp + q2 * 32);  // CACHED
#pragma unroll
      for (int q2 = 0; q2 < 16; ++q2) hf[q2] = *(const f16x8*)(hp + q2 * 32);  // CACHED
      f32x4 a0 = {0.f, 0.f, 0.f, 0.f}, a1 = a0, a2 = a0, a3 = a0;
      const f16* wb = A.wih1 + ((size_t)(j * 16 + lr)) * 1024 + kh * 512 + lk;
#pragma unroll
      for (int q2 = 0; q2 < 16; ++q2) {
        const size_t o = (size_t)q2 * 32;
        a0 = mf(gf[q2], *(const f16x8*)(wb + o), a0);
        a1 = mf(gf[q2], *(const f16x8*)(wb + (size_t)1024 * 1024 + o), a1);
        a2 = mf(gf[q2], *(const f16x8*)(wb + (size_t)2048 * 1024 + o), a2);  // i_n
      }
#pragma unroll
      for (int q2 = 0; q2 < 16; ++q2) {
        const int u8 = (kh * 16 + q2) * 4 + lk8;
        a0 = mf(hf[q2], ldb<128>(sm.wA, lr, u8), a0);
        a1 = mf(hf[q2], ldb<128>(sm.wA, 16 + lr, u8), a1);
        a3 = mf(hf[q2], ldb<128>(sm.wA, 32 + lr, u8), a3);  // h_n
      }
      if (kh) {
#pragma unroll
        for (int q = 0; q < 4; ++q) {
          sm.sc[rt][0][q][lane] = a0[q]; sm.sc[rt][1][q][lane] = a1[q];
          sm.sc[rt][2][q][lane] = a2[q]; sm.sc[rt][3][q][lane] = a3[q];
        }
      }
      __syncthreads();
      if (!kh) {
        float hn4[4];
#pragma unroll
        for (int q = 0; q < 4; ++q) {
          a0[q] += sm.sc[rt][0][q][lane]; a1[q] += sm.sc[rt][1][q][lane];
          a2[q] += sm.sc[rt][2][q][lane]; a3[q] += sm.sc[rt][3][q][lane];
        }
#pragma unroll
        for (int q = 0; q < 4; ++q) {
          const int row = rt * 16 + dr + q;
          float r = sigf(a0[q] + sm.bI[lr] + sm.bH[lr]);
          float z = sigf(a1[q] + sm.bI[16 + lr] + sm.bH[16 + lr]);
          float n = tanh_fast(a2[q] + sm.bI[32 + lr] + r * (a3[q] + sm.bH[32 + lr]));
          float hn = n + z * (sm.hm[row][lr] - n);
          sm.hm[row][lr] = hn;
          hn4[q] = hn;
        }
        u64 w = pack4(hn4, lr);
        unsigned wlo = (unsigned)w, whi = (unsigned)(w >> 32);
        unsigned plo = (unsigned)__shfl_xor((int)wlo, 4, 64);
        unsigned phi = (unsigned)__shfl_xor((int)whi, 4, 64);
        if ((lr & 4) == 0) {
          const int srow = rt * 16 + dr + (lr & 3);
          u32x4 v4 = {wlo, whi, plo, phi};
          st16_coh(h1g + ((size_t)(t & (RING - 1)) * 32 + srow) * 1024 + j * 16 + (lr & ~7), v4);
        }
      }
      __syncthreads();
      if (wave == 0) {
        if (lane == 0) astu(prod1 + wgid * 32, (unsigned)(t + 1));
        if (wgid == 0) {
          for (;;) {
            unsigned v = aldu(prod1 + lane * 32);
            if (__all((v >= (unsigned)(t + 1)) || (lane == 0))) break;
            __builtin_amdgcn_s_sleep(1);
          }
          astu(mbC + lane * 32, (unsigned)(t + 1));
          astu(mbD + lane * 32, (unsigned)(t + 1));
        }
      }
    }

    // ---- output projection: out rows gb..gb+31 = h1(1023) @ w_out^T + b_out ----
    if (tid == 0)
      while (aldu(mbC + wgid * 32) < 1024u) __builtin_amdgcn_s_sleep(2);
    __syncthreads();
    const int j2 = wgid & 31, rg2 = wgid >> 5;
    f32x4 acc = {0.f, 0.f, 0.f, 0.f};
    if (wave < 2) {
      const f16* Ah = h1g + ((size_t)(RING - 1) * 32 + rg2 * 16 + lr) * 1024 + wave * 512 + lk;
      const f16* Bp = A.wout + ((size_t)(j2 * 16 + lr)) * 1024 + wave * 512 + lk;
#pragma unroll
      for (int q2 = 0; q2 < 16; ++q2)
        acc = mf(*(const f16x8*)(Ah + q2 * 32), *(const f16x8*)(Bp + q2 * 32), acc);
    }
    if (wave == 1) {
#pragma unroll
      for (int q = 0; q < 4; ++q) sm.sc[0][0][q][lane] = acc[q];
    }
    __syncthreads();
    if (wave == 0) {
#pragma unroll
      for (int q = 0; q < 4; ++q) {
        float v = acc[q] + sm.sc[0][0][q][lane] + A.bout[j2 * 16 + lr];
        A.out[(gb + rg2 * 16 + dr + q) * 512 + j2 * 16 + lr] = v;
      }
    }
  }
}

// ---------------- host ----------------

extern "C" void kernel_launch(void* const* d_in, const int* in_sizes, int n_in,
                              void* d_out, int out_size, void* d_ws, size_t ws_size,
                              hipStream_t stream) {
  (void)in_sizes; (void)n_in; (void)out_size; (void)ws_size;
  const float* x = (const float*)d_in[0];
  const float* w_ih0 = (const float*)d_in[1];
  const float* w_hh0 = (const float*)d_in[2];
  const float* b_ih0 = (const float*)d_in[3];
  const float* b_hh0 = (const float*)d_in[4];
  const float* w_ih1 = (const float*)d_in[5];
  const float* w_hh1 = (const float*)d_in[6];
  const float* b_ih1 = (const float*)d_in[7];
  const float* b_hh1 = (const float*)d_in[8];
  const float* w_out = (const float*)d_in[9];
  const float* b_out = (const float*)d_in[10];

  char* ws = (char*)d_ws;
  size_t off = 0;
  auto alloc = [&](size_t b) {
    off = (off + 255) & ~(size_t)255;
    char* p = ws + off;
    off += b;
    return p;
  };

  float* pe = (float*)alloc((size_t)1024 * 512 * 4);
  f16* x16 = (f16*)alloc((size_t)1024 * 64 * 512 * 2);
  f16* wih0 = (f16*)alloc((size_t)3072 * 512 * 2);
  f16* whh0 = (f16*)alloc((size_t)3072 * 1024 * 2);
  f16* wih1 = (f16*)alloc((size_t)3072 * 1024 * 2);
  f16* whh1 = (f16*)alloc((size_t)3072 * 1024 * 2);
  f16* wout = (f16*)alloc((size_t)512 * 1024 * 2);
  f16* h0r = (f16*)alloc((size_t)2 * RING * 32 * 1024 * 2);
  f16* h1r = (f16*)alloc((size_t)2 * RING * 32 * 1024 * 2);
  unsigned* flg = (unsigned*)alloc(2 * 6 * 2048 * 4);  // 96 KB flag regions

  // per-call init: flags zero; ring slot RING-1 (initial h=0) zero, per group
  (void)hipMemsetAsync(flg, 0, 2 * 6 * 2048 * 4, stream);
  for (int g = 0; g < 2; ++g) {
    (void)hipMemsetAsync(h0r + ((size_t)g * RING + RING - 1) * 32 * 1024, 0, (size_t)32 * 1024 * 2, stream);
    (void)hipMemsetAsync(h1r + ((size_t)g * RING + RING - 1) * 32 * 1024, 0, (size_t)32 * 1024 * 2, stream);
  }

  gru_k_pe<<<(1024 * 512 + 255) / 256, 256, 0, stream>>>(pe);
  gru_k_x16<<<dim3(2, 1024, 64), 256, 0, stream>>>(x, pe, x16);
  gru_k_f16<<<(3072 * 512 + 255) / 256, 256, 0, stream>>>(w_ih0, wih0, 3072 * 512);
  gru_k_f16<<<(3072 * 1024 + 255) / 256, 256, 0, stream>>>(w_hh0, whh0, 3072 * 1024);
  gru_k_f16<<<(3072 * 1024 + 255) / 256, 256, 0, stream>>>(w_ih1, wih1, 3072 * 1024);
  gru_k_f16<<<(3072 * 1024 + 255) / 256, 256, 0, stream>>>(w_hh1, whh1, 3072 * 1024);
  gru_k_f16<<<(512 * 1024 + 255) / 256, 256, 0, stream>>>(w_out, wout, 512 * 1024);

  gru::Args A;
  A.x16 = x16;
  A.bih0 = b_ih0; A.bhh0 = b_hh0; A.bih1 = b_ih1; A.bhh1 = b_hh1; A.bout = b_out;
  A.wih0 = wih0; A.whh0 = whh0; A.wih1 = wih1; A.whh1 = whh1; A.wout = wout;
  A.h0 = h0r; A.h1 = h1r;
  A.out = (float*)d_out;
  A.flg = flg;

  // Plain launch: 256 blocks x 1 block/CU (LDS-bound) on 256 CUs -> co-resident.
  gru_main<<<dim3(NWG), dim3(WGSZ), 0, stream>>>(A);
}

// Round 11
// 11655.952 us; speedup vs baseline: 3.5611x; 1.0067x over previous
//
#include <hip/hip_runtime.h>
#include <cstdint>
#include <cstddef>

typedef _Float16 f16;
typedef _Float16 f16x8 __attribute__((ext_vector_type(8)));
typedef float f32x4 __attribute__((ext_vector_type(4)));
typedef unsigned u32x4 __attribute__((ext_vector_type(4)));
typedef unsigned long long u64;

#define NWG 256
#define WGSZ 256
#define RING 256   // h-ring depth; addr reuse every RING steps
#define FSTEP 160  // per-WG fence period (staggered); must be < RING w/ margin

namespace gru {

__device__ inline f32x4 mf(f16x8 a, f16x8 b, f32x4 c) {
  return __builtin_amdgcn_mfma_f32_16x16x32_f16(a, b, c, 0, 0, 0);
}
__device__ inline float sigf(float x) { return 1.f / (1.f + __expf(-x)); }
__device__ inline float tanh_fast(float x) {
  float xx = fminf(fmaxf(x, -15.f), 15.f);
  float e = __expf(-2.f * xx);
  return (1.f - e) / (1.f + e);
}

struct SMem {
  f16 wA[48 * 1024];      // 96 KB: whh0 (L0) or whh1 (L1), swizzled
  f16 wB[48 * 512];       // 48 KB: wih0 (L0) or wih1 K-half 0 (L1), swizzled
  float sc[2][4][4][64];  // 8 KB pairwise-reduce scratch
  float hm[32][16];       // fp32 master h tile (this WG's 32 rows x 16 cols)
  float bI[48], bH[48];
};

struct Args {
  const f16* x16;
  const float* bih0; const float* bhh0; const float* bih1; const float* bhh1; const float* bout;
  const f16* wih0; const f16* whh0; const f16* wih1; const f16* whh1; const f16* wout;
  f16* h0;   // per-group rings: [2][RING][32][1024]
  f16* h1;   // per-group rings: [2][RING][32][1024]
  float* out;
  unsigned* flg;  // per group: prod0[64], prod1[64], 128B stride each
};

// ---- sync: private per-WG producer counters; consumers DIRECT-poll all 64
// with wave0's 64 lanes (1 line per lane). No designee, no broadcast hop.

__device__ inline unsigned aldu(const unsigned* p) {
  return __hip_atomic_load(p, __ATOMIC_RELAXED, __HIP_MEMORY_SCOPE_AGENT);
}
__device__ inline void astu(unsigned* p, unsigned v) {
  __hip_atomic_store(p, v, __ATOMIC_RELAXED, __HIP_MEMORY_SCOPE_AGENT);
}

// Pack this lane's 4 gate outputs (rows dr..dr+3 of col lr) into one u64 holding
// 4 adjacent cols of ONE row, via 2x shfl_xor across the 4-lane col-group.
__device__ inline u64 pack4(const float* hn4, int lr) {
  u64 w = 0;
#pragma unroll
  for (int q = 0; q < 4; ++q) {
    f16 h = (f16)hn4[q];
    unsigned own = (unsigned)__builtin_bit_cast(unsigned short, h);
    unsigned p1 = (unsigned)__shfl_xor((int)own, 1, 64);
    unsigned v32 = (lr & 1) ? ((own << 16) | p1) : (own | (p1 << 16));
    unsigned o2 = (unsigned)__shfl_xor((int)v32, 2, 64);
    u64 v64 = (lr & 2) ? (((u64)v32 << 32) | (u64)o2) : (((u64)o2 << 32) | (u64)v32);
    if ((lr & 3) == q) w = v64;
  }
  return w;
}

// 16B coherent write-through store (2 rows' worth merged per lane pair).
__device__ inline void st16_coh(f16* p, u32x4 v) {
  asm volatile("global_store_dwordx4 %0, %1, off sc0 sc1" :: "v"(p), "v"(v) : "memory");
}

// Load 48 gate-rows (triplet j) of W into LDS, XOR-swizzled per 16B unit.
// K8 = dest K-units (8 f16 each); SK8 = source row stride in K-units.
template <int K8, int SK8>
__device__ void load_w(f16* dst, const f16* W, int j) {
  for (int u = threadIdx.x; u < 48 * K8; u += WGSZ) {
    int row = u / K8, k8 = u - row * K8;
    int gcol = (row >> 4) * 1024 + j * 16 + (row & 15);
    f16x8 v = *(const f16x8*)(W + (size_t)gcol * (size_t)(SK8 * 8) + (size_t)k8 * 8);
    *(f16x8*)(dst + ((size_t)row * K8 + (size_t)(k8 ^ (row & 7))) * 8) = v;
  }
}

template <int K8>
__device__ inline f16x8 ldb(const f16* base, int row, int u8) {
  return *(const f16x8*)(base + ((size_t)row * K8 + (size_t)(u8 ^ (row & 7))) * 8);
}

}  // namespace gru

// ---------------- prep kernels ----------------

__global__ void gru_k_pe(float* pe) {
  int idx = blockIdx.x * 256 + threadIdx.x;
  if (idx >= 1024 * 512) return;
  int t = idx >> 9, d = idx & 511;
  int jj = d >> 1;
  float freq = expf(-logf(10000.f) * (float)(2 * jj) * (1.f / 512.f));
  float ang = (float)t * freq;
  pe[idx] = (d & 1) ? cosf(ang) : sinf(ang);
}

__global__ void gru_k_x16(const float* __restrict__ x, const float* __restrict__ pe,
                          f16* __restrict__ x16) {
  int d = blockIdx.x * 256 + threadIdx.x;  // grid.x = 2
  int t = blockIdx.y, b = blockIdx.z;
  float v = x[((size_t)b * 1024 + t) * 512 + d] + pe[t * 512 + d];
  x16[((size_t)t * 64 + b) * 512 + d] = (f16)v;
}

__global__ void gru_k_f16(const float* __restrict__ src, f16* __restrict__ dst, int n) {
  int i = blockIdx.x * 256 + threadIdx.x;
  if (i < n) dst[i] = (f16)src[i];
}

// ---------------- main persistent pipelined kernel ----------------
// 2 independent groups x 32 batch rows (R9 layout):
//   xcd = wg%8: xcd>>2 = group; (xcd>>1)&1 = role; wgid = ((xcd&1)<<5)|(wg>>3).
// Sync: private counters + direct dual-scan poll by each consumer's wave 0.
// Fences: rare and per-WG-staggered (RING=256 gives a huge reuse window, and
// every XCD's L2 is invalidated by resident WGs far more often than RING).

__global__ __launch_bounds__(WGSZ, 1) void gru_main(gru::Args A) {
  using namespace gru;
  __shared__ SMem sm;
  const int wg = blockIdx.x, tid = threadIdx.x;
  const int xcd = wg & 7, slot = wg >> 3;
  const int grp = xcd >> 2;
  const bool isL0 = ((xcd >> 1) & 1) == 0;
  const int wgid = ((xcd & 1) << 5) | slot;
  const int j = wgid;
  const int wave = tid >> 6, lane = tid & 63;
  const int lr = lane & 15, lk8 = lane >> 4;
  const int lk = lk8 * 8, dr = lk8 * 4;
  const int rt = wave >> 1, kh = wave & 1;  // rowtile, K-half per wave
  const int rowbase = rt * 16;              // within the group's 32 rows
  const int gb = grp * 32;                  // global batch base
  const int fph = (wgid * 5 + (isL0 ? 0 : 80)) % FSTEP;  // staggered fence phase

  f16* h0g = A.h0 + (size_t)grp * RING * 32 * 1024;
  f16* h1g = A.h1 + (size_t)grp * RING * 32 * 1024;
  unsigned* prod0 = A.flg + (size_t)grp * 2 * 2048;
  unsigned* prod1 = prod0 + 2048;

  __threadfence();  // cross-replay cache hygiene (once; before any cached read)

  ((float*)sm.hm)[tid] = 0.f;
  ((float*)sm.hm)[tid + 256] = 0.f;

  if (isL0) {
    load_w<128, 128>(sm.wA, A.whh0, j);
    load_w<64, 64>(sm.wB, A.wih0, j);
    if (tid < 48) {
      int gcol = (tid >> 4) * 1024 + j * 16 + (tid & 15);
      sm.bI[tid] = A.bih0[gcol];
      sm.bH[tid] = A.bhh0[gcol];
    }
  } else {
    load_w<128, 128>(sm.wA, A.whh1, j);
    load_w<64, 128>(sm.wB, A.wih1, j);  // wih1 K-half 0 staged in LDS
    if (tid < 48) {
      int gcol = (tid >> 4) * 1024 + j * 16 + (tid & 15);
      sm.bI[tid] = A.bih1[gcol];
      sm.bH[tid] = A.bhh1[gcol];
    }
  }
  __syncthreads();

  if (isL0) {
    // =============== layer-0 ===============
    f16x8 xf[2][8];
    {
      const f16* xp = A.x16 + ((size_t)0 * 64 + gb + rowbase + lr) * 512 + kh * 256 + lk;
#pragma unroll
      for (int q2 = 0; q2 < 8; ++q2) xf[0][q2] = *(const f16x8*)(xp + q2 * 32);
    }
    for (int t = 0; t < 1024; ++t) {
      if (t != 0 && (t % FSTEP) == fph) __threadfence();  // rare, staggered
      const int cur = t & 1;
      f32x4 a0 = {0.f, 0.f, 0.f, 0.f}, a1 = a0, a2 = a0, a3 = a0;
      // ---- x-part MFMAs BEFORE the wait (independent of h) ----
#pragma unroll
      for (int q2 = 0; q2 < 8; ++q2) {
        const int u8 = (kh * 8 + q2) * 4 + lk8;
        a0 = mf(xf[cur][q2], ldb<64>(sm.wB, lr, u8), a0);
        a1 = mf(xf[cur][q2], ldb<64>(sm.wB, 16 + lr, u8), a1);
        a2 = mf(xf[cur][q2], ldb<64>(sm.wB, 32 + lr, u8), a2);  // i_n
      }
      if (t + 1 < 1024) {  // prefetch next x; completes under wait + h-MFMAs
        const f16* xp = A.x16 + ((size_t)(t + 1) * 64 + gb + rowbase + lr) * 512 + kh * 256 + lk;
#pragma unroll
        for (int q2 = 0; q2 < 8; ++q2) xf[cur ^ 1][q2] = *(const f16x8*)(xp + q2 * 32);
      }
      // ---- direct dual-scan wait: all prod0 >= t; ring guard on prod1 ----
      if (wave == 0) {
        const unsigned need0 = (unsigned)t;
        const unsigned need1 = (t > 200) ? (unsigned)(t - 200) : 0u;
        const unsigned* p0 = prod0 + lane * 32;
        const unsigned* p1 = prod1 + lane * 32;
        for (;;) {
          unsigned v0 = aldu(p0), v1 = aldu(p1);
          if (__all((v0 >= need0) && (v1 >= need1))) break;
          __builtin_amdgcn_s_sleep(1);
        }
      }
      __syncthreads();
      const f16* hp = h0g + ((size_t)((t + RING - 1) & (RING - 1)) * 32 + rowbase + lr) * 1024 + kh * 512 + lk;
      f16x8 hf[16];
#pragma unroll
      for (int q2 = 0; q2 < 16; ++q2) hf[q2] = *(const f16x8*)(hp + q2 * 32);  // CACHED
#pragma unroll
      for (int q2 = 0; q2 < 16; ++q2) {
        const int u8 = (kh * 16 + q2) * 4 + lk8;
        a0 = mf(hf[q2], ldb<128>(sm.wA, lr, u8), a0);
        a1 = mf(hf[q2], ldb<128>(sm.wA, 16 + lr, u8), a1);
        a3 = mf(hf[q2], ldb<128>(sm.wA, 32 + lr, u8), a3);  // h_n
      }
      if (kh) {
#pragma unroll
        for (int q = 0; q < 4; ++q) {
          sm.sc[rt][0][q][lane] = a0[q]; sm.sc[rt][1][q][lane] = a1[q];
          sm.sc[rt][2][q][lane] = a2[q]; sm.sc[rt][3][q][lane] = a3[q];
        }
      }
      __syncthreads();
      if (!kh) {
        float hn4[4];
#pragma unroll
        for (int q = 0; q < 4; ++q) {
          a0[q] += sm.sc[rt][0][q][lane]; a1[q] += sm.sc[rt][1][q][lane];
          a2[q] += sm.sc[rt][2][q][lane]; a3[q] += sm.sc[rt][3][q][lane];
        }
#pragma unroll
        for (int q = 0; q < 4; ++q) {
          const int row = rt * 16 + dr + q;
          float r = sigf(a0[q] + sm.bI[lr] + sm.bH[lr]);
          float z = sigf(a1[q] + sm.bI[16 + lr] + sm.bH[16 + lr]);
          float n = tanh_fast(a2[q] + sm.bI[32 + lr] + r * (a3[q] + sm.bH[32 + lr]));
          float hn = n + z * (sm.hm[row][lr] - n);
          sm.hm[row][lr] = hn;
          hn4[q] = hn;
        }
        u64 w = pack4(hn4, lr);
        unsigned wlo = (unsigned)w, whi = (unsigned)(w >> 32);
        unsigned plo = (unsigned)__shfl_xor((int)wlo, 4, 64);
        unsigned phi = (unsigned)__shfl_xor((int)whi, 4, 64);
        if ((lr & 4) == 0) {  // lane pair merged: 16B per store
          const int srow = rt * 16 + dr + (lr & 3);
          u32x4 v4 = {wlo, whi, plo, phi};
          st16_coh(h0g + ((size_t)(t & (RING - 1)) * 32 + srow) * 1024 + j * 16 + (lr & ~7), v4);
        }
      }
      __syncthreads();  // drains WT stores (vmcnt) before the signal
      if (tid == 0) astu(prod0 + wgid * 32, (unsigned)(t + 1));  // private signal
    }
  } else {
    // =============== layer-1 ===============
    for (int t = 0; t < 1024; ++t) {
      if (t != 0 && (t % FSTEP) == fph) __threadfence();
      // ---- direct dual-scan wait: prod0 >= t+1 (h0(t)); prod1 >= t (h1(t-1)) ----
      if (wave == 0) {
        const unsigned need0 = (unsigned)(t + 1);
        const unsigned need1 = (unsigned)t;
        const unsigned* p0 = prod0 + lane * 32;
        const unsigned* p1 = prod1 + lane * 32;
        for (;;) {
          unsigned v0 = aldu(p0), v1 = aldu(p1);
          if (__all((v0 >= need0) && (v1 >= need1))) break;
          __builtin_amdgcn_s_sleep(1);
        }
      }
      __syncthreads();
      const f16* gp = h0g + ((size_t)(t & (RING - 1)) * 32 + rowbase + lr) * 1024 + kh * 512 + lk;
      const f16* hp = h1g + ((size_t)((t + RING - 1) & (RING - 1)) * 32 + rowbase + lr) * 1024 + kh * 512 + lk;
      f16x8 gf[16], hf[16];
#pragma unroll
      for (int q2 = 0; q2 < 16; ++q2) gf[q2] = *(const f16x8*)(gp + q2 * 32);  // CACHED
#pragma unroll
      for (int q2 = 0; q2 < 16; ++q2) hf[q2] = *(const f16x8*)(hp + q2 * 32);  // CACHED
      f32x4 a0 = {0.f, 0.f, 0.f, 0.f}, a1 = a0, a2 = a0, a3 = a0;
      if (kh == 0) {
        // gi1 K-half 0 from LDS (staged once) -- no per-step L2 streaming
#pragma unroll
        for (int q2 = 0; q2 < 16; ++q2) {
          const int u8 = q2 * 4 + lk8;
          a0 = mf(gf[q2], ldb<64>(sm.wB, lr, u8), a0);
          a1 = mf(gf[q2], ldb<64>(sm.wB, 16 + lr, u8), a1);
          a2 = mf(gf[q2], ldb<64>(sm.wB, 32 + lr, u8), a2);  // i_n
        }
      } else {
        const f16* wb = A.wih1 + ((size_t)(j * 16 + lr)) * 1024 + 512 + lk;
#pragma unroll
        for (int q2 = 0; q2 < 16; ++q2) {
          const size_t o = (size_t)q2 * 32;
          a0 = mf(gf[q2], *(const f16x8*)(wb + o), a0);
          a1 = mf(gf[q2], *(const f16x8*)(wb + (size_t)1024 * 1024 + o), a1);
          a2 = mf(gf[q2], *(const f16x8*)(wb + (size_t)2048 * 1024 + o), a2);  // i_n
        }
      }
#pragma unroll
      for (int q2 = 0; q2 < 16; ++q2) {
        const int u8 = (kh * 16 + q2) * 4 + lk8;
        a0 = mf(hf[q2], ldb<128>(sm.wA, lr, u8), a0);
        a1 = mf(hf[q2], ldb<128>(sm.wA, 16 + lr, u8), a1);
        a3 = mf(hf[q2], ldb<128>(sm.wA, 32 + lr, u8), a3);  // h_n
      }
      if (kh) {
#pragma unroll
        for (int q = 0; q < 4; ++q) {
          sm.sc[rt][0][q][lane] = a0[q]; sm.sc[rt][1][q][lane] = a1[q];
          sm.sc[rt][2][q][lane] = a2[q]; sm.sc[rt][3][q][lane] = a3[q];
        }
      }
      __syncthreads();
      if (!kh) {
        float hn4[4];
#pragma unroll
        for (int q = 0; q < 4; ++q) {
          a0[q] += sm.sc[rt][0][q][lane]; a1[q] += sm.sc[rt][1][q][lane];
          a2[q] += sm.sc[rt][2][q][lane]; a3[q] += sm.sc[rt][3][q][lane];
        }
#pragma unroll
        for (int q = 0; q < 4; ++q) {
          const int row = rt * 16 + dr + q;
          float r = sigf(a0[q] + sm.bI[lr] + sm.bH[lr]);
          float z = sigf(a1[q] + sm.bI[16 + lr] + sm.bH[16 + lr]);
          float n = tanh_fast(a2[q] + sm.bI[32 + lr] + r * (a3[q] + sm.bH[32 + lr]));
          float hn = n + z * (sm.hm[row][lr] - n);
          sm.hm[row][lr] = hn;
          hn4[q] = hn;
        }
        u64 w = pack4(hn4, lr);
        unsigned wlo = (unsigned)w, whi = (unsigned)(w >> 32);
        unsigned plo = (unsigned)__shfl_xor((int)wlo, 4, 64);
        unsigned phi = (unsigned)__shfl_xor((int)whi, 4, 64);
        if ((lr & 4) == 0) {
          const int srow = rt * 16 + dr + (lr & 3);
          u32x4 v4 = {wlo, whi, plo, phi};
          st16_coh(h1g + ((size_t)(t & (RING - 1)) * 32 + srow) * 1024 + j * 16 + (lr & ~7), v4);
        }
      }
      __syncthreads();
      if (tid == 0) astu(prod1 + wgid * 32, (unsigned)(t + 1));
    }

    // ---- output projection: out rows gb..gb+31 = h1(1023) @ w_out^T + b_out ----
    if (wave == 0) {
      const unsigned* p1 = prod1 + lane * 32;
      while (!__all(aldu(p1) >= 1024u)) __builtin_amdgcn_s_sleep(1);
    }
    __syncthreads();
    const int j2 = wgid & 31, rg2 = wgid >> 5;
    f32x4 acc = {0.f, 0.f, 0.f, 0.f};
    if (wave < 2) {
      const f16* Ah = h1g + ((size_t)(1023 & (RING - 1)) * 32 + rg2 * 16 + lr) * 1024 + wave * 512 + lk;
      const f16* Bp = A.wout + ((size_t)(j2 * 16 + lr)) * 1024 + wave * 512 + lk;
#pragma unroll
      for (int q2 = 0; q2 < 16; ++q2)
        acc = mf(*(const f16x8*)(Ah + q2 * 32), *(const f16x8*)(Bp + q2 * 32), acc);
    }
    if (wave == 1) {
#pragma unroll
      for (int q = 0; q < 4; ++q) sm.sc[0][0][q][lane] = acc[q];
    }
    __syncthreads();
    if (wave == 0) {
#pragma unroll
      for (int q = 0; q < 4; ++q) {
        float v = acc[q] + sm.sc[0][0][q][lane] + A.bout[j2 * 16 + lr];
        A.out[(gb + rg2 * 16 + dr + q) * 512 + j2 * 16 + lr] = v;
      }
    }
  }
}

// ---------------- host ----------------

extern "C" void kernel_launch(void* const* d_in, const int* in_sizes, int n_in,
                              void* d_out, int out_size, void* d_ws, size_t ws_size,
                              hipStream_t stream) {
  (void)in_sizes; (void)n_in; (void)out_size; (void)ws_size;
  const float* x = (const float*)d_in[0];
  const float* w_ih0 = (const float*)d_in[1];
  const float* w_hh0 = (const float*)d_in[2];
  const float* b_ih0 = (const float*)d_in[3];
  const float* b_hh0 = (const float*)d_in[4];
  const float* w_ih1 = (const float*)d_in[5];
  const float* w_hh1 = (const float*)d_in[6];
  const float* b_ih1 = (const float*)d_in[7];
  const float* b_hh1 = (const float*)d_in[8];
  const float* w_out = (const float*)d_in[9];
  const float* b_out = (const float*)d_in[10];

  char* ws = (char*)d_ws;
  size_t off = 0;
  auto alloc = [&](size_t b) {
    off = (off + 255) & ~(size_t)255;
    char* p = ws + off;
    off += b;
    return p;
  };

  float* pe = (float*)alloc((size_t)1024 * 512 * 4);
  f16* x16 = (f16*)alloc((size_t)1024 * 64 * 512 * 2);
  f16* wih0 = (f16*)alloc((size_t)3072 * 512 * 2);
  f16* whh0 = (f16*)alloc((size_t)3072 * 1024 * 2);
  f16* wih1 = (f16*)alloc((size_t)3072 * 1024 * 2);
  f16* whh1 = (f16*)alloc((size_t)3072 * 1024 * 2);
  f16* wout = (f16*)alloc((size_t)512 * 1024 * 2);
  f16* h0r = (f16*)alloc((size_t)2 * RING * 32 * 1024 * 2);
  f16* h1r = (f16*)alloc((size_t)2 * RING * 32 * 1024 * 2);
  unsigned* flg = (unsigned*)alloc((size_t)2 * 2 * 2048 * 4);

  // per-call init: flags zero; ring slot RING-1 (initial h=0) zero, per group
  (void)hipMemsetAsync(flg, 0, (size_t)2 * 2 * 2048 * 4, stream);
  for (int g = 0; g < 2; ++g) {
    (void)hipMemsetAsync(h0r + ((size_t)g * RING + RING - 1) * 32 * 1024, 0, (size_t)32 * 1024 * 2, stream);
    (void)hipMemsetAsync(h1r + ((size_t)g * RING + RING - 1) * 32 * 1024, 0, (size_t)32 * 1024 * 2, stream);
  }

  gru_k_pe<<<(1024 * 512 + 255) / 256, 256, 0, stream>>>(pe);
  gru_k_x16<<<dim3(2, 1024, 64), 256, 0, stream>>>(x, pe, x16);
  gru_k_f16<<<(3072 * 512 + 255) / 256, 256, 0, stream>>>(w_ih0, wih0, 3072 * 512);
  gru_k_f16<<<(3072 * 1024 + 255) / 256, 256, 0, stream>>>(w_hh0, whh0, 3072 * 1024);
  gru_k_f16<<<(3072 * 1024 + 255) / 256, 256, 0, stream>>>(w_ih1, wih1, 3072 * 1024);
  gru_k_f16<<<(3072 * 1024 + 255) / 256, 256, 0, stream>>>(w_hh1, whh1, 3072 * 1024);
  gru_k_f16<<<(512 * 1024 + 255) / 256, 256, 0, stream>>>(w_out, wout, 512 * 1024);

  gru::Args A;
  A.x16 = x16;
  A.bih0 = b_ih0; A.bhh0 = b_hh0; A.bih1 = b_ih1; A.bhh1 = b_hh1; A.bout = b_out;
  A.wih0 = wih0; A.whh0 = whh0; A.wih1 = wih1; A.whh1 = whh1; A.wout = wout;
  A.h0 = h0r; A.h1 = h1r;
  A.out = (float*)d_out;
  A.flg = flg;

  // Plain launch: 256 blocks x 1 block/CU (LDS-bound) on 256 CUs -> co-resident.
  gru_main<<<dim3(NWG), dim3(WGSZ), 0, stream>>>(A);
}

// Round 12
// 11474.472 us; speedup vs baseline: 3.6174x; 1.0158x over previous
//
#include <hip/hip_runtime.h>
#include <cstdint>
#include <cstddef>

typedef _Float16 f16;
typedef _Float16 f16x8 __attribute__((ext_vector_type(8)));
typedef float f32x4 __attribute__((ext_vector_type(4)));
typedef unsigned u32x4 __attribute__((ext_vector_type(4)));
typedef unsigned long long u64;

#define NWG 256
#define WGSZ 256
#define RING 64   // ring depth; 64 % 3 == 1 -> stale slot tag always differs

namespace gru {

__device__ inline f32x4 mf(f16x8 a, f16x8 b, f32x4 c) {
  return __builtin_amdgcn_mfma_f32_16x16x32_f16(a, b, c, 0, 0, 0);
}
__device__ inline float sigf(float x) { return 1.f / (1.f + __expf(-x)); }
__device__ inline float tanh_fast(float x) {
  float xx = fminf(fmaxf(x, -15.f), 15.f);
  float e = __expf(-2.f * xx);
  return (1.f - e) / (1.f + e);
}
__device__ inline unsigned tag_of(int t) { return 1u + (unsigned)(t % 3); }  // 1..3, never 0

struct SMem {
  f16 wA[48 * 1024];      // 96 KB: whh0 (L0) or whh1 (L1), swizzled
  f16 wB[48 * 512];       // 48 KB: wih0 (L0) or wih1 K-half 0 (L1), swizzled
  float sc[2][4][4][64];  // 8 KB pairwise-reduce scratch
  float hm[32][16];       // fp32 master h tile
  float bI[48], bH[48];
};

struct Args {
  const f16* x16;
  const float* bih0; const float* bhh0; const float* bih1; const float* bhh1; const float* bout;
  const f16* wih0; const f16* whh0; const f16* wih1; const f16* whh1; const f16* wout;
  f16* h0;   // per-group rings: [2][RING][32][1024], every f16 carries a 2-bit step tag
  f16* h1;
  float* out;
  unsigned* flg;  // per group: [2048 unused][prod1: 64 x 128B-strided words]
};

__device__ inline unsigned aldu(const unsigned* p) {
  return __hip_atomic_load(p, __ATOMIC_RELAXED, __HIP_MEMORY_SCOPE_AGENT);
}
__device__ inline void astu(unsigned* p, unsigned v) {
  __hip_atomic_store(p, v, __ATOMIC_RELAXED, __HIP_MEMORY_SCOPE_AGENT);
}

// ---- batched coherent loads (bypass L1/L2 via sc0 sc1). "=&v" early-clobber:
// outputs must not alias the address operands (loads issue before asm ends).
struct frag16 { f16x8 v[16]; };
struct frag32 { f16x8 v[32]; };

__device__ inline frag16 ld16_coh(const f16* p) {
  frag16 f;
  asm volatile(
      "global_load_dwordx4 %0, %16, off sc0 sc1\n\t"
      "global_load_dwordx4 %1, %16, off offset:64 sc0 sc1\n\t"
      "global_load_dwordx4 %2, %16, off offset:128 sc0 sc1\n\t"
      "global_load_dwordx4 %3, %16, off offset:192 sc0 sc1\n\t"
      "global_load_dwordx4 %4, %16, off offset:256 sc0 sc1\n\t"
      "global_load_dwordx4 %5, %16, off offset:320 sc0 sc1\n\t"
      "global_load_dwordx4 %6, %16, off offset:384 sc0 sc1\n\t"
      "global_load_dwordx4 %7, %16, off offset:448 sc0 sc1\n\t"
      "global_load_dwordx4 %8, %16, off offset:512 sc0 sc1\n\t"
      "global_load_dwordx4 %9, %16, off offset:576 sc0 sc1\n\t"
      "global_load_dwordx4 %10, %16, off offset:640 sc0 sc1\n\t"
      "global_load_dwordx4 %11, %16, off offset:704 sc0 sc1\n\t"
      "global_load_dwordx4 %12, %16, off offset:768 sc0 sc1\n\t"
      "global_load_dwordx4 %13, %16, off offset:832 sc0 sc1\n\t"
      "global_load_dwordx4 %14, %16, off offset:896 sc0 sc1\n\t"
      "global_load_dwordx4 %15, %16, off offset:960 sc0 sc1\n\t"
      "s_waitcnt vmcnt(0)"
      : "=&v"(f.v[0]), "=&v"(f.v[1]), "=&v"(f.v[2]), "=&v"(f.v[3]),
        "=&v"(f.v[4]), "=&v"(f.v[5]), "=&v"(f.v[6]), "=&v"(f.v[7]),
        "=&v"(f.v[8]), "=&v"(f.v[9]), "=&v"(f.v[10]), "=&v"(f.v[11]),
        "=&v"(f.v[12]), "=&v"(f.v[13]), "=&v"(f.v[14]), "=&v"(f.v[15])
      : "v"(p)
      : "memory");
  return f;
}

// tag-validate: every dword holds 2 f16; low 2 bits of each must equal the tag.
__device__ inline int vfrag(const frag16& f, unsigned ep) {
  unsigned acc = 0;
#pragma unroll
  for (int r = 0; r < 16; ++r) {
    u32x4 w = __builtin_bit_cast(u32x4, f.v[r]);
    acc |= ((w[0] & 0x30003u) ^ ep) | ((w[1] & 0x30003u) ^ ep) |
           ((w[2] & 0x30003u) ^ ep) | ((w[3] & 0x30003u) ^ ep);
  }
  return acc == 0;
}

__device__ inline frag16 ld16_val(const f16* p, unsigned ep) {
  frag16 f = ld16_coh(p);
  while (!__all(vfrag(f, ep))) {
    __builtin_amdgcn_s_sleep(1);
    f = ld16_coh(p);
  }
  return f;
}

// Pack lane's 4 gate outputs into one u64 (4 adjacent cols of one row) via
// 2x shfl_xor; each f16's low 2 bits replaced by the step tag.
__device__ inline u64 pack4(const float* hn4, int lr, unsigned wtag) {
  u64 w = 0;
#pragma unroll
  for (int q = 0; q < 4; ++q) {
    f16 h = (f16)hn4[q];
    unsigned own = ((unsigned)__builtin_bit_cast(unsigned short, h) & 0xFFFCu) | wtag;
    unsigned p1 = (unsigned)__shfl_xor((int)own, 1, 64);
    unsigned v32 = (lr & 1) ? ((own << 16) | p1) : (own | (p1 << 16));
    unsigned o2 = (unsigned)__shfl_xor((int)v32, 2, 64);
    u64 v64 = (lr & 2) ? (((u64)v32 << 32) | (u64)o2) : (((u64)o2 << 32) | (u64)v32);
    if ((lr & 3) == q) w = v64;
  }
  return w;
}

// 16B coherent write-through store (fire-and-forget; tags announce validity).
__device__ inline void st16_coh(f16* p, u32x4 v) {
  asm volatile("global_store_dwordx4 %0, %1, off sc0 sc1" :: "v"(p), "v"(v) : "memory");
}

template <int K8, int SK8>
__device__ void load_w(f16* dst, const f16* W, int j) {
  for (int u = threadIdx.x; u < 48 * K8; u += WGSZ) {
    int row = u / K8, k8 = u - row * K8;
    int gcol = (row >> 4) * 1024 + j * 16 + (row & 15);
    f16x8 v = *(const f16x8*)(W + (size_t)gcol * (size_t)(SK8 * 8) + (size_t)k8 * 8);
    *(f16x8*)(dst + ((size_t)row * K8 + (size_t)(k8 ^ (row & 7))) * 8) = v;
  }
}

template <int K8>
__device__ inline f16x8 ldb(const f16* base, int row, int u8) {
  return *(const f16x8*)(base + ((size_t)row * K8 + (size_t)(u8 ^ (row & 7))) * 8);
}

}  // namespace gru

// ---------------- prep kernels ----------------

__global__ void gru_k_pe(float* pe) {
  int idx = blockIdx.x * 256 + threadIdx.x;
  if (idx >= 1024 * 512) return;
  int t = idx >> 9, d = idx & 511;
  int jj = d >> 1;
  float freq = expf(-logf(10000.f) * (float)(2 * jj) * (1.f / 512.f));
  float ang = (float)t * freq;
  pe[idx] = (d & 1) ? cosf(ang) : sinf(ang);
}

__global__ void gru_k_x16(const float* __restrict__ x, const float* __restrict__ pe,
                          f16* __restrict__ x16) {
  int d = blockIdx.x * 256 + threadIdx.x;  // grid.x = 2
  int t = blockIdx.y, b = blockIdx.z;
  float v = x[((size_t)b * 1024 + t) * 512 + d] + pe[t * 512 + d];
  x16[((size_t)t * 64 + b) * 512 + d] = (f16)v;
}

__global__ void gru_k_f16(const float* __restrict__ src, f16* __restrict__ dst, int n) {
  int i = blockIdx.x * 256 + threadIdx.x;
  if (i < n) dst[i] = (f16)src[i];
}

// ---------------- main persistent pipelined kernel ----------------
// 2 independent groups x 32 batch rows; xcd = wg%8: grp = xcd>>2,
// role = (xcd>>1)&1, wgid = ((xcd&1)<<5)|(wg>>3).
// ZERO-FLAG exchange: h values carry 2-bit step tags; consumers read
// speculatively (sc0 sc1, bypassing caches) and retry until tags match.
// No drains, no signals, no fences on the critical path. Ring-wrap deadlock
// prevented by an amortized L1-progress guard (checked every 16 steps).

__global__ __launch_bounds__(WGSZ, 1) void gru_main(gru::Args A) {
  using namespace gru;
  __shared__ SMem sm;
  const int wg = blockIdx.x, tid = threadIdx.x;
  const int xcd = wg & 7, slot = wg >> 3;
  const int grp = xcd >> 2;
  const bool isL0 = ((xcd >> 1) & 1) == 0;
  const int wgid = ((xcd & 1) << 5) | slot;
  const int j = wgid;
  const int wave = tid >> 6, lane = tid & 63;
  const int lr = lane & 15, lk8 = lane >> 4;
  const int lk = lk8 * 8, dr = lk8 * 4;
  const int rt = wave >> 1, kh = wave & 1;
  const int rowbase = rt * 16;
  const int gb = grp * 32;

  f16* h0g = A.h0 + (size_t)grp * RING * 32 * 1024;
  f16* h1g = A.h1 + (size_t)grp * RING * 32 * 1024;
  unsigned* prod1 = A.flg + (size_t)grp * 2 * 2048 + 2048;

  __threadfence();  // once: cross-replay cache hygiene for cached paths

  ((float*)sm.hm)[tid] = 0.f;
  ((float*)sm.hm)[tid + 256] = 0.f;

  if (isL0) {
    load_w<128, 128>(sm.wA, A.whh0, j);
    load_w<64, 64>(sm.wB, A.wih0, j);
    if (tid < 48) {
      int gcol = (tid >> 4) * 1024 + j * 16 + (tid & 15);
      sm.bI[tid] = A.bih0[gcol];
      sm.bH[tid] = A.bhh0[gcol];
    }
  } else {
    load_w<128, 128>(sm.wA, A.whh1, j);
    load_w<64, 128>(sm.wB, A.wih1, j);  // wih1 K-half 0 in LDS
    if (tid < 48) {
      int gcol = (tid >> 4) * 1024 + j * 16 + (tid & 15);
      sm.bI[tid] = A.bih1[gcol];
      sm.bH[tid] = A.bhh1[gcol];
    }
  }
  __syncthreads();

  if (isL0) {
    // =============== layer-0 ===============
    f16x8 xf[2][8];
    {
      const f16* xp = A.x16 + ((size_t)0 * 64 + gb + rowbase + lr) * 512 + kh * 256 + lk;
#pragma unroll
      for (int q2 = 0; q2 < 8; ++q2) xf[0][q2] = *(const f16x8*)(xp + q2 * 32);
    }
    for (int t = 0; t < 1024; ++t) {
      const int cur = t & 1;
      // ring-wrap guard, amortized: every 16 steps ensure L1 is within 40
      if (((t & 15) == 0) && t >= 48 && wave == 0) {
        const int need = t - 40;
        const unsigned* p1 = prod1 + lane * 32;
        while (!__all((int)aldu(p1) >= need)) __builtin_amdgcn_s_sleep(8);
      }
      f32x4 a0 = {0.f, 0.f, 0.f, 0.f}, a1 = a0, a2 = a0, a3 = a0;
      // x-part first (independent of h)
#pragma unroll
      for (int q2 = 0; q2 < 8; ++q2) {
        const int u8 = (kh * 8 + q2) * 4 + lk8;
        a0 = mf(xf[cur][q2], ldb<64>(sm.wB, lr, u8), a0);
        a1 = mf(xf[cur][q2], ldb<64>(sm.wB, 16 + lr, u8), a1);
        a2 = mf(xf[cur][q2], ldb<64>(sm.wB, 32 + lr, u8), a2);  // i_n
      }
      if (t + 1 < 1024) {
        const f16* xp = A.x16 + ((size_t)(t + 1) * 64 + gb + rowbase + lr) * 512 + kh * 256 + lk;
#pragma unroll
        for (int q2 = 0; q2 < 8; ++q2) xf[cur ^ 1][q2] = *(const f16x8*)(xp + q2 * 32);
      }
      // h0(t-1): tag-validated speculative read (zeros at t=0)
      frag16 hf;
      if (t == 0) {
#pragma unroll
        for (int q2 = 0; q2 < 16; ++q2) hf.v[q2] = 0;
      } else {
        const f16* hp = h0g + ((size_t)((t + RING - 1) & (RING - 1)) * 32 + rowbase + lr) * 1024 + kh * 512 + lk;
        hf = ld16_val(hp, 0x10001u * tag_of(t - 1));
      }
#pragma unroll
      for (int q2 = 0; q2 < 16; ++q2) {
        const int u8 = (kh * 16 + q2) * 4 + lk8;
        a0 = mf(hf.v[q2], ldb<128>(sm.wA, lr, u8), a0);
        a1 = mf(hf.v[q2], ldb<128>(sm.wA, 16 + lr, u8), a1);
        a3 = mf(hf.v[q2], ldb<128>(sm.wA, 32 + lr, u8), a3);  // h_n
      }
      if (kh) {
#pragma unroll
        for (int q = 0; q < 4; ++q) {
          sm.sc[rt][0][q][lane] = a0[q]; sm.sc[rt][1][q][lane] = a1[q];
          sm.sc[rt][2][q][lane] = a2[q]; sm.sc[rt][3][q][lane] = a3[q];
        }
      }
      __syncthreads();
      if (!kh) {
        float hn4[4];
#pragma unroll
        for (int q = 0; q < 4; ++q) {
          a0[q] += sm.sc[rt][0][q][lane]; a1[q] += sm.sc[rt][1][q][lane];
          a2[q] += sm.sc[rt][2][q][lane]; a3[q] += sm.sc[rt][3][q][lane];
        }
#pragma unroll
        for (int q = 0; q < 4; ++q) {
          const int row = rt * 16 + dr + q;
          float r = sigf(a0[q] + sm.bI[lr] + sm.bH[lr]);
          float z = sigf(a1[q] + sm.bI[16 + lr] + sm.bH[16 + lr]);
          float n = tanh_fast(a2[q] + sm.bI[32 + lr] + r * (a3[q] + sm.bH[32 + lr]));
          float hn = n + z * (sm.hm[row][lr] - n);
          sm.hm[row][lr] = hn;
          hn4[q] = hn;
        }
        u64 w = pack4(hn4, lr, tag_of(t));
        unsigned wlo = (unsigned)w, whi = (unsigned)(w >> 32);
        unsigned plo = (unsigned)__shfl_xor((int)wlo, 4, 64);
        unsigned phi = (unsigned)__shfl_xor((int)whi, 4, 64);
        if ((lr & 4) == 0) {
          const int srow = rt * 16 + dr + (lr & 3);
          u32x4 v4 = {wlo, whi, plo, phi};
          st16_coh(h0g + ((size_t)(t & (RING - 1)) * 32 + srow) * 1024 + j * 16 + (lr & ~7), v4);
        }
      }
      __syncthreads();
    }
  } else {
    // =============== layer-1 ===============
    for (int t = 0; t < 1024; ++t) {
      const f16* gp = h0g + ((size_t)(t & (RING - 1)) * 32 + rowbase + lr) * 1024 + kh * 512 + lk;
      frag16 gf = ld16_val(gp, 0x10001u * tag_of(t));  // h0(t)
      frag16 hf;
      if (t == 0) {
#pragma unroll
        for (int q2 = 0; q2 < 16; ++q2) hf.v[q2] = 0;
      } else {
        const f16* hp = h1g + ((size_t)((t + RING - 1) & (RING - 1)) * 32 + rowbase + lr) * 1024 + kh * 512 + lk;
        hf = ld16_val(hp, 0x10001u * tag_of(t - 1));   // h1(t-1)
      }
      f32x4 a0 = {0.f, 0.f, 0.f, 0.f}, a1 = a0, a2 = a0, a3 = a0;
      if (kh == 0) {
#pragma unroll
        for (int q2 = 0; q2 < 16; ++q2) {
          const int u8 = q2 * 4 + lk8;
          a0 = mf(gf.v[q2], ldb<64>(sm.wB, lr, u8), a0);
          a1 = mf(gf.v[q2], ldb<64>(sm.wB, 16 + lr, u8), a1);
          a2 = mf(gf.v[q2], ldb<64>(sm.wB, 32 + lr, u8), a2);  // i_n
        }
      } else {
        const f16* wb = A.wih1 + ((size_t)(j * 16 + lr)) * 1024 + 512 + lk;
#pragma unroll
        for (int q2 = 0; q2 < 16; ++q2) {
          const size_t o = (size_t)q2 * 32;
          a0 = mf(gf.v[q2], *(const f16x8*)(wb + o), a0);
          a1 = mf(gf.v[q2], *(const f16x8*)(wb + (size_t)1024 * 1024 + o), a1);
          a2 = mf(gf.v[q2], *(const f16x8*)(wb + (size_t)2048 * 1024 + o), a2);  // i_n
        }
      }
#pragma unroll
      for (int q2 = 0; q2 < 16; ++q2) {
        const int u8 = (kh * 16 + q2) * 4 + lk8;
        a0 = mf(hf.v[q2], ldb<128>(sm.wA, lr, u8), a0);
        a1 = mf(hf.v[q2], ldb<128>(sm.wA, 16 + lr, u8), a1);
        a3 = mf(hf.v[q2], ldb<128>(sm.wA, 32 + lr, u8), a3);  // h_n
      }
      if (kh) {
#pragma unroll
        for (int q = 0; q < 4; ++q) {
          sm.sc[rt][0][q][lane] = a0[q]; sm.sc[rt][1][q][lane] = a1[q];
          sm.sc[rt][2][q][lane] = a2[q]; sm.sc[rt][3][q][lane] = a3[q];
        }
      }
      __syncthreads();
      if (!kh) {
        float hn4[4];
#pragma unroll
        for (int q = 0; q < 4; ++q) {
          a0[q] += sm.sc[rt][0][q][lane]; a1[q] += sm.sc[rt][1][q][lane];
          a2[q] += sm.sc[rt][2][q][lane]; a3[q] += sm.sc[rt][3][q][lane];
        }
#pragma unroll
        for (int q = 0; q < 4; ++q) {
          const int row = rt * 16 + dr + q;
          float r = sigf(a0[q] + sm.bI[lr] + sm.bH[lr]);
          float z = sigf(a1[q] + sm.bI[16 + lr] + sm.bH[16 + lr]);
          float n = tanh_fast(a2[q] + sm.bI[32 + lr] + r * (a3[q] + sm.bH[32 + lr]));
          float hn = n + z * (sm.hm[row][lr] - n);
          sm.hm[row][lr] = hn;
          hn4[q] = hn;
        }
        u64 w = pack4(hn4, lr, tag_of(t));
        unsigned wlo = (unsigned)w, whi = (unsigned)(w >> 32);
        unsigned plo = (unsigned)__shfl_xor((int)wlo, 4, 64);
        unsigned phi = (unsigned)__shfl_xor((int)whi, 4, 64);
        if ((lr & 4) == 0) {
          const int srow = rt * 16 + dr + (lr & 3);
          u32x4 v4 = {wlo, whi, plo, phi};
          st16_coh(h1g + ((size_t)(t & (RING - 1)) * 32 + srow) * 1024 + j * 16 + (lr & ~7), v4);
        }
      }
      __syncthreads();
      // progress for L0's ring guard: all waves' reads completed before the
      // pre-write __syncthreads above, so tid 0's store here is safe.
      if (tid == 0) astu(prod1 + wgid * 32, (unsigned)(t + 1));
    }

    // ---- output projection: out rows gb..gb+31 = h1(1023) @ w_out^T + b_out ----
    const int j2 = wgid & 31, rg2 = wgid >> 5;
    f32x4 acc = {0.f, 0.f, 0.f, 0.f};
    if (wave < 2) {
      const f16* Ah = h1g + ((size_t)(1023 & (RING - 1)) * 32 + rg2 * 16 + lr) * 1024 + wave * 512 + lk;
      const f16* Bp = A.wout + ((size_t)(j2 * 16 + lr)) * 1024 + wave * 512 + lk;
      frag16 hv = ld16_val(Ah, 0x10001u * gru::tag_of(1023));
#pragma unroll
      for (int q2 = 0; q2 < 16; ++q2)
        acc = mf(hv.v[q2], *(const f16x8*)(Bp + q2 * 32), acc);
    }
    if (wave == 1) {
#pragma unroll
      for (int q = 0; q < 4; ++q) sm.sc[0][0][q][lane] = acc[q];
    }
    __syncthreads();
    if (wave == 0) {
#pragma unroll
      for (int q = 0; q < 4; ++q) {
        float v = acc[q] + sm.sc[0][0][q][lane] + A.bout[j2 * 16 + lr];
        A.out[(gb + rg2 * 16 + dr + q) * 512 + j2 * 16 + lr] = v;
      }
    }
  }
}

// ---------------- host ----------------

extern "C" void kernel_launch(void* const* d_in, const int* in_sizes, int n_in,
                              void* d_out, int out_size, void* d_ws, size_t ws_size,
                              hipStream_t stream) {
  (void)in_sizes; (void)n_in; (void)out_size; (void)ws_size;
  const float* x = (const float*)d_in[0];
  const float* w_ih0 = (const float*)d_in[1];
  const float* w_hh0 = (const float*)d_in[2];
  const float* b_ih0 = (const float*)d_in[3];
  const float* b_hh0 = (const float*)d_in[4];
  const float* w_ih1 = (const float*)d_in[5];
  const float* w_hh1 = (const float*)d_in[6];
  const float* b_ih1 = (const float*)d_in[7];
  const float* b_hh1 = (const float*)d_in[8];
  const float* w_out = (const float*)d_in[9];
  const float* b_out = (const float*)d_in[10];

  char* ws = (char*)d_ws;
  size_t off = 0;
  auto alloc = [&](size_t b) {
    off = (off + 255) & ~(size_t)255;
    char* p = ws + off;
    off += b;
    return p;
  };

  float* pe = (float*)alloc((size_t)1024 * 512 * 4);
  f16* x16 = (f16*)alloc((size_t)1024 * 64 * 512 * 2);
  f16* wih0 = (f16*)alloc((size_t)3072 * 512 * 2);
  f16* whh0 = (f16*)alloc((size_t)3072 * 1024 * 2);
  f16* wih1 = (f16*)alloc((size_t)3072 * 1024 * 2);
  f16* whh1 = (f16*)alloc((size_t)3072 * 1024 * 2);
  f16* wout = (f16*)alloc((size_t)512 * 1024 * 2);
  f16* h0r = (f16*)alloc((size_t)2 * RING * 32 * 1024 * 2);
  f16* h1r = (f16*)alloc((size_t)2 * RING * 32 * 1024 * 2);
  unsigned* flg = (unsigned*)alloc((size_t)2 * 2 * 2048 * 4);

  // per-call init: FULL ring memset (tag 0 = invalid everywhere -> no stale
  // cross-replay false-validation); progress counters zero.
  (void)hipMemsetAsync(h0r, 0, (size_t)2 * RING * 32 * 1024 * 2, stream);
  (void)hipMemsetAsync(h1r, 0, (size_t)2 * RING * 32 * 1024 * 2, stream);
  (void)hipMemsetAsync(flg, 0, (size_t)2 * 2 * 2048 * 4, stream);

  gru_k_pe<<<(1024 * 512 + 255) / 256, 256, 0, stream>>>(pe);
  gru_k_x16<<<dim3(2, 1024, 64), 256, 0, stream>>>(x, pe, x16);
  gru_k_f16<<<(3072 * 512 + 255) / 256, 256, 0, stream>>>(w_ih0, wih0, 3072 * 512);
  gru_k_f16<<<(3072 * 1024 + 255) / 256, 256, 0, stream>>>(w_hh0, whh0, 3072 * 1024);
  gru_k_f16<<<(3072 * 1024 + 255) / 256, 256, 0, stream>>>(w_ih1, wih1, 3072 * 1024);
  gru_k_f16<<<(3072 * 1024 + 255) / 256, 256, 0, stream>>>(w_hh1, whh1, 3072 * 1024);
  gru_k_f16<<<(512 * 1024 + 255) / 256, 256, 0, stream>>>(w_out, wout, 512 * 1024);

  gru::Args A;
  A.x16 = x16;
  A.bih0 = b_ih0; A.bhh0 = b_hh0; A.bih1 = b_ih1; A.bhh1 = b_hh1; A.bout = b_out;
  A.wih0 = wih0; A.whh0 = whh0; A.wih1 = wih1; A.whh1 = whh1; A.wout = wout;
  A.h0 = h0r; A.h1 = h1r;
  A.out = (float*)d_out;
  A.flg = flg;

  // Plain launch: 256 blocks x 1 block/CU (LDS-bound) on 256 CUs -> co-resident.
  gru_main<<<dim3(NWG), dim3(WGSZ), 0, stream>>>(A);
}

// Round 13
// 10999.517 us; speedup vs baseline: 3.7736x; 1.0432x over previous
//
#include <hip/hip_runtime.h>
#include <cstdint>
#include <cstddef>

typedef _Float16 f16;
typedef _Float16 f16x8 __attribute__((ext_vector_type(8)));
typedef float f32x4 __attribute__((ext_vector_type(4)));
typedef unsigned u32x4 __attribute__((ext_vector_type(4)));
typedef unsigned long long u64;

#define NWG 256
#define WGSZ 256
#define RING 64   // canonical ring; 64 % 3 == 1 -> stale tag always differs
#define SRING 4   // staging ring (local-L2 fast path); 4 % 3 == 1

namespace gru {

__device__ inline f32x4 mf(f16x8 a, f16x8 b, f32x4 c) {
  return __builtin_amdgcn_mfma_f32_16x16x32_f16(a, b, c, 0, 0, 0);
}
__device__ inline float sigf(float x) { return 1.f / (1.f + __expf(-x)); }
__device__ inline float tanh_fast(float x) {
  float xx = fminf(fmaxf(x, -15.f), 15.f);
  float e = __expf(-2.f * xx);
  return (1.f - e) / (1.f + e);
}
__device__ inline unsigned tag_of(int t) { return 1u + (unsigned)(t % 3); }  // 1..3, never 0

struct SMem {
  f16 wA[48 * 1024];      // 96 KB: whh0 (L0) or whh1 (L1), swizzled
  f16 wB[48 * 512];       // 48 KB: wih0 (L0) or wih1 K-half 0 (L1), swizzled
  float sc[2][4][4][64];  // 8 KB pairwise-reduce scratch
  float hm[32][16];       // fp32 master h tile
  float bI[48], bH[48];
};

struct Args {
  const f16* x16;
  const float* bih0; const float* bhh0; const float* bih1; const float* bhh1; const float* bout;
  const f16* wih0; const f16* whh0; const f16* wih1; const f16* whh1; const f16* wout;
  f16* h0;   // canonical rings [2][RING][32][1024], tagged f16
  f16* h1;
  f16* h0s;  // staging rings [2][SRING][32][1024], tagged, local-L2 fast path
  f16* h1s;
  float* out;
  unsigned* flg;  // per group: [2048 unused][prod1: 64 x 128B-strided words]
};

__device__ inline unsigned aldu(const unsigned* p) {
  return __hip_atomic_load(p, __ATOMIC_RELAXED, __HIP_MEMORY_SCOPE_AGENT);
}
__device__ inline void astu(unsigned* p, unsigned v) {
  __hip_atomic_store(p, v, __ATOMIC_RELAXED, __HIP_MEMORY_SCOPE_AGENT);
}

struct frag16 { f16x8 v[16]; };

// Fully-coherent batched load: sc0 sc1 bypasses L1+L2, reads the IF/coherent
// point. Proven correct (R12). Early-clobber: outputs must not alias addr.
__device__ inline frag16 ld16_coh(const f16* p) {
  frag16 f;
  asm volatile(
      "global_load_dwordx4 %0, %16, off sc0 sc1\n\t"
      "global_load_dwordx4 %1, %16, off offset:64 sc0 sc1\n\t"
      "global_load_dwordx4 %2, %16, off offset:128 sc0 sc1\n\t"
      "global_load_dwordx4 %3, %16, off offset:192 sc0 sc1\n\t"
      "global_load_dwordx4 %4, %16, off offset:256 sc0 sc1\n\t"
      "global_load_dwordx4 %5, %16, off offset:320 sc0 sc1\n\t"
      "global_load_dwordx4 %6, %16, off offset:384 sc0 sc1\n\t"
      "global_load_dwordx4 %7, %16, off offset:448 sc0 sc1\n\t"
      "global_load_dwordx4 %8, %16, off offset:512 sc0 sc1\n\t"
      "global_load_dwordx4 %9, %16, off offset:576 sc0 sc1\n\t"
      "global_load_dwordx4 %10, %16, off offset:640 sc0 sc1\n\t"
      "global_load_dwordx4 %11, %16, off offset:704 sc0 sc1\n\t"
      "global_load_dwordx4 %12, %16, off offset:768 sc0 sc1\n\t"
      "global_load_dwordx4 %13, %16, off offset:832 sc0 sc1\n\t"
      "global_load_dwordx4 %14, %16, off offset:896 sc0 sc1\n\t"
      "global_load_dwordx4 %15, %16, off offset:960 sc0 sc1\n\t"
      "s_waitcnt vmcnt(0)"
      : "=&v"(f.v[0]), "=&v"(f.v[1]), "=&v"(f.v[2]), "=&v"(f.v[3]),
        "=&v"(f.v[4]), "=&v"(f.v[5]), "=&v"(f.v[6]), "=&v"(f.v[7]),
        "=&v"(f.v[8]), "=&v"(f.v[9]), "=&v"(f.v[10]), "=&v"(f.v[11]),
        "=&v"(f.v[12]), "=&v"(f.v[13]), "=&v"(f.v[14]), "=&v"(f.v[15])
      : "v"(p)
      : "memory");
  return f;
}

// L2-path batched load: sc0 only (bypass L1, served by local XCD L2; misses
// fill from the coherent point). Tags decide whether the content is usable.
__device__ inline frag16 ld16_l2(const f16* p) {
  frag16 f;
  asm volatile(
      "global_load_dwordx4 %0, %16, off sc0\n\t"
      "global_load_dwordx4 %1, %16, off offset:64 sc0\n\t"
      "global_load_dwordx4 %2, %16, off offset:128 sc0\n\t"
      "global_load_dwordx4 %3, %16, off offset:192 sc0\n\t"
      "global_load_dwordx4 %4, %16, off offset:256 sc0\n\t"
      "global_load_dwordx4 %5, %16, off offset:320 sc0\n\t"
      "global_load_dwordx4 %6, %16, off offset:384 sc0\n\t"
      "global_load_dwordx4 %7, %16, off offset:448 sc0\n\t"
      "global_load_dwordx4 %8, %16, off offset:512 sc0\n\t"
      "global_load_dwordx4 %9, %16, off offset:576 sc0\n\t"
      "global_load_dwordx4 %10, %16, off offset:640 sc0\n\t"
      "global_load_dwordx4 %11, %16, off offset:704 sc0\n\t"
      "global_load_dwordx4 %12, %16, off offset:768 sc0\n\t"
      "global_load_dwordx4 %13, %16, off offset:832 sc0\n\t"
      "global_load_dwordx4 %14, %16, off offset:896 sc0\n\t"
      "global_load_dwordx4 %15, %16, off offset:960 sc0\n\t"
      "s_waitcnt vmcnt(0)"
      : "=&v"(f.v[0]), "=&v"(f.v[1]), "=&v"(f.v[2]), "=&v"(f.v[3]),
        "=&v"(f.v[4]), "=&v"(f.v[5]), "=&v"(f.v[6]), "=&v"(f.v[7]),
        "=&v"(f.v[8]), "=&v"(f.v[9]), "=&v"(f.v[10]), "=&v"(f.v[11]),
        "=&v"(f.v[12]), "=&v"(f.v[13]), "=&v"(f.v[14]), "=&v"(f.v[15])
      : "v"(p)
      : "memory");
  return f;
}

// tag-validate: low 2 bits of every f16 must equal the step tag.
__device__ inline int vfrag(const frag16& f, unsigned ep) {
  unsigned acc = 0;
#pragma unroll
  for (int r = 0; r < 16; ++r) {
    u32x4 w = __builtin_bit_cast(u32x4, f.v[r]);
    acc |= ((w[0] & 0x30003u) ^ ep) | ((w[1] & 0x30003u) ^ ep) |
           ((w[2] & 0x30003u) ^ ep) | ((w[3] & 0x30003u) ^ ep);
  }
  return acc == 0;
}

__device__ inline frag16 ld16_val(const f16* p, unsigned ep) {
  frag16 f = ld16_coh(p);
  while (!__all(vfrag(f, ep))) {
    __builtin_amdgcn_s_sleep(1);
    f = ld16_coh(p);
  }
  return f;
}

// Pack lane's 4 gate outputs into one u64 (4 adjacent cols of one row) via
// 2x shfl_xor; each f16's low 2 bits replaced by the step tag.
__device__ inline u64 pack4(const float* hn4, int lr, unsigned wtag) {
  u64 w = 0;
#pragma unroll
  for (int q = 0; q < 4; ++q) {
    f16 h = (f16)hn4[q];
    unsigned own = ((unsigned)__builtin_bit_cast(unsigned short, h) & 0xFFFCu) | wtag;
    unsigned p1 = (unsigned)__shfl_xor((int)own, 1, 64);
    unsigned v32 = (lr & 1) ? ((own << 16) | p1) : (own | (p1 << 16));
    unsigned o2 = (unsigned)__shfl_xor((int)v32, 2, 64);
    u64 v64 = (lr & 2) ? (((u64)v32 << 32) | (u64)o2) : (((u64)o2 << 32) | (u64)v32);
    if ((lr & 3) == q) w = v64;
  }
  return w;
}

// 16B coherent write-through store (canonical copy).
__device__ inline void st16_coh(f16* p, u32x4 v) {
  asm volatile("global_store_dwordx4 %0, %1, off sc0 sc1" :: "v"(p), "v"(v) : "memory");
}

template <int K8, int SK8>
__device__ void load_w(f16* dst, const f16* W, int j) {
  for (int u = threadIdx.x; u < 48 * K8; u += WGSZ) {
    int row = u / K8, k8 = u - row * K8;
    int gcol = (row >> 4) * 1024 + j * 16 + (row & 15);
    f16x8 v = *(const f16x8*)(W + (size_t)gcol * (size_t)(SK8 * 8) + (size_t)k8 * 8);
    *(f16x8*)(dst + ((size_t)row * K8 + (size_t)(k8 ^ (row & 7))) * 8) = v;
  }
}

template <int K8>
__device__ inline f16x8 ldb(const f16* base, int row, int u8) {
  return *(const f16x8*)(base + ((size_t)row * K8 + (size_t)(u8 ^ (row & 7))) * 8);
}

}  // namespace gru

// ---------------- prep kernels ----------------

__global__ void gru_k_pe(float* pe) {
  int idx = blockIdx.x * 256 + threadIdx.x;
  if (idx >= 1024 * 512) return;
  int t = idx >> 9, d = idx & 511;
  int jj = d >> 1;
  float freq = expf(-logf(10000.f) * (float)(2 * jj) * (1.f / 512.f));
  float ang = (float)t * freq;
  pe[idx] = (d & 1) ? cosf(ang) : sinf(ang);
}

__global__ void gru_k_x16(const float* __restrict__ x, const float* __restrict__ pe,
                          f16* __restrict__ x16) {
  int d = blockIdx.x * 256 + threadIdx.x;  // grid.x = 2
  int t = blockIdx.y, b = blockIdx.z;
  float v = x[((size_t)b * 1024 + t) * 512 + d] + pe[t * 512 + d];
  x16[((size_t)t * 64 + b) * 512 + d] = (f16)v;
}

__global__ void gru_k_f16(const float* __restrict__ src, f16* __restrict__ dst, int n) {
  int i = blockIdx.x * 256 + threadIdx.x;
  if (i < n) dst[i] = (f16)src[i];
}

// ---------------- main persistent pipelined kernel ----------------
// 2 groups x 32 rows; xcd = wg%8: grp = xcd>>2, role = (xcd>>1)&1,
// wgid = ((xcd&1)<<5)|(wg>>3).
// R13: tag-routed cache paths to cut coherent-point BYTES (the R7-R12 floor):
//  - producers dual-write: canonical (sc0 sc1) + staging ring (normal cached
//    store -> dirty line in the producer's OWN XCD L2, fence-free visible to
//    same-XCD sc0 readers).
//  - hf: try staging (sc0, cap 2, sticky-disable after 6 consecutive fails)
//    -> fallback canonical spin. Local halves come from L2; remote halves
//    fall back. Placement affects SPEED only; tags guarantee correctness.
//  - gf (h0(t), written ~40 steps early by the free-running L0): sc0-cached
//    read of the canonical address -> one IF fill per XCD, 32x dedup.

__global__ __launch_bounds__(WGSZ, 1) void gru_main(gru::Args A) {
  using namespace gru;
  __shared__ SMem sm;
  const int wg = blockIdx.x, tid = threadIdx.x;
  const int xcd = wg & 7, slot = wg >> 3;
  const int grp = xcd >> 2;
  const bool isL0 = ((xcd >> 1) & 1) == 0;
  const int wgid = ((xcd & 1) << 5) | slot;
  const int j = wgid;
  const int wave = tid >> 6, lane = tid & 63;
  const int lr = lane & 15, lk8 = lane >> 4;
  const int lk = lk8 * 8, dr = lk8 * 4;
  const int rt = wave >> 1, kh = wave & 1;
  const int rowbase = rt * 16;
  const int gb = grp * 32;

  f16* h0g = A.h0 + (size_t)grp * RING * 32 * 1024;
  f16* h1g = A.h1 + (size_t)grp * RING * 32 * 1024;
  f16* h0sg = A.h0s + (size_t)grp * SRING * 32 * 1024;
  f16* h1sg = A.h1s + (size_t)grp * SRING * 32 * 1024;
  unsigned* prod1 = A.flg + (size_t)grp * 2 * 2048 + 2048;

  __threadfence();  // once: cross-replay hygiene (wb+inv all cache levels)

  ((float*)sm.hm)[tid] = 0.f;
  ((float*)sm.hm)[tid + 256] = 0.f;

  if (isL0) {
    load_w<128, 128>(sm.wA, A.whh0, j);
    load_w<64, 64>(sm.wB, A.wih0, j);
    if (tid < 48) {
      int gcol = (tid >> 4) * 1024 + j * 16 + (tid & 15);
      sm.bI[tid] = A.bih0[gcol];
      sm.bH[tid] = A.bhh0[gcol];
    }
  } else {
    load_w<128, 128>(sm.wA, A.whh1, j);
    load_w<64, 128>(sm.wB, A.wih1, j);  // wih1 K-half 0 in LDS
    if (tid < 48) {
      int gcol = (tid >> 4) * 1024 + j * 16 + (tid & 15);
      sm.bI[tid] = A.bih1[gcol];
      sm.bH[tid] = A.bhh1[gcol];
    }
  }
  __syncthreads();

  int consec = 0;      // consecutive staging failures (wave-uniform)
  bool fastok = true;  // sticky staging enable

  if (isL0) {
    // =============== layer-0 ===============
    f16x8 xf[2][8];
    {
      const f16* xp = A.x16 + ((size_t)0 * 64 + gb + rowbase + lr) * 512 + kh * 256 + lk;
#pragma unroll
      for (int q2 = 0; q2 < 8; ++q2) xf[0][q2] = *(const f16x8*)(xp + q2 * 32);
    }
    for (int t = 0; t < 1024; ++t) {
      const int cur = t & 1;
      if (((t & 15) == 0) && t >= 48 && wave == 0) {  // amortized ring guard
        const int need = t - 40;
        const unsigned* p1 = prod1 + lane * 32;
        while (!__all((int)aldu(p1) >= need)) __builtin_amdgcn_s_sleep(8);
      }
      f32x4 a0 = {0.f, 0.f, 0.f, 0.f}, a1 = a0, a2 = a0, a3 = a0;
#pragma unroll
      for (int q2 = 0; q2 < 8; ++q2) {
        const int u8 = (kh * 8 + q2) * 4 + lk8;
        a0 = mf(xf[cur][q2], ldb<64>(sm.wB, lr, u8), a0);
        a1 = mf(xf[cur][q2], ldb<64>(sm.wB, 16 + lr, u8), a1);
        a2 = mf(xf[cur][q2], ldb<64>(sm.wB, 32 + lr, u8), a2);  // i_n
      }
      if (t + 1 < 1024) {
        const f16* xp = A.x16 + ((size_t)(t + 1) * 64 + gb + rowbase + lr) * 512 + kh * 256 + lk;
#pragma unroll
        for (int q2 = 0; q2 < 8; ++q2) xf[cur ^ 1][q2] = *(const f16x8*)(xp + q2 * 32);
      }
      // ---- hf = h0(t-1): staging fast path -> canonical fallback ----
      frag16 hf;
      if (t == 0) {
#pragma unroll
        for (int q2 = 0; q2 < 16; ++q2) hf.v[q2] = 0;
      } else {
        const unsigned ep = 0x10001u * tag_of(t - 1);
        bool got = false;
        if (fastok) {
          const f16* sp = h0sg + (((size_t)((t - 1) & (SRING - 1))) * 32 + rowbase + lr) * 1024 + kh * 512 + lk;
          frag16 f = ld16_l2(sp);
          int tries = 0;
          for (;;) {
            if (__all(vfrag(f, ep))) { hf = f; got = true; break; }
            if (++tries > 2) break;
            __builtin_amdgcn_s_sleep(1);
            f = ld16_l2(sp);
          }
          if (got) consec = 0;
          else if (++consec >= 6) fastok = false;
        }
        if (!got) {
          const f16* hp = h0g + ((size_t)((t + RING - 1) & (RING - 1)) * 32 + rowbase + lr) * 1024 + kh * 512 + lk;
          hf = ld16_val(hp, ep);
        }
      }
#pragma unroll
      for (int q2 = 0; q2 < 16; ++q2) {
        const int u8 = (kh * 16 + q2) * 4 + lk8;
        a0 = mf(hf.v[q2], ldb<128>(sm.wA, lr, u8), a0);
        a1 = mf(hf.v[q2], ldb<128>(sm.wA, 16 + lr, u8), a1);
        a3 = mf(hf.v[q2], ldb<128>(sm.wA, 32 + lr, u8), a3);  // h_n
      }
      if (kh) {
#pragma unroll
        for (int q = 0; q < 4; ++q) {
          sm.sc[rt][0][q][lane] = a0[q]; sm.sc[rt][1][q][lane] = a1[q];
          sm.sc[rt][2][q][lane] = a2[q]; sm.sc[rt][3][q][lane] = a3[q];
        }
      }
      __syncthreads();
      if (!kh) {
        float hn4[4];
#pragma unroll
        for (int q = 0; q < 4; ++q) {
          a0[q] += sm.sc[rt][0][q][lane]; a1[q] += sm.sc[rt][1][q][lane];
          a2[q] += sm.sc[rt][2][q][lane]; a3[q] += sm.sc[rt][3][q][lane];
        }
#pragma unroll
        for (int q = 0; q < 4; ++q) {
          const int row = rt * 16 + dr + q;
          float r = sigf(a0[q] + sm.bI[lr] + sm.bH[lr]);
          float z = sigf(a1[q] + sm.bI[16 + lr] + sm.bH[16 + lr]);
          float n = tanh_fast(a2[q] + sm.bI[32 + lr] + r * (a3[q] + sm.bH[32 + lr]));
          float hn = n + z * (sm.hm[row][lr] - n);
          sm.hm[row][lr] = hn;
          hn4[q] = hn;
        }
        u64 w = pack4(hn4, lr, tag_of(t));
        unsigned wlo = (unsigned)w, whi = (unsigned)(w >> 32);
        unsigned plo = (unsigned)__shfl_xor((int)wlo, 4, 64);
        unsigned phi = (unsigned)__shfl_xor((int)whi, 4, 64);
        if ((lr & 4) == 0) {
          const int srow = rt * 16 + dr + (lr & 3);
          u32x4 v4 = {wlo, whi, plo, phi};
          const size_t co = (size_t)srow * 1024 + j * 16 + (lr & ~7);
          st16_coh(h0g + ((size_t)(t & (RING - 1)) * 32) * 1024 + co, v4);      // canonical
          *(u32x4*)(h0sg + ((size_t)(t & (SRING - 1)) * 32) * 1024 + co) = v4;  // staging (local L2)
        }
      }
      __syncthreads();
    }
  } else {
    // =============== layer-1 ===============
    for (int t = 0; t < 1024; ++t) {
      // ---- gf = h0(t): sc0-cached (L0 far ahead; one IF fill per XCD) ----
      const f16* gp = h0g + ((size_t)(t & (RING - 1)) * 32 + rowbase + lr) * 1024 + kh * 512 + lk;
      const unsigned epg = 0x10001u * tag_of(t);
      frag16 gf;
      {
        frag16 f = ld16_l2(gp);
        int tries = 0; bool ok = false;
        for (;;) {
          if (__all(vfrag(f, epg))) { gf = f; ok = true; break; }
          if (++tries > 2) break;
          __builtin_amdgcn_s_sleep(1);
          f = ld16_l2(gp);
        }
        if (!ok) gf = ld16_val(gp, epg);
      }
      // ---- hf = h1(t-1): staging fast path -> canonical fallback ----
      frag16 hf;
      if (t == 0) {
#pragma unroll
        for (int q2 = 0; q2 < 16; ++q2) hf.v[q2] = 0;
      } else {
        const unsigned ep = 0x10001u * tag_of(t - 1);
        bool got = false;
        if (fastok) {
          const f16* sp = h1sg + (((size_t)((t - 1) & (SRING - 1))) * 32 + rowbase + lr) * 1024 + kh * 512 + lk;
          frag16 f = ld16_l2(sp);
          int tries = 0;
          for (;;) {
            if (__all(vfrag(f, ep))) { hf = f; got = true; break; }
            if (++tries > 2) break;
            __builtin_amdgcn_s_sleep(1);
            f = ld16_l2(sp);
          }
          if (got) consec = 0;
          else if (++consec >= 6) fastok = false;
        }
        if (!got) {
          const f16* hp = h1g + ((size_t)((t + RING - 1) & (RING - 1)) * 32 + rowbase + lr) * 1024 + kh * 512 + lk;
          hf = ld16_val(hp, ep);
        }
      }
      f32x4 a0 = {0.f, 0.f, 0.f, 0.f}, a1 = a0, a2 = a0, a3 = a0;
      if (kh == 0) {
#pragma unroll
        for (int q2 = 0; q2 < 16; ++q2) {
          const int u8 = q2 * 4 + lk8;
          a0 = mf(gf.v[q2], ldb<64>(sm.wB, lr, u8), a0);
          a1 = mf(gf.v[q2], ldb<64>(sm.wB, 16 + lr, u8), a1);
          a2 = mf(gf.v[q2], ldb<64>(sm.wB, 32 + lr, u8), a2);  // i_n
        }
      } else {
        const f16* wb = A.wih1 + ((size_t)(j * 16 + lr)) * 1024 + 512 + lk;
#pragma unroll
        for (int q2 = 0; q2 < 16; ++q2) {
          const size_t o = (size_t)q2 * 32;
          a0 = mf(gf.v[q2], *(const f16x8*)(wb + o), a0);
          a1 = mf(gf.v[q2], *(const f16x8*)(wb + (size_t)1024 * 1024 + o), a1);
          a2 = mf(gf.v[q2], *(const f16x8*)(wb + (size_t)2048 * 1024 + o), a2);  // i_n
        }
      }
#pragma unroll
      for (int q2 = 0; q2 < 16; ++q2) {
        const int u8 = (kh * 16 + q2) * 4 + lk8;
        a0 = mf(hf.v[q2], ldb<128>(sm.wA, lr, u8), a0);
        a1 = mf(hf.v[q2], ldb<128>(sm.wA, 16 + lr, u8), a1);
        a3 = mf(hf.v[q2], ldb<128>(sm.wA, 32 + lr, u8), a3);  // h_n
      }
      if (kh) {
#pragma unroll
        for (int q = 0; q < 4; ++q) {
          sm.sc[rt][0][q][lane] = a0[q]; sm.sc[rt][1][q][lane] = a1[q];
          sm.sc[rt][2][q][lane] = a2[q]; sm.sc[rt][3][q][lane] = a3[q];
        }
      }
      __syncthreads();
      if (!kh) {
        float hn4[4];
#pragma unroll
        for (int q = 0; q < 4; ++q) {
          a0[q] += sm.sc[rt][0][q][lane]; a1[q] += sm.sc[rt][1][q][lane];
          a2[q] += sm.sc[rt][2][q][lane]; a3[q] += sm.sc[rt][3][q][lane];
        }
#pragma unroll
        for (int q = 0; q < 4; ++q) {
          const int row = rt * 16 + dr + q;
          float r = sigf(a0[q] + sm.bI[lr] + sm.bH[lr]);
          float z = sigf(a1[q] + sm.bI[16 + lr] + sm.bH[16 + lr]);
          float n = tanh_fast(a2[q] + sm.bI[32 + lr] + r * (a3[q] + sm.bH[32 + lr]));
          float hn = n + z * (sm.hm[row][lr] - n);
          sm.hm[row][lr] = hn;
          hn4[q] = hn;
        }
        u64 w = pack4(hn4, lr, tag_of(t));
        unsigned wlo = (unsigned)w, whi = (unsigned)(w >> 32);
        unsigned plo = (unsigned)__shfl_xor((int)wlo, 4, 64);
        unsigned phi = (unsigned)__shfl_xor((int)whi, 4, 64);
        if ((lr & 4) == 0) {
          const int srow = rt * 16 + dr + (lr & 3);
          u32x4 v4 = {wlo, whi, plo, phi};
          const size_t co = (size_t)srow * 1024 + j * 16 + (lr & ~7);
          st16_coh(h1g + ((size_t)(t & (RING - 1)) * 32) * 1024 + co, v4);      // canonical
          *(u32x4*)(h1sg + ((size_t)(t & (SRING - 1)) * 32) * 1024 + co) = v4;  // staging
        }
      }
      __syncthreads();
      if (tid == 0) astu(prod1 + wgid * 32, (unsigned)(t + 1));
    }

    // ---- output projection: out rows gb..gb+31 = h1(1023) @ w_out^T + b_out ----
    const int j2 = wgid & 31, rg2 = wgid >> 5;
    f32x4 acc = {0.f, 0.f, 0.f, 0.f};
    if (wave < 2) {
      const f16* Ah = h1g + ((size_t)(1023 & (RING - 1)) * 32 + rg2 * 16 + lr) * 1024 + wave * 512 + lk;
      const f16* Bp = A.wout + ((size_t)(j2 * 16 + lr)) * 1024 + wave * 512 + lk;
      frag16 hv = ld16_val(Ah, 0x10001u * gru::tag_of(1023));
#pragma unroll
      for (int q2 = 0; q2 < 16; ++q2)
        acc = mf(hv.v[q2], *(const f16x8*)(Bp + q2 * 32), acc);
    }
    if (wave == 1) {
#pragma unroll
      for (int q = 0; q < 4; ++q) sm.sc[0][0][q][lane] = acc[q];
    }
    __syncthreads();
    if (wave == 0) {
#pragma unroll
      for (int q = 0; q < 4; ++q) {
        float v = acc[q] + sm.sc[0][0][q][lane] + A.bout[j2 * 16 + lr];
        A.out[(gb + rg2 * 16 + dr + q) * 512 + j2 * 16 + lr] = v;
      }
    }
  }
}

// ---------------- host ----------------

extern "C" void kernel_launch(void* const* d_in, const int* in_sizes, int n_in,
                              void* d_out, int out_size, void* d_ws, size_t ws_size,
                              hipStream_t stream) {
  (void)in_sizes; (void)n_in; (void)out_size; (void)ws_size;
  const float* x = (const float*)d_in[0];
  const float* w_ih0 = (const float*)d_in[1];
  const float* w_hh0 = (const float*)d_in[2];
  const float* b_ih0 = (const float*)d_in[3];
  const float* b_hh0 = (const float*)d_in[4];
  const float* w_ih1 = (const float*)d_in[5];
  const float* w_hh1 = (const float*)d_in[6];
  const float* b_ih1 = (const float*)d_in[7];
  const float* b_hh1 = (const float*)d_in[8];
  const float* w_out = (const float*)d_in[9];
  const float* b_out = (const float*)d_in[10];

  char* ws = (char*)d_ws;
  size_t off = 0;
  auto alloc = [&](size_t b) {
    off = (off + 255) & ~(size_t)255;
    char* p = ws + off;
    off += b;
    return p;
  };

  float* pe = (float*)alloc((size_t)1024 * 512 * 4);
  f16* x16 = (f16*)alloc((size_t)1024 * 64 * 512 * 2);
  f16* wih0 = (f16*)alloc((size_t)3072 * 512 * 2);
  f16* whh0 = (f16*)alloc((size_t)3072 * 1024 * 2);
  f16* wih1 = (f16*)alloc((size_t)3072 * 1024 * 2);
  f16* whh1 = (f16*)alloc((size_t)3072 * 1024 * 2);
  f16* wout = (f16*)alloc((size_t)512 * 1024 * 2);
  f16* h0r = (f16*)alloc((size_t)2 * RING * 32 * 1024 * 2);
  f16* h1r = (f16*)alloc((size_t)2 * RING * 32 * 1024 * 2);
  f16* h0s = (f16*)alloc((size_t)2 * SRING * 32 * 1024 * 2);
  f16* h1s = (f16*)alloc((size_t)2 * SRING * 32 * 1024 * 2);
  unsigned* flg = (unsigned*)alloc((size_t)2 * 2 * 2048 * 4);

  // per-call init: rings + staging all tag-0 (invalid); counters zero.
  (void)hipMemsetAsync(h0r, 0, (size_t)2 * RING * 32 * 1024 * 2, stream);
  (void)hipMemsetAsync(h1r, 0, (size_t)2 * RING * 32 * 1024 * 2, stream);
  (void)hipMemsetAsync(h0s, 0, (size_t)2 * SRING * 32 * 1024 * 2, stream);
  (void)hipMemsetAsync(h1s, 0, (size_t)2 * SRING * 32 * 1024 * 2, stream);
  (void)hipMemsetAsync(flg, 0, (size_t)2 * 2 * 2048 * 4, stream);

  gru_k_pe<<<(1024 * 512 + 255) / 256, 256, 0, stream>>>(pe);
  gru_k_x16<<<dim3(2, 1024, 64), 256, 0, stream>>>(x, pe, x16);
  gru_k_f16<<<(3072 * 512 + 255) / 256, 256, 0, stream>>>(w_ih0, wih0, 3072 * 512);
  gru_k_f16<<<(3072 * 1024 + 255) / 256, 256, 0, stream>>>(w_hh0, whh0, 3072 * 1024);
  gru_k_f16<<<(3072 * 1024 + 255) / 256, 256, 0, stream>>>(w_ih1, wih1, 3072 * 1024);
  gru_k_f16<<<(3072 * 1024 + 255) / 256, 256, 0, stream>>>(w_hh1, whh1, 3072 * 1024);
  gru_k_f16<<<(512 * 1024 + 255) / 256, 256, 0, stream>>>(w_out, wout, 512 * 1024);

  gru::Args A;
  A.x16 = x16;
  A.bih0 = b_ih0; A.bhh0 = b_hh0; A.bih1 = b_ih1; A.bhh1 = b_hh1; A.bout = b_out;
  A.wih0 = wih0; A.whh0 = whh0; A.wih1 = wih1; A.whh1 = whh1; A.wout = wout;
  A.h0 = h0r; A.h1 = h1r;
  A.h0s = h0s; A.h1s = h1s;
  A.out = (float*)d_out;
  A.flg = flg;

  // Plain launch: 256 blocks x 1 block/CU (LDS-bound) on 256 CUs -> co-resident.
  gru_main<<<dim3(NWG), dim3(WGSZ), 0, stream>>>(A);
}